// Round 3
// baseline (1747.435 us; speedup 1.0000x reference)
//
#include <hip/hip_runtime.h>
#include <hip/hip_bf16.h>
#include <math.h>

static constexpr int Bc = 2, Tc = 2048, Cc = 1024, Hc = 16;
static constexpr int Mc = Bc * Tc;  // 4096 rows

// ---------- dtype helpers ----------
__device__ __forceinline__ float bf2f(unsigned short u) {
  return __uint_as_float((unsigned)u << 16);
}
__device__ __forceinline__ unsigned short f2bf(float f) {
  __hip_bfloat16 h = __float2bfloat16(f);
  return *(unsigned short*)&h;
}
__device__ __forceinline__ float4 ld4(const float* p) { return *(const float4*)p; }
__device__ __forceinline__ float4 ld4(const unsigned short* p) {
  ushort4 u = *(const ushort4*)p;
  return make_float4(bf2f(u.x), bf2f(u.y), bf2f(u.z), bf2f(u.w));
}
__device__ __forceinline__ void stv(float* p, float v) { *p = v; }
__device__ __forceinline__ void stv(unsigned short* p, float v) { *p = f2bf(v); }
__device__ __forceinline__ float ldsc(const float* p) { return *p; }
__device__ __forceinline__ float ldsc(const unsigned short* p) { return bf2f(*p); }

// ---------------- RoPE tables ----------------
__global__ __launch_bounds__(256) void k_tables(float* __restrict__ tc, float* __restrict__ ts) {
  int i = blockIdx.x * 256 + threadIdx.x;       // < Tc*32
  int t = i >> 5, f = i & 31;
  float ivf = 1.0f / powf(10000.f, (float)f / 32.f);
  float fr = (float)t * ivf;
  tc[i] = cosf(fr);
  ts[i] = sinf(fr);
}

__device__ __forceinline__ float phi_fn(float x) { return x > 0.f ? x + 1.f : __expf(x); }

// ---------------- 128x128 fp32 GEMM, fused epilogues ----------------
// MODE 0: plain store   MODE 1: RoPE + phi (q/k)   MODE 2: +bias +residual
template <typename AT, typename OT, int MODE>
__global__ __launch_bounds__(256) void k_gemm128(
    const AT* __restrict__ A, const float* __restrict__ Bw, OT* __restrict__ Co,
    int M, int N, int K,
    const float* __restrict__ tabC, const float* __restrict__ tabS,
    const float* __restrict__ bias, const float* __restrict__ resid) {
  __shared__ float As[16][132];
  __shared__ float Bs[16][132];
  const int tid = threadIdx.x;
  const int tx = tid & 15, ty = tid >> 4;
  const int n0 = blockIdx.x * 128, m0 = blockIdx.y * 128;

  float acc[8][8];
#pragma unroll
  for (int i = 0; i < 8; ++i)
#pragma unroll
    for (int j = 0; j < 8; ++j) acc[i][j] = 0.f;

  for (int k0 = 0; k0 < K; k0 += 16) {
#pragma unroll
    for (int rep = 0; rep < 2; ++rep) {
      int lin = tid + rep * 256;
      int r = lin >> 2, c4 = (lin & 3) << 2;
      float4 av = ld4(&A[(size_t)(m0 + r) * K + k0 + c4]);
      As[c4 + 0][r] = av.x; As[c4 + 1][r] = av.y;
      As[c4 + 2][r] = av.z; As[c4 + 3][r] = av.w;
      int rb = lin >> 5, cb = (lin & 31) << 2;
      *(float4*)&Bs[rb][cb] = *(const float4*)&Bw[(size_t)(k0 + rb) * N + n0 + cb];
    }
    __syncthreads();
#pragma unroll
    for (int kk = 0; kk < 16; ++kk) {
      float4 a0 = *(const float4*)&As[kk][ty * 8];
      float4 a1 = *(const float4*)&As[kk][ty * 8 + 4];
      float4 b0 = *(const float4*)&Bs[kk][tx * 8];
      float4 b1 = *(const float4*)&Bs[kk][tx * 8 + 4];
      float avv[8] = {a0.x, a0.y, a0.z, a0.w, a1.x, a1.y, a1.z, a1.w};
      float bvv[8] = {b0.x, b0.y, b0.z, b0.w, b1.x, b1.y, b1.z, b1.w};
#pragma unroll
      for (int i = 0; i < 8; ++i)
#pragma unroll
        for (int j = 0; j < 8; ++j) acc[i][j] = fmaf(avv[i], bvv[j], acc[i][j]);
    }
    __syncthreads();
  }

  if constexpr (MODE == 1) {
#pragma unroll
    for (int i = 0; i < 8; ++i) {
      int row = m0 + ty * 8 + i;
      int t = row & (Tc - 1);
#pragma unroll
      for (int j = 0; j < 8; j += 2) {
        int col = n0 + tx * 8 + j;
        int pi = (col & 63) >> 1;
        float cv = tabC[t * 32 + pi], sv = tabS[t * 32 + pi];
        float xe = acc[i][j], xo = acc[i][j + 1];
        float re = xe * cv - xo * sv;
        float ro = xe * sv + xo * cv;
        stv(&Co[(size_t)row * N + col], phi_fn(re));
        stv(&Co[(size_t)row * N + col + 1], phi_fn(ro));
      }
    }
  } else if constexpr (MODE == 2) {
#pragma unroll
    for (int i = 0; i < 8; ++i) {
      int row = m0 + ty * 8 + i;
#pragma unroll
      for (int j = 0; j < 8; ++j) {
        int col = n0 + tx * 8 + j;
        float v = acc[i][j] + bias[col] + resid[(size_t)row * N + col];
        stv(&Co[(size_t)row * N + col], v);
      }
    }
  } else {
#pragma unroll
    for (int i = 0; i < 8; ++i) {
      int row = m0 + ty * 8 + i;
#pragma unroll
      for (int j = 0; j < 8; ++j) {
        int col = n0 + tx * 8 + j;
        stv(&Co[(size_t)row * N + col], acc[i][j]);
      }
    }
  }
}

// ---------------- gate / decay projections (N=32) ----------------
__global__ __launch_bounds__(256) void k_small(
    const float* __restrict__ x, const float* __restrict__ gate_w, const float* __restrict__ gate_b,
    const float* __restrict__ decay_w, const float* __restrict__ decay_b,
    const float* __restrict__ decay_w0, float* __restrict__ gate_o, float* __restrict__ beta_o) {
  __shared__ float xs[1024];
  __shared__ float part[8][32];
  int bt = blockIdx.x;
  int tid = threadIdx.x;
  *(float4*)&xs[tid * 4] = *(const float4*)&x[(size_t)bt * Cc + tid * 4];
  __syncthreads();
  int o = tid & 31, seg = tid >> 5;
  const float* wp = (o < 16) ? gate_w : decay_w;
  int oc = o & 15;
  float p = 0.f;
  int kb = seg * 128;
#pragma unroll 4
  for (int kk = 0; kk < 128; ++kk) {
    int k = kb + kk;
    p = fmaf(xs[k], wp[(size_t)k * 16 + oc], p);
  }
  part[seg][o] = p;
  __syncthreads();
  if (tid < 32) {
    float s = 0.f;
#pragma unroll
    for (int sg = 0; sg < 8; ++sg) s += part[sg][tid];
    int b = bt >> 11, t = bt & (Tc - 1);
    if (tid < 16) {
      float gv = 1.f / (1.f + expf(-(s + gate_b[tid])));
      gate_o[((size_t)(b * Hc + tid)) * Tc + t] = gv;
    } else {
      int hh = tid - 16;
      float raw = s + decay_b[hh] + decay_w0[hh];
      float sp = raw > 20.f ? raw : log1pf(expf(raw));
      float rate = fminf(fmaxf(sp, 1e-4f), 10.f);
      beta_o[((size_t)(b * Hc + hh)) * Tc + t] = expf(-rate);
    }
  }
}

// ---------------- serial decayed-rank1 scan, one block per (b,h) ----------------
__device__ __forceinline__ void load16(const float* __restrict__ p, float* d) {
  float4 a = *(const float4*)p, b = *(const float4*)(p + 4);
  float4 c = *(const float4*)(p + 8), e = *(const float4*)(p + 12);
  d[0] = a.x; d[1] = a.y; d[2] = a.z; d[3] = a.w;
  d[4] = b.x; d[5] = b.y; d[6] = b.z; d[7] = b.w;
  d[8] = c.x; d[9] = c.y; d[10] = c.z; d[11] = c.w;
  d[12] = e.x; d[13] = e.y; d[14] = e.z; d[15] = e.w;
}
__device__ __forceinline__ void load16(const unsigned short* __restrict__ p, float* d) {
  uint4 u = *(const uint4*)p;
  uint4 v = *(const uint4*)(p + 8);
  d[0] = __uint_as_float(u.x << 16); d[1] = __uint_as_float(u.x & 0xFFFF0000u);
  d[2] = __uint_as_float(u.y << 16); d[3] = __uint_as_float(u.y & 0xFFFF0000u);
  d[4] = __uint_as_float(u.z << 16); d[5] = __uint_as_float(u.z & 0xFFFF0000u);
  d[6] = __uint_as_float(u.w << 16); d[7] = __uint_as_float(u.w & 0xFFFF0000u);
  d[8] = __uint_as_float(v.x << 16); d[9] = __uint_as_float(v.x & 0xFFFF0000u);
  d[10] = __uint_as_float(v.y << 16); d[11] = __uint_as_float(v.y & 0xFFFF0000u);
  d[12] = __uint_as_float(v.z << 16); d[13] = __uint_as_float(v.z & 0xFFFF0000u);
  d[14] = __uint_as_float(v.w << 16); d[15] = __uint_as_float(v.w & 0xFFFF0000u);
}

template <typename ET>
__device__ __forceinline__ void load_step(const ET* __restrict__ qp, const ET* __restrict__ kp,
    const ET* __restrict__ vp, const float* __restrict__ bp, const float* __restrict__ gp,
    int t, float* q, float* k, float& vv, float& btv, float& gtv) {
  size_t off = (size_t)t * Cc;
  load16(qp + off, q);
  load16(kp + off, k);
  vv = ldsc(vp + off);
  btv = bp[t];
  gtv = gp[t];
}

__device__ __forceinline__ float do_step(const float* q, const float* k, float vv, float btv, float gtv,
                                         float* Ns, float* Ds) {
  float yn = 0.f, den = 0.f;
#pragma unroll
  for (int j = 0; j < 16; ++j) {
    float wj = k[j] * gtv;
    float ns = fmaf(Ns[j], btv, wj * vv);
    float ds = fmaf(Ds[j], btv, wj);
    Ns[j] = ns; Ds[j] = ds;
    yn = fmaf(q[j], ns, yn);
    den = fmaf(q[j], ds, den);
  }
  yn += __shfl_xor(yn, 16); yn += __shfl_xor(yn, 32);
  den += __shfl_xor(den, 16); den += __shfl_xor(den, 32);
  return yn / (den + 1e-6f);
}

template <typename ET>
__global__ __launch_bounds__(256) void k_scan(const ET* __restrict__ phiQ, const ET* __restrict__ phiK,
    const ET* __restrict__ Vb, const float* __restrict__ betaB, const float* __restrict__ gateB,
    ET* __restrict__ Yb) {
  int bh = blockIdx.x;
  int b = bh >> 4, h = bh & 15;
  int tid = threadIdx.x;
  int w = tid >> 6, l = tid & 63;
  int e = (w << 4) | (l & 15);   // output column 0..63
  int d0 = (l >> 4) << 4;        // 16 d's per lane
  size_t base = ((size_t)b * Tc) * Cc + h * 64;
  const ET* qp = phiQ + base + d0;
  const ET* kp = phiK + base + d0;
  const ET* vp = Vb + base + e;
  const float* bp = betaB + (size_t)bh * Tc;
  const float* gp = gateB + (size_t)bh * Tc;
  ET* yp = Yb + base + e;

  float Ns[16], Ds[16];
#pragma unroll
  for (int j = 0; j < 16; ++j) { Ns[j] = 0.f; Ds[j] = 0.f; }
  float qA[16], kA[16], vA, btA, gtA;
  float qB[16], kB[16], vB, btB, gtB;
  load_step(qp, kp, vp, bp, gp, 0, qA, kA, vA, btA, gtA);
  load_step(qp, kp, vp, bp, gp, 1, qB, kB, vB, btB, gtB);
  const bool wr = (l < 16);
  for (int t = 0; t < Tc; t += 2) {
    float y0 = do_step(qA, kA, vA, btA, gtA, Ns, Ds);
    if (wr) stv(yp + (size_t)t * Cc, y0);
    if (t + 2 < Tc) load_step(qp, kp, vp, bp, gp, t + 2, qA, kA, vA, btA, gtA);
    float y1 = do_step(qB, kB, vB, btB, gtB, Ns, Ds);
    if (wr) stv(yp + (size_t)(t + 1) * Cc, y1);
    if (t + 3 < Tc) load_step(qp, kp, vp, bp, gp, t + 3, qB, kB, vB, btB, gtB);
  }
}

// ---------------- row LayerNorm -> fp32 out (reference output dtype is float32) ----------------
__global__ __launch_bounds__(256) void k_ln(const float* __restrict__ pre, const float* __restrict__ ln_g,
    const float* __restrict__ ln_b, float* __restrict__ out) {
  int row = blockIdx.x;
  int tid = threadIdx.x;
  float4 v = *(const float4*)&pre[(size_t)row * Cc + tid * 4];
  float s = v.x + v.y + v.z + v.w;
  float q = v.x * v.x + v.y * v.y + v.z * v.z + v.w * v.w;
#pragma unroll
  for (int off = 1; off < 64; off <<= 1) {
    s += __shfl_xor(s, off);
    q += __shfl_xor(q, off);
  }
  __shared__ float ss[4], qq[4];
  if ((tid & 63) == 0) { ss[tid >> 6] = s; qq[tid >> 6] = q; }
  __syncthreads();
  s = ss[0] + ss[1] + ss[2] + ss[3];
  q = qq[0] + qq[1] + qq[2] + qq[3];
  float mu = s * (1.f / 1024.f);
  float var = q * (1.f / 1024.f) - mu * mu;
  float rstd = rsqrtf(var + 1e-5f);
  int c0 = tid * 4;
  float4 g = *(const float4*)&ln_g[c0];
  float4 bb = *(const float4*)&ln_b[c0];
  float4 o;
  o.x = (v.x - mu) * rstd * g.x + bb.x;
  o.y = (v.y - mu) * rstd * g.y + bb.y;
  o.z = (v.z - mu) * rstd * g.z + bb.z;
  o.w = (v.w - mu) * rstd * g.w + bb.w;
  *(float4*)&out[(size_t)row * Cc + c0] = o;
}

extern "C" void kernel_launch(void* const* d_in, const int* in_sizes, int n_in,
                              void* d_out, int out_size, void* d_ws, size_t ws_size,
                              hipStream_t stream) {
  const float* x        = (const float*)d_in[0];
  const float* q_w      = (const float*)d_in[1];
  const float* k_w      = (const float*)d_in[2];
  const float* v_w      = (const float*)d_in[3];
  const float* out_w    = (const float*)d_in[4];
  const float* out_b    = (const float*)d_in[5];
  const float* decay_w  = (const float*)d_in[6];
  const float* decay_b  = (const float*)d_in[7];
  const float* gate_w   = (const float*)d_in[8];
  const float* gate_b   = (const float*)d_in[9];
  const float* decay_w0 = (const float*)d_in[10];
  const float* ln_g     = (const float*)d_in[11];
  const float* ln_b     = (const float*)d_in[12];
  float* out            = (float*)d_out;   // reference output dtype = float32

  const size_t MC  = (size_t)Mc * Cc;      // 4,194,304 elements
  const size_t BHT = (size_t)Bc * Hc * Tc; // 65,536
  dim3 gg(Cc / 128, Mc / 128);

  const bool fp32path = ws_size >= (size_t)52 * 1024 * 1024;

  if (fp32path) {
    // ---- 49 MiB fp32 layout; Y aliases V (scan reads V[t..t+3] before writing Y[t]) ----
    float* tabC  = (float*)d_ws;
    float* tabS  = tabC + (size_t)Tc * 32;
    float* phiQ  = tabS + (size_t)Tc * 32;
    float* phiK  = phiQ + MC;
    float* VY    = phiK + MC;             // V, later overwritten in-place by Y
    float* betaB = VY + MC;
    float* gateB = betaB + BHT;
    float* preO  = phiK;                  // phiK dead after scan

    k_tables<<<(Tc * 32) / 256, 256, 0, stream>>>(tabC, tabS);
    k_gemm128<float, float, 1><<<gg, 256, 0, stream>>>(x, q_w, phiQ, Mc, Cc, Cc, tabC, tabS, nullptr, nullptr);
    k_gemm128<float, float, 1><<<gg, 256, 0, stream>>>(x, k_w, phiK, Mc, Cc, Cc, tabC, tabS, nullptr, nullptr);
    k_gemm128<float, float, 0><<<gg, 256, 0, stream>>>(x, v_w, VY, Mc, Cc, Cc, nullptr, nullptr, nullptr, nullptr);
    k_small<<<Mc, 256, 0, stream>>>(x, gate_w, gate_b, decay_w, decay_b, decay_w0, gateB, betaB);
    k_scan<float><<<Bc * Hc, 256, 0, stream>>>(phiQ, phiK, VY, betaB, gateB, VY);
    k_gemm128<float, float, 2><<<gg, 256, 0, stream>>>(VY, out_w, preO, Mc, Cc, Cc, nullptr, nullptr, out_b, x);
    k_ln<<<Mc, 256, 0, stream>>>(preO, ln_g, ln_b, out);
  } else {
    // ---- 33 MiB bf16-intermediate layout ----
    float* tabC  = (float*)d_ws;
    float* tabS  = tabC + (size_t)Tc * 32;
    unsigned short* phiQb = (unsigned short*)(tabS + (size_t)Tc * 32);
    unsigned short* phiKb = phiQb + MC;
    unsigned short* Vbb   = phiKb + MC;
    unsigned short* Ybb   = Vbb + MC;
    float* betaB = (float*)(Ybb + MC);
    float* gateB = betaB + BHT;
    float* preO  = (float*)phiQb;         // phiQ/phiK dead after scan; 16 MB fp32 fits over both

    k_tables<<<(Tc * 32) / 256, 256, 0, stream>>>(tabC, tabS);
    k_gemm128<float, unsigned short, 1><<<gg, 256, 0, stream>>>(x, q_w, phiQb, Mc, Cc, Cc, tabC, tabS, nullptr, nullptr);
    k_gemm128<float, unsigned short, 1><<<gg, 256, 0, stream>>>(x, k_w, phiKb, Mc, Cc, Cc, tabC, tabS, nullptr, nullptr);
    k_gemm128<float, unsigned short, 0><<<gg, 256, 0, stream>>>(x, v_w, Vbb, Mc, Cc, Cc, nullptr, nullptr, nullptr, nullptr);
    k_small<<<Mc, 256, 0, stream>>>(x, gate_w, gate_b, decay_w, decay_b, decay_w0, gateB, betaB);
    k_scan<unsigned short><<<Bc * Hc, 256, 0, stream>>>(phiQb, phiKb, Vbb, betaB, gateB, Ybb);
    k_gemm128<unsigned short, float, 2><<<gg, 256, 0, stream>>>(Ybb, out_w, preO, Mc, Cc, Cc, nullptr, nullptr, out_b, x);
    k_ln<<<Mc, 256, 0, stream>>>(preO, ln_g, ln_b, out);
  }
}

// Round 4
// 932.068 us; speedup vs baseline: 1.8748x; 1.8748x over previous
//
#include <hip/hip_runtime.h>
#include <hip/hip_bf16.h>
#include <math.h>

static constexpr int Bc = 2, Tc = 2048, Cc = 1024, Hc = 16;
static constexpr int Mc = Bc * Tc;  // 4096 rows
static constexpr int NCc = 8, Lc = 256;  // chunks per (b,h), chunk length

// ---------- dtype helpers ----------
__device__ __forceinline__ float bf2f(unsigned short u) {
  return __uint_as_float((unsigned)u << 16);
}
__device__ __forceinline__ unsigned short f2bf(float f) {
  __hip_bfloat16 h = __float2bfloat16(f);
  return *(unsigned short*)&h;
}
__device__ __forceinline__ float4 ld4(const float* p) { return *(const float4*)p; }
__device__ __forceinline__ float4 ld4(const unsigned short* p) {
  ushort4 u = *(const ushort4*)p;
  return make_float4(bf2f(u.x), bf2f(u.y), bf2f(u.z), bf2f(u.w));
}
__device__ __forceinline__ void stv(float* p, float v) { *p = v; }
__device__ __forceinline__ void stv(unsigned short* p, float v) { *p = f2bf(v); }
__device__ __forceinline__ float ldsc(const float* p) { return *p; }
__device__ __forceinline__ float ldsc(const unsigned short* p) { return bf2f(*p); }

// ---------------- RoPE tables ----------------
__global__ __launch_bounds__(256) void k_tables(float* __restrict__ tc, float* __restrict__ ts) {
  int i = blockIdx.x * 256 + threadIdx.x;       // < Tc*32
  int t = i >> 5, f = i & 31;
  float ivf = 1.0f / powf(10000.f, (float)f / 32.f);
  float fr = (float)t * ivf;
  tc[i] = cosf(fr);
  ts[i] = sinf(fr);
}

__device__ __forceinline__ float phi_fn(float x) { return x > 0.f ? x + 1.f : __expf(x); }

// ---------------- 128x128 fp32 GEMM, fused epilogues ----------------
// MODE 0: plain store   MODE 1: RoPE + phi (q/k)   MODE 2: +bias +residual
template <typename AT, typename OT, int MODE>
__global__ __launch_bounds__(256) void k_gemm128(
    const AT* __restrict__ A, const float* __restrict__ Bw, OT* __restrict__ Co,
    int M, int N, int K,
    const float* __restrict__ tabC, const float* __restrict__ tabS,
    const float* __restrict__ bias, const float* __restrict__ resid) {
  __shared__ float As[16][132];
  __shared__ float Bs[16][132];
  const int tid = threadIdx.x;
  const int tx = tid & 15, ty = tid >> 4;
  const int n0 = blockIdx.x * 128, m0 = blockIdx.y * 128;

  float acc[8][8];
#pragma unroll
  for (int i = 0; i < 8; ++i)
#pragma unroll
    for (int j = 0; j < 8; ++j) acc[i][j] = 0.f;

  for (int k0 = 0; k0 < K; k0 += 16) {
#pragma unroll
    for (int rep = 0; rep < 2; ++rep) {
      int lin = tid + rep * 256;
      int r = lin >> 2, c4 = (lin & 3) << 2;
      float4 av = ld4(&A[(size_t)(m0 + r) * K + k0 + c4]);
      As[c4 + 0][r] = av.x; As[c4 + 1][r] = av.y;
      As[c4 + 2][r] = av.z; As[c4 + 3][r] = av.w;
      int rb = lin >> 5, cb = (lin & 31) << 2;
      *(float4*)&Bs[rb][cb] = *(const float4*)&Bw[(size_t)(k0 + rb) * N + n0 + cb];
    }
    __syncthreads();
#pragma unroll
    for (int kk = 0; kk < 16; ++kk) {
      float4 a0 = *(const float4*)&As[kk][ty * 8];
      float4 a1 = *(const float4*)&As[kk][ty * 8 + 4];
      float4 b0 = *(const float4*)&Bs[kk][tx * 8];
      float4 b1 = *(const float4*)&Bs[kk][tx * 8 + 4];
      float avv[8] = {a0.x, a0.y, a0.z, a0.w, a1.x, a1.y, a1.z, a1.w};
      float bvv[8] = {b0.x, b0.y, b0.z, b0.w, b1.x, b1.y, b1.z, b1.w};
#pragma unroll
      for (int i = 0; i < 8; ++i)
#pragma unroll
        for (int j = 0; j < 8; ++j) acc[i][j] = fmaf(avv[i], bvv[j], acc[i][j]);
    }
    __syncthreads();
  }

  if constexpr (MODE == 1) {
#pragma unroll
    for (int i = 0; i < 8; ++i) {
      int row = m0 + ty * 8 + i;
      int t = row & (Tc - 1);
#pragma unroll
      for (int j = 0; j < 8; j += 2) {
        int col = n0 + tx * 8 + j;
        int pi = (col & 63) >> 1;
        float cv = tabC[t * 32 + pi], sv = tabS[t * 32 + pi];
        float xe = acc[i][j], xo = acc[i][j + 1];
        float re = xe * cv - xo * sv;
        float ro = xe * sv + xo * cv;
        stv(&Co[(size_t)row * N + col], phi_fn(re));
        stv(&Co[(size_t)row * N + col + 1], phi_fn(ro));
      }
    }
  } else if constexpr (MODE == 2) {
#pragma unroll
    for (int i = 0; i < 8; ++i) {
      int row = m0 + ty * 8 + i;
#pragma unroll
      for (int j = 0; j < 8; ++j) {
        int col = n0 + tx * 8 + j;
        float v = acc[i][j] + bias[col] + resid[(size_t)row * N + col];
        stv(&Co[(size_t)row * N + col], v);
      }
    }
  } else {
#pragma unroll
    for (int i = 0; i < 8; ++i) {
      int row = m0 + ty * 8 + i;
#pragma unroll
      for (int j = 0; j < 8; ++j) {
        int col = n0 + tx * 8 + j;
        stv(&Co[(size_t)row * N + col], acc[i][j]);
      }
    }
  }
}

// ---------------- gate / decay projections (N=32) ----------------
__global__ __launch_bounds__(256) void k_small(
    const float* __restrict__ x, const float* __restrict__ gate_w, const float* __restrict__ gate_b,
    const float* __restrict__ decay_w, const float* __restrict__ decay_b,
    const float* __restrict__ decay_w0, float* __restrict__ gate_o, float* __restrict__ beta_o) {
  __shared__ float xs[1024];
  __shared__ float part[8][32];
  int bt = blockIdx.x;
  int tid = threadIdx.x;
  *(float4*)&xs[tid * 4] = *(const float4*)&x[(size_t)bt * Cc + tid * 4];
  __syncthreads();
  int o = tid & 31, seg = tid >> 5;
  const float* wp = (o < 16) ? gate_w : decay_w;
  int oc = o & 15;
  float p = 0.f;
  int kb = seg * 128;
#pragma unroll 4
  for (int kk = 0; kk < 128; ++kk) {
    int k = kb + kk;
    p = fmaf(xs[k], wp[(size_t)k * 16 + oc], p);
  }
  part[seg][o] = p;
  __syncthreads();
  if (tid < 32) {
    float s = 0.f;
#pragma unroll
    for (int sg = 0; sg < 8; ++sg) s += part[sg][tid];
    int b = bt >> 11, t = bt & (Tc - 1);
    if (tid < 16) {
      float gv = 1.f / (1.f + expf(-(s + gate_b[tid])));
      gate_o[((size_t)(b * Hc + tid)) * Tc + t] = gv;
    } else {
      int hh = tid - 16;
      float raw = s + decay_b[hh] + decay_w0[hh];
      float sp = raw > 20.f ? raw : log1pf(expf(raw));
      float rate = fminf(fmaxf(sp, 1e-4f), 10.f);
      beta_o[((size_t)(b * Hc + hh)) * Tc + t] = expf(-rate);
    }
  }
}

// ---------------- shared scan helpers ----------------
__device__ __forceinline__ void load16(const float* __restrict__ p, float* d) {
  float4 a = *(const float4*)p, b = *(const float4*)(p + 4);
  float4 c = *(const float4*)(p + 8), e = *(const float4*)(p + 12);
  d[0] = a.x; d[1] = a.y; d[2] = a.z; d[3] = a.w;
  d[4] = b.x; d[5] = b.y; d[6] = b.z; d[7] = b.w;
  d[8] = c.x; d[9] = c.y; d[10] = c.z; d[11] = c.w;
  d[12] = e.x; d[13] = e.y; d[14] = e.z; d[15] = e.w;
}
__device__ __forceinline__ void load16(const unsigned short* __restrict__ p, float* d) {
  uint4 u = *(const uint4*)p;
  uint4 v = *(const uint4*)(p + 8);
  d[0] = __uint_as_float(u.x << 16); d[1] = __uint_as_float(u.x & 0xFFFF0000u);
  d[2] = __uint_as_float(u.y << 16); d[3] = __uint_as_float(u.y & 0xFFFF0000u);
  d[4] = __uint_as_float(u.z << 16); d[5] = __uint_as_float(u.z & 0xFFFF0000u);
  d[6] = __uint_as_float(u.w << 16); d[7] = __uint_as_float(u.w & 0xFFFF0000u);
  d[8] = __uint_as_float(v.x << 16); d[9] = __uint_as_float(v.x & 0xFFFF0000u);
  d[10] = __uint_as_float(v.y << 16); d[11] = __uint_as_float(v.y & 0xFFFF0000u);
  d[12] = __uint_as_float(v.z << 16); d[13] = __uint_as_float(v.z & 0xFFFF0000u);
  d[14] = __uint_as_float(v.w << 16); d[15] = __uint_as_float(v.w & 0xFFFF0000u);
}

template <typename ET>
__device__ __forceinline__ void load_step(const ET* __restrict__ qp, const ET* __restrict__ kp,
    const ET* __restrict__ vp, const float* __restrict__ bp, const float* __restrict__ gp,
    int t, float* q, float* k, float& vv, float& btv, float& gtv) {
  size_t off = (size_t)t * Cc;
  load16(qp + off, q);
  load16(kp + off, k);
  vv = ldsc(vp + off);
  btv = bp[t];
  gtv = gp[t];
}

// yn/den returned UNDIVIDED
__device__ __forceinline__ void do_step2(const float* q, const float* k, float vv, float btv, float gtv,
                                         float* Ns, float* Ds, float& ynO, float& denO) {
  float yn = 0.f, den = 0.f;
#pragma unroll
  for (int j = 0; j < 16; ++j) {
    float wj = k[j] * gtv;
    float ns = fmaf(Ns[j], btv, wj * vv);
    float ds = fmaf(Ds[j], btv, wj);
    Ns[j] = ns; Ds[j] = ds;
    yn = fmaf(q[j], ns, yn);
    den = fmaf(q[j], ds, den);
  }
  yn += __shfl_xor(yn, 16); yn += __shfl_xor(yn, 32);
  den += __shfl_xor(den, 16); den += __shfl_xor(den, 32);
  ynO = yn; denO = den;
}

// ---------------- Phase A: per-chunk local scan (zero start state) ----------------
// grid = 32 bh * NCc chunks. Writes raw num into VY (in-place over V), den, a=prefix-beta,
// plus chunk summaries S (bf16, [blk][d][e]), Dsum ([blk][d]), P=prod beta ([blk]).
__global__ __launch_bounds__(256) void k_scanA(const float* __restrict__ phiQ, const float* __restrict__ phiK,
    float* __restrict__ VY, const float* __restrict__ betaB, const float* __restrict__ gateB,
    float* __restrict__ denB, float* __restrict__ aB,
    unsigned short* __restrict__ S, float* __restrict__ Dsum, float* __restrict__ Pbuf) {
  int blk = blockIdx.x;
  int bh = blk >> 3, c = blk & (NCc - 1);
  int b = bh >> 4, h = bh & 15;
  int tid = threadIdx.x;
  int w = tid >> 6, l = tid & 63;
  int e = (w << 4) | (l & 15);
  int d0 = (l >> 4) << 4;
  size_t base = ((size_t)b * Tc + (size_t)c * Lc) * Cc + h * 64;
  const float* qp = phiQ + base + d0;
  const float* kp = phiK + base + d0;
  const float* vp = VY + base + e;
  const float* bp = betaB + (size_t)bh * Tc + c * Lc;
  const float* gp = gateB + (size_t)bh * Tc + c * Lc;
  float* np = VY + base + e;
  float* dnp = denB + (size_t)bh * Tc + c * Lc;
  float* ap = aB + (size_t)bh * Tc + c * Lc;

  float Ns[16], Ds[16];
#pragma unroll
  for (int j = 0; j < 16; ++j) { Ns[j] = 0.f; Ds[j] = 0.f; }
  float aprod = 1.f;
  float qA[16], kA[16], vA, btA, gtA;
  float qB[16], kB[16], vB, btB, gtB;
  load_step(qp, kp, vp, bp, gp, 0, qA, kA, vA, btA, gtA);
  load_step(qp, kp, vp, bp, gp, 1, qB, kB, vB, btB, gtB);
  const bool wr = (l < 16);
  for (int t = 0; t < Lc; t += 2) {
    float yn, den;
    do_step2(qA, kA, vA, btA, gtA, Ns, Ds, yn, den);
    aprod *= btA;
    if (wr) np[(size_t)t * Cc] = yn;
    if (tid == 0) { dnp[t] = den; ap[t] = aprod; }
    if (t + 2 < Lc) load_step(qp, kp, vp, bp, gp, t + 2, qA, kA, vA, btA, gtA);
    do_step2(qB, kB, vB, btB, gtB, Ns, Ds, yn, den);
    aprod *= btB;
    if (wr) np[(size_t)(t + 1) * Cc] = yn;
    if (tid == 0) { dnp[t + 1] = den; ap[t + 1] = aprod; }
    if (t + 3 < Lc) load_step(qp, kp, vp, bp, gp, t + 3, qB, kB, vB, btB, gtB);
  }
  // chunk summaries
  size_t sbase = (size_t)blk * 4096;
#pragma unroll
  for (int j = 0; j < 16; ++j)
    S[sbase + (size_t)(d0 + j) * 64 + e] = f2bf(Ns[j]);
  if (w == 0 && (l & 15) == 0) {
#pragma unroll
    for (int j = 0; j < 16; ++j) Dsum[(size_t)blk * 64 + d0 + j] = Ds[j];
  }
  if (tid == 0) Pbuf[blk] = aprod;
}

// ---------------- Phase B: serial carry across chunks (in-place: S/Dsum become start states) ----------------
__global__ __launch_bounds__(256) void k_scanB(unsigned short* __restrict__ S, float* __restrict__ Dsum,
                                               const float* __restrict__ Pbuf) {
  int bh = blockIdx.x;
  int tid = threadIdx.x;
  float Nreg[16];
#pragma unroll
  for (int k = 0; k < 16; ++k) Nreg[k] = 0.f;
  float Dreg = 0.f;
  for (int c = 0; c < NCc; ++c) {
    size_t sb = ((size_t)bh * NCc + c) * 4096;
    float Pc = Pbuf[bh * NCc + c];
#pragma unroll
    for (int k = 0; k < 16; ++k) {
      size_t f = sb + tid + k * 256;
      float tmp = bf2f(S[f]);
      S[f] = f2bf(Nreg[k]);
      Nreg[k] = Nreg[k] * Pc + tmp;
    }
    if (tid < 64) {
      size_t db = ((size_t)bh * NCc + c) * 64 + tid;
      float tmp = Dsum[db];
      Dsum[db] = Dreg;
      Dreg = Dreg * Pc + tmp;
    }
  }
}

// ---------------- Phase C: apply start-state correction + division ----------------
__global__ __launch_bounds__(256) void k_scanC(const float* __restrict__ phiQ,
    const unsigned short* __restrict__ S, const float* __restrict__ Dsum,
    const float* __restrict__ denB, const float* __restrict__ aB, float* __restrict__ VY) {
  int blk = blockIdx.x;
  int bh = blk >> 3, c = blk & (NCc - 1);
  int b = bh >> 4, h = bh & 15;
  int tid = threadIdx.x;
  int w = tid >> 6, l = tid & 63;
  int e = (w << 4) | (l & 15);
  int d0 = (l >> 4) << 4;
  size_t sbase = (size_t)blk * 4096;
  float Nst[16], Dst[16];
#pragma unroll
  for (int j = 0; j < 16; ++j) {
    Nst[j] = bf2f(S[sbase + (size_t)(d0 + j) * 64 + e]);
    Dst[j] = Dsum[(size_t)blk * 64 + d0 + j];
  }
  size_t base = ((size_t)b * Tc + (size_t)c * Lc) * Cc + h * 64;
  const float* qp = phiQ + base + d0;
  const float* aP = aB + (size_t)bh * Tc + c * Lc;
  const float* dP = denB + (size_t)bh * Tc + c * Lc;
  float* yp = VY + base + e;
  const bool wr = (l < 16);
  for (int t = 0; t < Lc; ++t) {
    float q[16];
    load16(qp + (size_t)t * Cc, q);
    float acc = 0.f, dac = 0.f;
#pragma unroll
    for (int j = 0; j < 16; ++j) {
      acc = fmaf(q[j], Nst[j], acc);
      dac = fmaf(q[j], Dst[j], dac);
    }
    acc += __shfl_xor(acc, 16); acc += __shfl_xor(acc, 32);
    dac += __shfl_xor(dac, 16); dac += __shfl_xor(dac, 32);
    if (wr) {
      float a = aP[t], den = dP[t];
      float num = yp[(size_t)t * Cc];
      yp[(size_t)t * Cc] = (num + a * acc) / (den + a * dac + 1e-6f);
    }
  }
}

// ---------------- legacy serial scan (bf16 fallback path only) ----------------
__device__ __forceinline__ float do_step(const float* q, const float* k, float vv, float btv, float gtv,
                                         float* Ns, float* Ds) {
  float yn, den;
  do_step2(q, k, vv, btv, gtv, Ns, Ds, yn, den);
  return yn / (den + 1e-6f);
}

template <typename ET>
__global__ __launch_bounds__(256) void k_scan(const ET* __restrict__ phiQ, const ET* __restrict__ phiK,
    const ET* __restrict__ Vb, const float* __restrict__ betaB, const float* __restrict__ gateB,
    ET* __restrict__ Yb) {
  int bh = blockIdx.x;
  int b = bh >> 4, h = bh & 15;
  int tid = threadIdx.x;
  int w = tid >> 6, l = tid & 63;
  int e = (w << 4) | (l & 15);
  int d0 = (l >> 4) << 4;
  size_t base = ((size_t)b * Tc) * Cc + h * 64;
  const ET* qp = phiQ + base + d0;
  const ET* kp = phiK + base + d0;
  const ET* vp = Vb + base + e;
  const float* bp = betaB + (size_t)bh * Tc;
  const float* gp = gateB + (size_t)bh * Tc;
  ET* yp = Yb + base + e;

  float Ns[16], Ds[16];
#pragma unroll
  for (int j = 0; j < 16; ++j) { Ns[j] = 0.f; Ds[j] = 0.f; }
  float qA[16], kA[16], vA, btA, gtA;
  float qB[16], kB[16], vB, btB, gtB;
  load_step(qp, kp, vp, bp, gp, 0, qA, kA, vA, btA, gtA);
  load_step(qp, kp, vp, bp, gp, 1, qB, kB, vB, btB, gtB);
  const bool wr = (l < 16);
  for (int t = 0; t < Tc; t += 2) {
    float y0 = do_step(qA, kA, vA, btA, gtA, Ns, Ds);
    if (wr) stv(yp + (size_t)t * Cc, y0);
    if (t + 2 < Tc) load_step(qp, kp, vp, bp, gp, t + 2, qA, kA, vA, btA, gtA);
    float y1 = do_step(qB, kB, vB, btB, gtB, Ns, Ds);
    if (wr) stv(yp + (size_t)(t + 1) * Cc, y1);
    if (t + 3 < Tc) load_step(qp, kp, vp, bp, gp, t + 3, qB, kB, vB, btB, gtB);
  }
}

// ---------------- row LayerNorm -> fp32 out ----------------
__global__ __launch_bounds__(256) void k_ln(const float* __restrict__ pre, const float* __restrict__ ln_g,
    const float* __restrict__ ln_b, float* __restrict__ out) {
  int row = blockIdx.x;
  int tid = threadIdx.x;
  float4 v = *(const float4*)&pre[(size_t)row * Cc + tid * 4];
  float s = v.x + v.y + v.z + v.w;
  float q = v.x * v.x + v.y * v.y + v.z * v.z + v.w * v.w;
#pragma unroll
  for (int off = 1; off < 64; off <<= 1) {
    s += __shfl_xor(s, off);
    q += __shfl_xor(q, off);
  }
  __shared__ float ss[4], qq[4];
  if ((tid & 63) == 0) { ss[tid >> 6] = s; qq[tid >> 6] = q; }
  __syncthreads();
  s = ss[0] + ss[1] + ss[2] + ss[3];
  q = qq[0] + qq[1] + qq[2] + qq[3];
  float mu = s * (1.f / 1024.f);
  float var = q * (1.f / 1024.f) - mu * mu;
  float rstd = rsqrtf(var + 1e-5f);
  int c0 = tid * 4;
  float4 g = *(const float4*)&ln_g[c0];
  float4 bb = *(const float4*)&ln_b[c0];
  float4 o;
  o.x = (v.x - mu) * rstd * g.x + bb.x;
  o.y = (v.y - mu) * rstd * g.y + bb.y;
  o.z = (v.z - mu) * rstd * g.z + bb.z;
  o.w = (v.w - mu) * rstd * g.w + bb.w;
  *(float4*)&out[(size_t)row * Cc + c0] = o;
}

extern "C" void kernel_launch(void* const* d_in, const int* in_sizes, int n_in,
                              void* d_out, int out_size, void* d_ws, size_t ws_size,
                              hipStream_t stream) {
  const float* x        = (const float*)d_in[0];
  const float* q_w      = (const float*)d_in[1];
  const float* k_w      = (const float*)d_in[2];
  const float* v_w      = (const float*)d_in[3];
  const float* out_w    = (const float*)d_in[4];
  const float* out_b    = (const float*)d_in[5];
  const float* decay_w  = (const float*)d_in[6];
  const float* decay_b  = (const float*)d_in[7];
  const float* gate_w   = (const float*)d_in[8];
  const float* gate_b   = (const float*)d_in[9];
  const float* decay_w0 = (const float*)d_in[10];
  const float* ln_g     = (const float*)d_in[11];
  const float* ln_b     = (const float*)d_in[12];
  float* out            = (float*)d_out;   // reference output dtype = float32

  const size_t MC  = (size_t)Mc * Cc;      // 4,194,304 elements
  const size_t BHT = (size_t)Bc * Hc * Tc; // 65,536
  const int NBH = Bc * Hc;                 // 32
  dim3 gg(Cc / 128, Mc / 128);

  const bool fp32path = ws_size >= (size_t)52 * 1024 * 1024;

  if (fp32path) {
    // ---- 51.6 MiB layout: fp32 intermediates, bf16 chunk summaries ----
    float* tabC  = (float*)d_ws;
    float* tabS  = tabC + (size_t)Tc * 32;
    float* phiQ  = tabS + (size_t)Tc * 32;
    float* phiK  = phiQ + MC;
    float* VY    = phiK + MC;              // V -> num -> Y, all in place
    float* betaB = VY + MC;
    float* gateB = betaB + BHT;
    float* denB  = gateB + BHT;
    float* aB    = denB + BHT;
    unsigned short* S = (unsigned short*)(aB + BHT);          // [32*NCc][64][64] bf16
    float* Dsum  = (float*)(S + (size_t)NBH * NCc * 4096);    // [32*NCc][64]
    float* Pbuf  = Dsum + (size_t)NBH * NCc * 64;             // [32*NCc]
    float* preO  = phiK;                   // phiK dead after scan

    k_tables<<<(Tc * 32) / 256, 256, 0, stream>>>(tabC, tabS);
    k_gemm128<float, float, 1><<<gg, 256, 0, stream>>>(x, q_w, phiQ, Mc, Cc, Cc, tabC, tabS, nullptr, nullptr);
    k_gemm128<float, float, 1><<<gg, 256, 0, stream>>>(x, k_w, phiK, Mc, Cc, Cc, tabC, tabS, nullptr, nullptr);
    k_gemm128<float, float, 0><<<gg, 256, 0, stream>>>(x, v_w, VY, Mc, Cc, Cc, nullptr, nullptr, nullptr, nullptr);
    k_small<<<Mc, 256, 0, stream>>>(x, gate_w, gate_b, decay_w, decay_b, decay_w0, gateB, betaB);

    k_scanA<<<NBH * NCc, 256, 0, stream>>>(phiQ, phiK, VY, betaB, gateB, denB, aB, S, Dsum, Pbuf);
    k_scanB<<<NBH, 256, 0, stream>>>(S, Dsum, Pbuf);
    k_scanC<<<NBH * NCc, 256, 0, stream>>>(phiQ, S, Dsum, denB, aB, VY);

    k_gemm128<float, float, 2><<<gg, 256, 0, stream>>>(VY, out_w, preO, Mc, Cc, Cc, nullptr, nullptr, out_b, x);
    k_ln<<<Mc, 256, 0, stream>>>(preO, ln_g, ln_b, out);
  } else {
    // ---- 33 MiB bf16-intermediate fallback (serial scan) ----
    float* tabC  = (float*)d_ws;
    float* tabS  = tabC + (size_t)Tc * 32;
    unsigned short* phiQb = (unsigned short*)(tabS + (size_t)Tc * 32);
    unsigned short* phiKb = phiQb + MC;
    unsigned short* Vbb   = phiKb + MC;
    unsigned short* Ybb   = Vbb + MC;
    float* betaB = (float*)(Ybb + MC);
    float* gateB = betaB + BHT;
    float* preO  = (float*)phiQb;

    k_tables<<<(Tc * 32) / 256, 256, 0, stream>>>(tabC, tabS);
    k_gemm128<float, unsigned short, 1><<<gg, 256, 0, stream>>>(x, q_w, phiQb, Mc, Cc, Cc, tabC, tabS, nullptr, nullptr);
    k_gemm128<float, unsigned short, 1><<<gg, 256, 0, stream>>>(x, k_w, phiKb, Mc, Cc, Cc, tabC, tabS, nullptr, nullptr);
    k_gemm128<float, unsigned short, 0><<<gg, 256, 0, stream>>>(x, v_w, Vbb, Mc, Cc, Cc, nullptr, nullptr, nullptr, nullptr);
    k_small<<<Mc, 256, 0, stream>>>(x, gate_w, gate_b, decay_w, decay_b, decay_w0, gateB, betaB);
    k_scan<unsigned short><<<Bc * Hc, 256, 0, stream>>>(phiQb, phiKb, Vbb, betaB, gateB, Ybb);
    k_gemm128<unsigned short, float, 2><<<gg, 256, 0, stream>>>(Ybb, out_w, preO, Mc, Cc, Cc, nullptr, nullptr, out_b, x);
    k_ln<<<Mc, 256, 0, stream>>>(preO, ln_g, ln_b, out);
  }
}

// Round 5
// 490.690 us; speedup vs baseline: 3.5612x; 1.8995x over previous
//
#include <hip/hip_runtime.h>
#include <hip/hip_bf16.h>
#include <math.h>

static constexpr int Bc = 2, Tc = 2048, Cc = 1024, Hc = 16;
static constexpr int Mc = Bc * Tc;  // 4096 rows
static constexpr int NCc = 8, Lc = 256;  // chunks per (b,h), chunk length

typedef __attribute__((ext_vector_type(8))) short bf16x8;
typedef __attribute__((ext_vector_type(4))) float f32x4;

// ---------- dtype helpers ----------
__device__ __forceinline__ float bf2f(unsigned short u) {
  return __uint_as_float((unsigned)u << 16);
}
__device__ __forceinline__ unsigned short f2bf(float f) {
  __hip_bfloat16 h = __float2bfloat16(f);
  return *(unsigned short*)&h;
}
__device__ __forceinline__ float4 ld4(const float* p) { return *(const float4*)p; }
__device__ __forceinline__ float4 ld4(const unsigned short* p) {
  ushort4 u = *(const ushort4*)p;
  return make_float4(bf2f(u.x), bf2f(u.y), bf2f(u.z), bf2f(u.w));
}
__device__ __forceinline__ void stv(float* p, float v) { *p = v; }
__device__ __forceinline__ void stv(unsigned short* p, float v) { *p = f2bf(v); }
__device__ __forceinline__ float ldsc(const float* p) { return *p; }
__device__ __forceinline__ float ldsc(const unsigned short* p) { return bf2f(*p); }

// ---------------- RoPE tables ----------------
__global__ __launch_bounds__(256) void k_tables(float* __restrict__ tc, float* __restrict__ ts) {
  int i = blockIdx.x * 256 + threadIdx.x;       // < Tc*32
  int t = i >> 5, f = i & 31;
  float ivf = 1.0f / powf(10000.f, (float)f / 32.f);
  float fr = (float)t * ivf;
  tc[i] = cosf(fr);
  ts[i] = sinf(fr);
}

__device__ __forceinline__ float phi_fn(float x) { return x > 0.f ? x + 1.f : __expf(x); }

// ---------------- fp32 -> bf16 convert (x) ----------------
__global__ __launch_bounds__(256) void k_cvtx(const float* __restrict__ src, unsigned short* __restrict__ dst) {
  int i = blockIdx.x * 256 + threadIdx.x;   // 8 elems each
  float4 a = *(const float4*)&src[(size_t)i * 8];
  float4 b = *(const float4*)&src[(size_t)i * 8 + 4];
  ushort4 u0 = make_ushort4(f2bf(a.x), f2bf(a.y), f2bf(a.z), f2bf(a.w));
  ushort4 u1 = make_ushort4(f2bf(b.x), f2bf(b.y), f2bf(b.z), f2bf(b.w));
  *(ushort4*)&dst[(size_t)i * 8] = u0;
  *(ushort4*)&dst[(size_t)i * 8 + 4] = u1;
}

// ---------------- W[K][N] fp32 -> WT[N][K] bf16, 4 weights via blockIdx.z ----------------
__global__ __launch_bounds__(256) void k_trans(
    const float* __restrict__ w0, const float* __restrict__ w1,
    const float* __restrict__ w2, const float* __restrict__ w3,
    unsigned short* __restrict__ o0, unsigned short* __restrict__ o1,
    unsigned short* __restrict__ o2, unsigned short* __restrict__ o3) {
  const float* W = (blockIdx.z == 0) ? w0 : (blockIdx.z == 1) ? w1 : (blockIdx.z == 2) ? w2 : w3;
  unsigned short* O = (blockIdx.z == 0) ? o0 : (blockIdx.z == 1) ? o1 : (blockIdx.z == 2) ? o2 : o3;
  __shared__ float tile[32][33];
  int k0 = blockIdx.x * 32, n0 = blockIdx.y * 32;
  int t = threadIdx.x;
  int kk = t >> 3, nn4 = (t & 7) * 4;
  float4 v = *(const float4*)&W[(size_t)(k0 + kk) * Cc + n0 + nn4];
  tile[kk][nn4] = v.x; tile[kk][nn4 + 1] = v.y; tile[kk][nn4 + 2] = v.z; tile[kk][nn4 + 3] = v.w;
  __syncthreads();
  int nn = t >> 3, kk4 = (t & 7) * 4;
  ushort4 o = make_ushort4(f2bf(tile[kk4][nn]), f2bf(tile[kk4 + 1][nn]),
                           f2bf(tile[kk4 + 2][nn]), f2bf(tile[kk4 + 3][nn]));
  *(ushort4*)&O[(size_t)(n0 + nn) * Cc + k0 + kk4] = o;
}

// ---------------- bf16 MFMA GEMM: A[M][K] bf16 row-major, BT[N][K] bf16 row-major ----------------
// 128x128 tile, BK=32, 4 waves (2x2), each wave 64x64 = 4x4 frags of 16x16x32.
// MODE 0: fp32 store   MODE 1: RoPE+phi -> bf16 store   MODE 2: +bias+resid -> fp32 store
static constexpr int LDP = 40;  // padded LDS row pitch in shorts (80 B): row*20 mod 32 spreads banks
template <typename OT, int MODE>
__global__ __launch_bounds__(256) void k_mfma(
    const unsigned short* __restrict__ A, const unsigned short* __restrict__ BT,
    OT* __restrict__ Co,
    const float* __restrict__ tabC, const float* __restrict__ tabS,
    const float* __restrict__ bias, const float* __restrict__ resid) {
  constexpr int K = Cc, N = Cc;
  __shared__ unsigned short As[128 * LDP];
  __shared__ unsigned short Bs[128 * LDP];
  const int tid = threadIdx.x;
  const int n0 = blockIdx.x * 128, m0 = blockIdx.y * 128;
  const int l = tid & 63, w = tid >> 6;
  const int wr = w >> 1, wc = w & 1;           // wave 64x64 sub-tile
  const int lrow = l & 15, lk = (l >> 4) * 8;  // frag lane mapping

  f32x4 acc[4][4];
#pragma unroll
  for (int i = 0; i < 4; ++i)
#pragma unroll
    for (int j = 0; j < 4; ++j) acc[i][j] = (f32x4){0.f, 0.f, 0.f, 0.f};

  const int srow = tid >> 1, shalf = tid & 1;  // staging: row 0..127, 16-col half
  const size_t abase = (size_t)(m0 + srow) * K + shalf * 16;
  const size_t bbase = (size_t)(n0 + srow) * K + shalf * 16;
  const int sdst = srow * LDP + shalf * 16;

  for (int k0 = 0; k0 < K; k0 += 32) {
    uint4 a0 = *(const uint4*)&A[abase + k0];
    uint4 a1 = *(const uint4*)&A[abase + k0 + 8];
    uint4 b0 = *(const uint4*)&BT[bbase + k0];
    uint4 b1 = *(const uint4*)&BT[bbase + k0 + 8];
    __syncthreads();
    *(uint4*)&As[sdst] = a0;
    *(uint4*)&As[sdst + 8] = a1;
    *(uint4*)&Bs[sdst] = b0;
    *(uint4*)&Bs[sdst + 8] = b1;
    __syncthreads();
    bf16x8 af[4], bf[4];
#pragma unroll
    for (int fm = 0; fm < 4; ++fm)
      af[fm] = *(const bf16x8*)&As[(wr * 64 + fm * 16 + lrow) * LDP + lk];
#pragma unroll
    for (int fn = 0; fn < 4; ++fn)
      bf[fn] = *(const bf16x8*)&Bs[(wc * 64 + fn * 16 + lrow) * LDP + lk];
#pragma unroll
    for (int fm = 0; fm < 4; ++fm)
#pragma unroll
      for (int fn = 0; fn < 4; ++fn)
        acc[fm][fn] = __builtin_amdgcn_mfma_f32_16x16x32_bf16(af[fm], bf[fn], acc[fm][fn], 0, 0, 0);
  }

  // epilogue: D[row = 4*(l>>4)+r (+16*fm +64*wr +m0)][col = (l&15) (+16*fn +64*wc +n0)]
#pragma unroll
  for (int fm = 0; fm < 4; ++fm) {
#pragma unroll
    for (int fn = 0; fn < 4; ++fn) {
#pragma unroll
      for (int r = 0; r < 4; ++r) {
        float v = acc[fm][fn][r];
        int row = m0 + wr * 64 + fm * 16 + (l >> 4) * 4 + r;
        int col = n0 + wc * 64 + fn * 16 + (l & 15);
        if constexpr (MODE == 1) {
          float p = __shfl_xor(v, 1);
          int t = row & (Tc - 1);
          int pi = (col & 63) >> 1;
          float cv = tabC[t * 32 + pi], sv = tabS[t * 32 + pi];
          float res = (col & 1) ? (p * sv + v * cv) : (v * cv - p * sv);
          stv(&Co[(size_t)row * N + col], phi_fn(res));
        } else if constexpr (MODE == 2) {
          stv(&Co[(size_t)row * N + col], v + bias[col] + resid[(size_t)row * N + col]);
        } else {
          stv(&Co[(size_t)row * N + col], v);
        }
      }
    }
  }
}

// ---------------- legacy fp32 SIMT GEMM (fallback path) ----------------
template <typename AT, typename OT, int MODE>
__global__ __launch_bounds__(256) void k_gemm128(
    const AT* __restrict__ A, const float* __restrict__ Bw, OT* __restrict__ Co,
    int M, int N, int K,
    const float* __restrict__ tabC, const float* __restrict__ tabS,
    const float* __restrict__ bias, const float* __restrict__ resid) {
  __shared__ float As[16][132];
  __shared__ float Bs[16][132];
  const int tid = threadIdx.x;
  const int tx = tid & 15, ty = tid >> 4;
  const int n0 = blockIdx.x * 128, m0 = blockIdx.y * 128;

  float acc[8][8];
#pragma unroll
  for (int i = 0; i < 8; ++i)
#pragma unroll
    for (int j = 0; j < 8; ++j) acc[i][j] = 0.f;

  for (int k0 = 0; k0 < K; k0 += 16) {
#pragma unroll
    for (int rep = 0; rep < 2; ++rep) {
      int lin = tid + rep * 256;
      int r = lin >> 2, c4 = (lin & 3) << 2;
      float4 av = ld4(&A[(size_t)(m0 + r) * K + k0 + c4]);
      As[c4 + 0][r] = av.x; As[c4 + 1][r] = av.y;
      As[c4 + 2][r] = av.z; As[c4 + 3][r] = av.w;
      int rb = lin >> 5, cb = (lin & 31) << 2;
      *(float4*)&Bs[rb][cb] = *(const float4*)&Bw[(size_t)(k0 + rb) * N + n0 + cb];
    }
    __syncthreads();
#pragma unroll
    for (int kk = 0; kk < 16; ++kk) {
      float4 a0 = *(const float4*)&As[kk][ty * 8];
      float4 a1 = *(const float4*)&As[kk][ty * 8 + 4];
      float4 b0 = *(const float4*)&Bs[kk][tx * 8];
      float4 b1 = *(const float4*)&Bs[kk][tx * 8 + 4];
      float avv[8] = {a0.x, a0.y, a0.z, a0.w, a1.x, a1.y, a1.z, a1.w};
      float bvv[8] = {b0.x, b0.y, b0.z, b0.w, b1.x, b1.y, b1.z, b1.w};
#pragma unroll
      for (int i = 0; i < 8; ++i)
#pragma unroll
        for (int j = 0; j < 8; ++j) acc[i][j] = fmaf(avv[i], bvv[j], acc[i][j]);
    }
    __syncthreads();
  }

  if constexpr (MODE == 1) {
#pragma unroll
    for (int i = 0; i < 8; ++i) {
      int row = m0 + ty * 8 + i;
      int t = row & (Tc - 1);
#pragma unroll
      for (int j = 0; j < 8; j += 2) {
        int col = n0 + tx * 8 + j;
        int pi = (col & 63) >> 1;
        float cv = tabC[t * 32 + pi], sv = tabS[t * 32 + pi];
        float xe = acc[i][j], xo = acc[i][j + 1];
        float re = xe * cv - xo * sv;
        float ro = xe * sv + xo * cv;
        stv(&Co[(size_t)row * N + col], phi_fn(re));
        stv(&Co[(size_t)row * N + col + 1], phi_fn(ro));
      }
    }
  } else if constexpr (MODE == 2) {
#pragma unroll
    for (int i = 0; i < 8; ++i) {
      int row = m0 + ty * 8 + i;
#pragma unroll
      for (int j = 0; j < 8; ++j) {
        int col = n0 + tx * 8 + j;
        float v = acc[i][j] + bias[col] + resid[(size_t)row * N + col];
        stv(&Co[(size_t)row * N + col], v);
      }
    }
  } else {
#pragma unroll
    for (int i = 0; i < 8; ++i) {
      int row = m0 + ty * 8 + i;
#pragma unroll
      for (int j = 0; j < 8; ++j) {
        int col = n0 + tx * 8 + j;
        stv(&Co[(size_t)row * N + col], acc[i][j]);
      }
    }
  }
}

// ---------------- gate / decay projections (N=32) ----------------
__global__ __launch_bounds__(256) void k_small(
    const float* __restrict__ x, const float* __restrict__ gate_w, const float* __restrict__ gate_b,
    const float* __restrict__ decay_w, const float* __restrict__ decay_b,
    const float* __restrict__ decay_w0, float* __restrict__ gate_o, float* __restrict__ beta_o) {
  __shared__ float xs[1024];
  __shared__ float part[8][32];
  int bt = blockIdx.x;
  int tid = threadIdx.x;
  *(float4*)&xs[tid * 4] = *(const float4*)&x[(size_t)bt * Cc + tid * 4];
  __syncthreads();
  int o = tid & 31, seg = tid >> 5;
  const float* wp = (o < 16) ? gate_w : decay_w;
  int oc = o & 15;
  float p = 0.f;
  int kb = seg * 128;
#pragma unroll 4
  for (int kk = 0; kk < 128; ++kk) {
    int k = kb + kk;
    p = fmaf(xs[k], wp[(size_t)k * 16 + oc], p);
  }
  part[seg][o] = p;
  __syncthreads();
  if (tid < 32) {
    float s = 0.f;
#pragma unroll
    for (int sg = 0; sg < 8; ++sg) s += part[sg][tid];
    int b = bt >> 11, t = bt & (Tc - 1);
    if (tid < 16) {
      float gv = 1.f / (1.f + expf(-(s + gate_b[tid])));
      gate_o[((size_t)(b * Hc + tid)) * Tc + t] = gv;
    } else {
      int hh = tid - 16;
      float raw = s + decay_b[hh] + decay_w0[hh];
      float sp = raw > 20.f ? raw : log1pf(expf(raw));
      float rate = fminf(fmaxf(sp, 1e-4f), 10.f);
      beta_o[((size_t)(b * Hc + hh)) * Tc + t] = expf(-rate);
    }
  }
}

// ---------------- shared scan helpers ----------------
__device__ __forceinline__ void load16(const float* __restrict__ p, float* d) {
  float4 a = *(const float4*)p, b = *(const float4*)(p + 4);
  float4 c = *(const float4*)(p + 8), e = *(const float4*)(p + 12);
  d[0] = a.x; d[1] = a.y; d[2] = a.z; d[3] = a.w;
  d[4] = b.x; d[5] = b.y; d[6] = b.z; d[7] = b.w;
  d[8] = c.x; d[9] = c.y; d[10] = c.z; d[11] = c.w;
  d[12] = e.x; d[13] = e.y; d[14] = e.z; d[15] = e.w;
}
__device__ __forceinline__ void load16(const unsigned short* __restrict__ p, float* d) {
  uint4 u = *(const uint4*)p;
  uint4 v = *(const uint4*)(p + 8);
  d[0] = __uint_as_float(u.x << 16); d[1] = __uint_as_float(u.x & 0xFFFF0000u);
  d[2] = __uint_as_float(u.y << 16); d[3] = __uint_as_float(u.y & 0xFFFF0000u);
  d[4] = __uint_as_float(u.z << 16); d[5] = __uint_as_float(u.z & 0xFFFF0000u);
  d[6] = __uint_as_float(u.w << 16); d[7] = __uint_as_float(u.w & 0xFFFF0000u);
  d[8] = __uint_as_float(v.x << 16); d[9] = __uint_as_float(v.x & 0xFFFF0000u);
  d[10] = __uint_as_float(v.y << 16); d[11] = __uint_as_float(v.y & 0xFFFF0000u);
  d[12] = __uint_as_float(v.z << 16); d[13] = __uint_as_float(v.z & 0xFFFF0000u);
  d[14] = __uint_as_float(v.w << 16); d[15] = __uint_as_float(v.w & 0xFFFF0000u);
}

template <typename ET>
__device__ __forceinline__ void load_step(const ET* __restrict__ qp, const ET* __restrict__ kp,
    const ET* __restrict__ vp, const float* __restrict__ bp, const float* __restrict__ gp,
    int t, float* q, float* k, float& vv, float& btv, float& gtv) {
  size_t off = (size_t)t * Cc;
  load16(qp + off, q);
  load16(kp + off, k);
  vv = ldsc(vp + off);
  btv = bp[t];
  gtv = gp[t];
}

// mixed: q/k bf16, v fp32
__device__ __forceinline__ void load_stepM(const unsigned short* __restrict__ qp,
    const unsigned short* __restrict__ kp, const float* __restrict__ vp,
    const float* __restrict__ bp, const float* __restrict__ gp,
    int t, float* q, float* k, float& vv, float& btv, float& gtv) {
  size_t off = (size_t)t * Cc;
  load16(qp + off, q);
  load16(kp + off, k);
  vv = vp[off];
  btv = bp[t];
  gtv = gp[t];
}

// yn/den returned UNDIVIDED
__device__ __forceinline__ void do_step2(const float* q, const float* k, float vv, float btv, float gtv,
                                         float* Ns, float* Ds, float& ynO, float& denO) {
  float yn = 0.f, den = 0.f;
#pragma unroll
  for (int j = 0; j < 16; ++j) {
    float wj = k[j] * gtv;
    float ns = fmaf(Ns[j], btv, wj * vv);
    float ds = fmaf(Ds[j], btv, wj);
    Ns[j] = ns; Ds[j] = ds;
    yn = fmaf(q[j], ns, yn);
    den = fmaf(q[j], ds, den);
  }
  yn += __shfl_xor(yn, 16); yn += __shfl_xor(yn, 32);
  den += __shfl_xor(den, 16); den += __shfl_xor(den, 32);
  ynO = yn; denO = den;
}

// ---------------- Phase A: per-chunk local scan (zero start state) ----------------
__global__ __launch_bounds__(256) void k_scanA(const unsigned short* __restrict__ phiQ,
    const unsigned short* __restrict__ phiK,
    float* __restrict__ VY, const float* __restrict__ betaB, const float* __restrict__ gateB,
    float* __restrict__ denB, float* __restrict__ aB,
    unsigned short* __restrict__ S, float* __restrict__ Dsum, float* __restrict__ Pbuf) {
  int blk = blockIdx.x;
  int bh = blk >> 3, c = blk & (NCc - 1);
  int b = bh >> 4, h = bh & 15;
  int tid = threadIdx.x;
  int w = tid >> 6, l = tid & 63;
  int e = (w << 4) | (l & 15);
  int d0 = (l >> 4) << 4;
  size_t base = ((size_t)b * Tc + (size_t)c * Lc) * Cc + h * 64;
  const unsigned short* qp = phiQ + base + d0;
  const unsigned short* kp = phiK + base + d0;
  const float* vp = VY + base + e;
  const float* bp = betaB + (size_t)bh * Tc + c * Lc;
  const float* gp = gateB + (size_t)bh * Tc + c * Lc;
  float* np = VY + base + e;
  float* dnp = denB + (size_t)bh * Tc + c * Lc;
  float* ap = aB + (size_t)bh * Tc + c * Lc;

  float Ns[16], Ds[16];
#pragma unroll
  for (int j = 0; j < 16; ++j) { Ns[j] = 0.f; Ds[j] = 0.f; }
  float aprod = 1.f;
  float qA[16], kA[16], vA, btA, gtA;
  float qB[16], kB[16], vB, btB, gtB;
  load_stepM(qp, kp, vp, bp, gp, 0, qA, kA, vA, btA, gtA);
  load_stepM(qp, kp, vp, bp, gp, 1, qB, kB, vB, btB, gtB);
  const bool wr = (l < 16);
  for (int t = 0; t < Lc; t += 2) {
    float yn, den;
    do_step2(qA, kA, vA, btA, gtA, Ns, Ds, yn, den);
    aprod *= btA;
    if (wr) np[(size_t)t * Cc] = yn;
    if (tid == 0) { dnp[t] = den; ap[t] = aprod; }
    if (t + 2 < Lc) load_stepM(qp, kp, vp, bp, gp, t + 2, qA, kA, vA, btA, gtA);
    do_step2(qB, kB, vB, btB, gtB, Ns, Ds, yn, den);
    aprod *= btB;
    if (wr) np[(size_t)(t + 1) * Cc] = yn;
    if (tid == 0) { dnp[t + 1] = den; ap[t + 1] = aprod; }
    if (t + 3 < Lc) load_stepM(qp, kp, vp, bp, gp, t + 3, qB, kB, vB, btB, gtB);
  }
  size_t sbase = (size_t)blk * 4096;
#pragma unroll
  for (int j = 0; j < 16; ++j)
    S[sbase + (size_t)(d0 + j) * 64 + e] = f2bf(Ns[j]);
  if (w == 0 && (l & 15) == 0) {
#pragma unroll
    for (int j = 0; j < 16; ++j) Dsum[(size_t)blk * 64 + d0 + j] = Ds[j];
  }
  if (tid == 0) Pbuf[blk] = aprod;
}

// ---------------- Phase B: serial carry across chunks ----------------
__global__ __launch_bounds__(256) void k_scanB(unsigned short* __restrict__ S, float* __restrict__ Dsum,
                                               const float* __restrict__ Pbuf) {
  int bh = blockIdx.x;
  int tid = threadIdx.x;
  float Nreg[16];
#pragma unroll
  for (int k = 0; k < 16; ++k) Nreg[k] = 0.f;
  float Dreg = 0.f;
  for (int c = 0; c < NCc; ++c) {
    size_t sb = ((size_t)bh * NCc + c) * 4096;
    float Pc = Pbuf[bh * NCc + c];
#pragma unroll
    for (int k = 0; k < 16; ++k) {
      size_t f = sb + tid + k * 256;
      float tmp = bf2f(S[f]);
      S[f] = f2bf(Nreg[k]);
      Nreg[k] = Nreg[k] * Pc + tmp;
    }
    if (tid < 64) {
      size_t db = ((size_t)bh * NCc + c) * 64 + tid;
      float tmp = Dsum[db];
      Dsum[db] = Dreg;
      Dreg = Dreg * Pc + tmp;
    }
  }
}

// ---------------- Phase C: apply start-state correction + division -> Ybf (bf16) ----------------
__global__ __launch_bounds__(256) void k_scanC(const unsigned short* __restrict__ phiQ,
    const unsigned short* __restrict__ S, const float* __restrict__ Dsum,
    const float* __restrict__ denB, const float* __restrict__ aB,
    const float* __restrict__ VY, unsigned short* __restrict__ Ybf) {
  int blk = blockIdx.x;
  int bh = blk >> 3, c = blk & (NCc - 1);
  int b = bh >> 4, h = bh & 15;
  int tid = threadIdx.x;
  int w = tid >> 6, l = tid & 63;
  int e = (w << 4) | (l & 15);
  int d0 = (l >> 4) << 4;
  size_t sbase = (size_t)blk * 4096;
  float Nst[16], Dst[16];
#pragma unroll
  for (int j = 0; j < 16; ++j) {
    Nst[j] = bf2f(S[sbase + (size_t)(d0 + j) * 64 + e]);
    Dst[j] = Dsum[(size_t)blk * 64 + d0 + j];
  }
  size_t base = ((size_t)b * Tc + (size_t)c * Lc) * Cc + h * 64;
  const unsigned short* qp = phiQ + base + d0;
  const float* aP = aB + (size_t)bh * Tc + c * Lc;
  const float* dP = denB + (size_t)bh * Tc + c * Lc;
  const float* np = VY + base + e;
  unsigned short* yp = Ybf + base + e;
  const bool wr = (l < 16);
  for (int t = 0; t < Lc; ++t) {
    float q[16];
    load16(qp + (size_t)t * Cc, q);
    float acc = 0.f, dac = 0.f;
#pragma unroll
    for (int j = 0; j < 16; ++j) {
      acc = fmaf(q[j], Nst[j], acc);
      dac = fmaf(q[j], Dst[j], dac);
    }
    acc += __shfl_xor(acc, 16); acc += __shfl_xor(acc, 32);
    dac += __shfl_xor(dac, 16); dac += __shfl_xor(dac, 32);
    if (wr) {
      float a = aP[t], den = dP[t];
      float num = np[(size_t)t * Cc];
      yp[(size_t)t * Cc] = f2bf((num + a * acc) / (den + a * dac + 1e-6f));
    }
  }
}

// ---------------- legacy serial scan (fallback path only) ----------------
__device__ __forceinline__ float do_step(const float* q, const float* k, float vv, float btv, float gtv,
                                         float* Ns, float* Ds) {
  float yn, den;
  do_step2(q, k, vv, btv, gtv, Ns, Ds, yn, den);
  return yn / (den + 1e-6f);
}

template <typename ET>
__global__ __launch_bounds__(256) void k_scan(const ET* __restrict__ phiQ, const ET* __restrict__ phiK,
    const ET* __restrict__ Vb, const float* __restrict__ betaB, const float* __restrict__ gateB,
    ET* __restrict__ Yb) {
  int bh = blockIdx.x;
  int b = bh >> 4, h = bh & 15;
  int tid = threadIdx.x;
  int w = tid >> 6, l = tid & 63;
  int e = (w << 4) | (l & 15);
  int d0 = (l >> 4) << 4;
  size_t base = ((size_t)b * Tc) * Cc + h * 64;
  const ET* qp = phiQ + base + d0;
  const ET* kp = phiK + base + d0;
  const ET* vp = Vb + base + e;
  const float* bp = betaB + (size_t)bh * Tc;
  const float* gp = gateB + (size_t)bh * Tc;
  ET* yp = Yb + base + e;

  float Ns[16], Ds[16];
#pragma unroll
  for (int j = 0; j < 16; ++j) { Ns[j] = 0.f; Ds[j] = 0.f; }
  float qA[16], kA[16], vA, btA, gtA;
  float qB[16], kB[16], vB, btB, gtB;
  load_step(qp, kp, vp, bp, gp, 0, qA, kA, vA, btA, gtA);
  load_step(qp, kp, vp, bp, gp, 1, qB, kB, vB, btB, gtB);
  const bool wr = (l < 16);
  for (int t = 0; t < Tc; t += 2) {
    float y0 = do_step(qA, kA, vA, btA, gtA, Ns, Ds);
    if (wr) stv(yp + (size_t)t * Cc, y0);
    if (t + 2 < Tc) load_step(qp, kp, vp, bp, gp, t + 2, qA, kA, vA, btA, gtA);
    float y1 = do_step(qB, kB, vB, btB, gtB, Ns, Ds);
    if (wr) stv(yp + (size_t)(t + 1) * Cc, y1);
    if (t + 3 < Tc) load_step(qp, kp, vp, bp, gp, t + 3, qB, kB, vB, btB, gtB);
  }
}

// ---------------- row LayerNorm -> fp32 out ----------------
__global__ __launch_bounds__(256) void k_ln(const float* __restrict__ pre, const float* __restrict__ ln_g,
    const float* __restrict__ ln_b, float* __restrict__ out) {
  int row = blockIdx.x;
  int tid = threadIdx.x;
  float4 v = *(const float4*)&pre[(size_t)row * Cc + tid * 4];
  float s = v.x + v.y + v.z + v.w;
  float q = v.x * v.x + v.y * v.y + v.z * v.z + v.w * v.w;
#pragma unroll
  for (int off = 1; off < 64; off <<= 1) {
    s += __shfl_xor(s, off);
    q += __shfl_xor(q, off);
  }
  __shared__ float ss[4], qq[4];
  if ((tid & 63) == 0) { ss[tid >> 6] = s; qq[tid >> 6] = q; }
  __syncthreads();
  s = ss[0] + ss[1] + ss[2] + ss[3];
  q = qq[0] + qq[1] + qq[2] + qq[3];
  float mu = s * (1.f / 1024.f);
  float var = q * (1.f / 1024.f) - mu * mu;
  float rstd = rsqrtf(var + 1e-5f);
  int c0 = tid * 4;
  float4 g = *(const float4*)&ln_g[c0];
  float4 bb = *(const float4*)&ln_b[c0];
  float4 o;
  o.x = (v.x - mu) * rstd * g.x + bb.x;
  o.y = (v.y - mu) * rstd * g.y + bb.y;
  o.z = (v.z - mu) * rstd * g.z + bb.z;
  o.w = (v.w - mu) * rstd * g.w + bb.w;
  *(float4*)&out[(size_t)row * Cc + c0] = o;
}

extern "C" void kernel_launch(void* const* d_in, const int* in_sizes, int n_in,
                              void* d_out, int out_size, void* d_ws, size_t ws_size,
                              hipStream_t stream) {
  const float* x        = (const float*)d_in[0];
  const float* q_w      = (const float*)d_in[1];
  const float* k_w      = (const float*)d_in[2];
  const float* v_w      = (const float*)d_in[3];
  const float* out_w    = (const float*)d_in[4];
  const float* out_b    = (const float*)d_in[5];
  const float* decay_w  = (const float*)d_in[6];
  const float* decay_b  = (const float*)d_in[7];
  const float* gate_w   = (const float*)d_in[8];
  const float* gate_b   = (const float*)d_in[9];
  const float* decay_w0 = (const float*)d_in[10];
  const float* ln_g     = (const float*)d_in[11];
  const float* ln_b     = (const float*)d_in[12];
  float* out            = (float*)d_out;   // reference output dtype = float32

  const size_t MC  = (size_t)Mc * Cc;      // 4,194,304 elements
  const size_t BHT = (size_t)Bc * Hc * Tc; // 65,536
  const int NBH = Bc * Hc;                 // 32
  dim3 gg(Cc / 128, Mc / 128);

  const bool fp32path = ws_size >= (size_t)52 * 1024 * 1024;

  if (fp32path) {
    // ---- ~44 MiB layout: bf16 GEMM operands/phi, fp32 num/den ----
    char* p = (char*)d_ws;
    float* tabC = (float*)p;                 p += (size_t)Tc * 32 * 4;
    float* tabS = (float*)p;                 p += (size_t)Tc * 32 * 4;
    unsigned short* xbf   = (unsigned short*)p; p += MC * 2;
    unsigned short* qwT   = (unsigned short*)p; p += (size_t)Cc * Cc * 2;
    unsigned short* kwT   = (unsigned short*)p; p += (size_t)Cc * Cc * 2;
    unsigned short* vwT   = (unsigned short*)p; p += (size_t)Cc * Cc * 2;
    unsigned short* owT   = (unsigned short*)p; p += (size_t)Cc * Cc * 2;
    unsigned short* phiQb = (unsigned short*)p; p += MC * 2;
    unsigned short* phiKb = (unsigned short*)p; p += MC * 2;   // Ybf aliases after scanA
    float* VY    = (float*)p;                p += MC * 4;      // V -> num; preO aliases after scanC
    float* betaB = (float*)p;                p += BHT * 4;
    float* gateB = (float*)p;                p += BHT * 4;
    float* denB  = (float*)p;                p += BHT * 4;
    float* aB    = (float*)p;                p += BHT * 4;
    unsigned short* S = (unsigned short*)p;  p += (size_t)NBH * NCc * 4096 * 2;
    float* Dsum  = (float*)p;                p += (size_t)NBH * NCc * 64 * 4;
    float* Pbuf  = (float*)p;                p += (size_t)NBH * NCc * 4;
    unsigned short* Ybf = phiKb;             // phiK dead after scanA
    float* preO = VY;                        // VY dead after scanC

    k_tables<<<(Tc * 32) / 256, 256, 0, stream>>>(tabC, tabS);
    k_cvtx<<<(int)(MC / 8 / 256), 256, 0, stream>>>(x, xbf);
    k_trans<<<dim3(Cc / 32, Cc / 32, 4), 256, 0, stream>>>(q_w, k_w, v_w, out_w, qwT, kwT, vwT, owT);

    k_mfma<unsigned short, 1><<<gg, 256, 0, stream>>>(xbf, qwT, phiQb, tabC, tabS, nullptr, nullptr);
    k_mfma<unsigned short, 1><<<gg, 256, 0, stream>>>(xbf, kwT, phiKb, tabC, tabS, nullptr, nullptr);
    k_mfma<float, 0><<<gg, 256, 0, stream>>>(xbf, vwT, VY, nullptr, nullptr, nullptr, nullptr);

    k_small<<<Mc, 256, 0, stream>>>(x, gate_w, gate_b, decay_w, decay_b, decay_w0, gateB, betaB);

    k_scanA<<<NBH * NCc, 256, 0, stream>>>(phiQb, phiKb, VY, betaB, gateB, denB, aB, S, Dsum, Pbuf);
    k_scanB<<<NBH, 256, 0, stream>>>(S, Dsum, Pbuf);
    k_scanC<<<NBH * NCc, 256, 0, stream>>>(phiQb, S, Dsum, denB, aB, VY, Ybf);

    k_mfma<float, 2><<<gg, 256, 0, stream>>>(Ybf, owT, preO, nullptr, nullptr, out_b, x);
    k_ln<<<Mc, 256, 0, stream>>>(preO, ln_g, ln_b, out);
  } else {
    // ---- 33 MiB bf16-intermediate fallback (serial scan, SIMT GEMM) ----
    float* tabC  = (float*)d_ws;
    float* tabS  = tabC + (size_t)Tc * 32;
    unsigned short* phiQb = (unsigned short*)(tabS + (size_t)Tc * 32);
    unsigned short* phiKb = phiQb + MC;
    unsigned short* Vbb   = phiKb + MC;
    unsigned short* Ybb   = Vbb + MC;
    float* betaB = (float*)(Ybb + MC);
    float* gateB = betaB + BHT;
    float* preO  = (float*)phiQb;

    k_tables<<<(Tc * 32) / 256, 256, 0, stream>>>(tabC, tabS);
    k_gemm128<float, unsigned short, 1><<<gg, 256, 0, stream>>>(x, q_w, phiQb, Mc, Cc, Cc, tabC, tabS, nullptr, nullptr);
    k_gemm128<float, unsigned short, 1><<<gg, 256, 0, stream>>>(x, k_w, phiKb, Mc, Cc, Cc, tabC, tabS, nullptr, nullptr);
    k_gemm128<float, unsigned short, 0><<<gg, 256, 0, stream>>>(x, v_w, Vbb, Mc, Cc, Cc, nullptr, nullptr, nullptr, nullptr);
    k_small<<<Mc, 256, 0, stream>>>(x, gate_w, gate_b, decay_w, decay_b, decay_w0, gateB, betaB);
    k_scan<unsigned short><<<Bc * Hc, 256, 0, stream>>>(phiQb, phiKb, Vbb, betaB, gateB, Ybb);
    k_gemm128<unsigned short, float, 2><<<gg, 256, 0, stream>>>(Ybb, out_w, preO, Mc, Cc, Cc, nullptr, nullptr, out_b, x);
    k_ln<<<Mc, 256, 0, stream>>>(preO, ln_g, ln_b, out);
  }
}

// Round 6
// 291.931 us; speedup vs baseline: 5.9858x; 1.6808x over previous
//
#include <hip/hip_runtime.h>
#include <hip/hip_bf16.h>
#include <math.h>

static constexpr int Bc = 2, Tc = 2048, Cc = 1024, Hc = 16;
static constexpr int Mc = Bc * Tc;  // 4096 rows
static constexpr int NCc = 32, Lc = 64;  // chunks per (b,h), chunk length
static constexpr int SPLITC = 2, TSC = Lc / SPLITC;  // phase-C t-split

typedef __attribute__((ext_vector_type(8))) short bf16x8;
typedef __attribute__((ext_vector_type(4))) float f32x4;

// ---------- dtype helpers ----------
__device__ __forceinline__ float bf2f(unsigned short u) {
  return __uint_as_float((unsigned)u << 16);
}
__device__ __forceinline__ unsigned short f2bf(float f) {
  __hip_bfloat16 h = __float2bfloat16(f);
  return *(unsigned short*)&h;
}
__device__ __forceinline__ float4 ld4(const float* p) { return *(const float4*)p; }
__device__ __forceinline__ float4 ld4(const unsigned short* p) {
  ushort4 u = *(const ushort4*)p;
  return make_float4(bf2f(u.x), bf2f(u.y), bf2f(u.z), bf2f(u.w));
}
__device__ __forceinline__ void stv(float* p, float v) { *p = v; }
__device__ __forceinline__ void stv(unsigned short* p, float v) { *p = f2bf(v); }
__device__ __forceinline__ float ldsc(const float* p) { return *p; }
__device__ __forceinline__ float ldsc(const unsigned short* p) { return bf2f(*p); }

// ---------------- RoPE tables ----------------
__global__ __launch_bounds__(256) void k_tables(float* __restrict__ tc, float* __restrict__ ts) {
  int i = blockIdx.x * 256 + threadIdx.x;       // < Tc*32
  int t = i >> 5, f = i & 31;
  float ivf = 1.0f / powf(10000.f, (float)f / 32.f);
  float fr = (float)t * ivf;
  tc[i] = cosf(fr);
  ts[i] = sinf(fr);
}

__device__ __forceinline__ float phi_fn(float x) { return x > 0.f ? x + 1.f : __expf(x); }

// ---------------- fp32 -> bf16 convert (x) ----------------
__global__ __launch_bounds__(256) void k_cvtx(const float* __restrict__ src, unsigned short* __restrict__ dst) {
  int i = blockIdx.x * 256 + threadIdx.x;   // 8 elems each
  float4 a = *(const float4*)&src[(size_t)i * 8];
  float4 b = *(const float4*)&src[(size_t)i * 8 + 4];
  ushort4 u0 = make_ushort4(f2bf(a.x), f2bf(a.y), f2bf(a.z), f2bf(a.w));
  ushort4 u1 = make_ushort4(f2bf(b.x), f2bf(b.y), f2bf(b.z), f2bf(b.w));
  *(ushort4*)&dst[(size_t)i * 8] = u0;
  *(ushort4*)&dst[(size_t)i * 8 + 4] = u1;
}

// ---------------- W[K][N] fp32 -> WT[N][K] bf16, 4 weights via blockIdx.z ----------------
__global__ __launch_bounds__(256) void k_trans(
    const float* __restrict__ w0, const float* __restrict__ w1,
    const float* __restrict__ w2, const float* __restrict__ w3,
    unsigned short* __restrict__ o0, unsigned short* __restrict__ o1,
    unsigned short* __restrict__ o2, unsigned short* __restrict__ o3) {
  const float* W = (blockIdx.z == 0) ? w0 : (blockIdx.z == 1) ? w1 : (blockIdx.z == 2) ? w2 : w3;
  unsigned short* O = (blockIdx.z == 0) ? o0 : (blockIdx.z == 1) ? o1 : (blockIdx.z == 2) ? o2 : o3;
  __shared__ float tile[32][33];
  int k0 = blockIdx.x * 32, n0 = blockIdx.y * 32;
  int t = threadIdx.x;
  int kk = t >> 3, nn4 = (t & 7) * 4;
  float4 v = *(const float4*)&W[(size_t)(k0 + kk) * Cc + n0 + nn4];
  tile[kk][nn4] = v.x; tile[kk][nn4 + 1] = v.y; tile[kk][nn4 + 2] = v.z; tile[kk][nn4 + 3] = v.w;
  __syncthreads();
  int nn = t >> 3, kk4 = (t & 7) * 4;
  ushort4 o = make_ushort4(f2bf(tile[kk4][nn]), f2bf(tile[kk4 + 1][nn]),
                           f2bf(tile[kk4 + 2][nn]), f2bf(tile[kk4 + 3][nn]));
  *(ushort4*)&O[(size_t)(n0 + nn) * Cc + k0 + kk4] = o;
}

// ---------------- bf16 MFMA GEMM: A[M][K] bf16 row-major, BT[N][K] bf16 row-major ----------------
// 128x128 tile, BK=32, 4 waves (2x2), each wave 64x64 = 4x4 frags of 16x16x32.
// MODE 0: fp32 store   MODE 1: RoPE+phi -> bf16 store   MODE 2: +bias+resid -> fp32 store
static constexpr int LDP = 40;  // padded LDS row pitch in shorts (80 B)
template <typename OT, int MODE>
__global__ __launch_bounds__(256) void k_mfma(
    const unsigned short* __restrict__ A, const unsigned short* __restrict__ BT,
    OT* __restrict__ Co,
    const float* __restrict__ tabC, const float* __restrict__ tabS,
    const float* __restrict__ bias, const float* __restrict__ resid) {
  constexpr int K = Cc, N = Cc;
  __shared__ unsigned short As[128 * LDP];
  __shared__ unsigned short Bs[128 * LDP];
  const int tid = threadIdx.x;
  const int n0 = blockIdx.x * 128, m0 = blockIdx.y * 128;
  const int l = tid & 63, w = tid >> 6;
  const int wr = w >> 1, wc = w & 1;           // wave 64x64 sub-tile
  const int lrow = l & 15, lk = (l >> 4) * 8;  // frag lane mapping

  f32x4 acc[4][4];
#pragma unroll
  for (int i = 0; i < 4; ++i)
#pragma unroll
    for (int j = 0; j < 4; ++j) acc[i][j] = (f32x4){0.f, 0.f, 0.f, 0.f};

  const int srow = tid >> 1, shalf = tid & 1;  // staging: row 0..127, 16-col half
  const size_t abase = (size_t)(m0 + srow) * K + shalf * 16;
  const size_t bbase = (size_t)(n0 + srow) * K + shalf * 16;
  const int sdst = srow * LDP + shalf * 16;

  for (int k0 = 0; k0 < K; k0 += 32) {
    uint4 a0 = *(const uint4*)&A[abase + k0];
    uint4 a1 = *(const uint4*)&A[abase + k0 + 8];
    uint4 b0 = *(const uint4*)&BT[bbase + k0];
    uint4 b1 = *(const uint4*)&BT[bbase + k0 + 8];
    __syncthreads();
    *(uint4*)&As[sdst] = a0;
    *(uint4*)&As[sdst + 8] = a1;
    *(uint4*)&Bs[sdst] = b0;
    *(uint4*)&Bs[sdst + 8] = b1;
    __syncthreads();
    bf16x8 af[4], bf[4];
#pragma unroll
    for (int fm = 0; fm < 4; ++fm)
      af[fm] = *(const bf16x8*)&As[(wr * 64 + fm * 16 + lrow) * LDP + lk];
#pragma unroll
    for (int fn = 0; fn < 4; ++fn)
      bf[fn] = *(const bf16x8*)&Bs[(wc * 64 + fn * 16 + lrow) * LDP + lk];
#pragma unroll
    for (int fm = 0; fm < 4; ++fm)
#pragma unroll
      for (int fn = 0; fn < 4; ++fn)
        acc[fm][fn] = __builtin_amdgcn_mfma_f32_16x16x32_bf16(af[fm], bf[fn], acc[fm][fn], 0, 0, 0);
  }

#pragma unroll
  for (int fm = 0; fm < 4; ++fm) {
#pragma unroll
    for (int fn = 0; fn < 4; ++fn) {
#pragma unroll
      for (int r = 0; r < 4; ++r) {
        float v = acc[fm][fn][r];
        int row = m0 + wr * 64 + fm * 16 + (l >> 4) * 4 + r;
        int col = n0 + wc * 64 + fn * 16 + (l & 15);
        if constexpr (MODE == 1) {
          float p = __shfl_xor(v, 1);
          int t = row & (Tc - 1);
          int pi = (col & 63) >> 1;
          float cv = tabC[t * 32 + pi], sv = tabS[t * 32 + pi];
          float res = (col & 1) ? (p * sv + v * cv) : (v * cv - p * sv);
          stv(&Co[(size_t)row * N + col], phi_fn(res));
        } else if constexpr (MODE == 2) {
          stv(&Co[(size_t)row * N + col], v + bias[col] + resid[(size_t)row * N + col]);
        } else {
          stv(&Co[(size_t)row * N + col], v);
        }
      }
    }
  }
}

// ---------------- legacy fp32 SIMT GEMM (fallback path) ----------------
template <typename AT, typename OT, int MODE>
__global__ __launch_bounds__(256) void k_gemm128(
    const AT* __restrict__ A, const float* __restrict__ Bw, OT* __restrict__ Co,
    int M, int N, int K,
    const float* __restrict__ tabC, const float* __restrict__ tabS,
    const float* __restrict__ bias, const float* __restrict__ resid) {
  __shared__ float As[16][132];
  __shared__ float Bs[16][132];
  const int tid = threadIdx.x;
  const int tx = tid & 15, ty = tid >> 4;
  const int n0 = blockIdx.x * 128, m0 = blockIdx.y * 128;

  float acc[8][8];
#pragma unroll
  for (int i = 0; i < 8; ++i)
#pragma unroll
    for (int j = 0; j < 8; ++j) acc[i][j] = 0.f;

  for (int k0 = 0; k0 < K; k0 += 16) {
#pragma unroll
    for (int rep = 0; rep < 2; ++rep) {
      int lin = tid + rep * 256;
      int r = lin >> 2, c4 = (lin & 3) << 2;
      float4 av = ld4(&A[(size_t)(m0 + r) * K + k0 + c4]);
      As[c4 + 0][r] = av.x; As[c4 + 1][r] = av.y;
      As[c4 + 2][r] = av.z; As[c4 + 3][r] = av.w;
      int rb = lin >> 5, cb = (lin & 31) << 2;
      *(float4*)&Bs[rb][cb] = *(const float4*)&Bw[(size_t)(k0 + rb) * N + n0 + cb];
    }
    __syncthreads();
#pragma unroll
    for (int kk = 0; kk < 16; ++kk) {
      float4 a0 = *(const float4*)&As[kk][ty * 8];
      float4 a1 = *(const float4*)&As[kk][ty * 8 + 4];
      float4 b0 = *(const float4*)&Bs[kk][tx * 8];
      float4 b1 = *(const float4*)&Bs[kk][tx * 8 + 4];
      float avv[8] = {a0.x, a0.y, a0.z, a0.w, a1.x, a1.y, a1.z, a1.w};
      float bvv[8] = {b0.x, b0.y, b0.z, b0.w, b1.x, b1.y, b1.z, b1.w};
#pragma unroll
      for (int i = 0; i < 8; ++i)
#pragma unroll
        for (int j = 0; j < 8; ++j) acc[i][j] = fmaf(avv[i], bvv[j], acc[i][j]);
    }
    __syncthreads();
  }

  if constexpr (MODE == 1) {
#pragma unroll
    for (int i = 0; i < 8; ++i) {
      int row = m0 + ty * 8 + i;
      int t = row & (Tc - 1);
#pragma unroll
      for (int j = 0; j < 8; j += 2) {
        int col = n0 + tx * 8 + j;
        int pi = (col & 63) >> 1;
        float cv = tabC[t * 32 + pi], sv = tabS[t * 32 + pi];
        float xe = acc[i][j], xo = acc[i][j + 1];
        float re = xe * cv - xo * sv;
        float ro = xe * sv + xo * cv;
        stv(&Co[(size_t)row * N + col], phi_fn(re));
        stv(&Co[(size_t)row * N + col + 1], phi_fn(ro));
      }
    }
  } else if constexpr (MODE == 2) {
#pragma unroll
    for (int i = 0; i < 8; ++i) {
      int row = m0 + ty * 8 + i;
#pragma unroll
      for (int j = 0; j < 8; ++j) {
        int col = n0 + tx * 8 + j;
        float v = acc[i][j] + bias[col] + resid[(size_t)row * N + col];
        stv(&Co[(size_t)row * N + col], v);
      }
    }
  } else {
#pragma unroll
    for (int i = 0; i < 8; ++i) {
      int row = m0 + ty * 8 + i;
#pragma unroll
      for (int j = 0; j < 8; ++j) {
        int col = n0 + tx * 8 + j;
        stv(&Co[(size_t)row * N + col], acc[i][j]);
      }
    }
  }
}

// ---------------- gate / decay projections (N=32) ----------------
__global__ __launch_bounds__(256) void k_small(
    const float* __restrict__ x, const float* __restrict__ gate_w, const float* __restrict__ gate_b,
    const float* __restrict__ decay_w, const float* __restrict__ decay_b,
    const float* __restrict__ decay_w0, float* __restrict__ gate_o, float* __restrict__ beta_o) {
  __shared__ float xs[1024];
  __shared__ float part[8][32];
  int bt = blockIdx.x;
  int tid = threadIdx.x;
  *(float4*)&xs[tid * 4] = *(const float4*)&x[(size_t)bt * Cc + tid * 4];
  __syncthreads();
  int o = tid & 31, seg = tid >> 5;
  const float* wp = (o < 16) ? gate_w : decay_w;
  int oc = o & 15;
  float p = 0.f;
  int kb = seg * 128;
#pragma unroll 4
  for (int kk = 0; kk < 128; ++kk) {
    int k = kb + kk;
    p = fmaf(xs[k], wp[(size_t)k * 16 + oc], p);
  }
  part[seg][o] = p;
  __syncthreads();
  if (tid < 32) {
    float s = 0.f;
#pragma unroll
    for (int sg = 0; sg < 8; ++sg) s += part[sg][tid];
    int b = bt >> 11, t = bt & (Tc - 1);
    if (tid < 16) {
      float gv = 1.f / (1.f + expf(-(s + gate_b[tid])));
      gate_o[((size_t)(b * Hc + tid)) * Tc + t] = gv;
    } else {
      int hh = tid - 16;
      float raw = s + decay_b[hh] + decay_w0[hh];
      float sp = raw > 20.f ? raw : log1pf(expf(raw));
      float rate = fminf(fmaxf(sp, 1e-4f), 10.f);
      beta_o[((size_t)(b * Hc + hh)) * Tc + t] = expf(-rate);
    }
  }
}

// ---------------- shared scan helpers ----------------
__device__ __forceinline__ void load16(const float* __restrict__ p, float* d) {
  float4 a = *(const float4*)p, b = *(const float4*)(p + 4);
  float4 c = *(const float4*)(p + 8), e = *(const float4*)(p + 12);
  d[0] = a.x; d[1] = a.y; d[2] = a.z; d[3] = a.w;
  d[4] = b.x; d[5] = b.y; d[6] = b.z; d[7] = b.w;
  d[8] = c.x; d[9] = c.y; d[10] = c.z; d[11] = c.w;
  d[12] = e.x; d[13] = e.y; d[14] = e.z; d[15] = e.w;
}
__device__ __forceinline__ void load16(const unsigned short* __restrict__ p, float* d) {
  uint4 u = *(const uint4*)p;
  uint4 v = *(const uint4*)(p + 8);
  d[0] = __uint_as_float(u.x << 16); d[1] = __uint_as_float(u.x & 0xFFFF0000u);
  d[2] = __uint_as_float(u.y << 16); d[3] = __uint_as_float(u.y & 0xFFFF0000u);
  d[4] = __uint_as_float(u.z << 16); d[5] = __uint_as_float(u.z & 0xFFFF0000u);
  d[6] = __uint_as_float(u.w << 16); d[7] = __uint_as_float(u.w & 0xFFFF0000u);
  d[8] = __uint_as_float(v.x << 16); d[9] = __uint_as_float(v.x & 0xFFFF0000u);
  d[10] = __uint_as_float(v.y << 16); d[11] = __uint_as_float(v.y & 0xFFFF0000u);
  d[12] = __uint_as_float(v.z << 16); d[13] = __uint_as_float(v.z & 0xFFFF0000u);
  d[14] = __uint_as_float(v.w << 16); d[15] = __uint_as_float(v.w & 0xFFFF0000u);
}

template <typename ET>
__device__ __forceinline__ void load_step(const ET* __restrict__ qp, const ET* __restrict__ kp,
    const ET* __restrict__ vp, const float* __restrict__ bp, const float* __restrict__ gp,
    int t, float* q, float* k, float& vv, float& btv, float& gtv) {
  size_t off = (size_t)t * Cc;
  load16(qp + off, q);
  load16(kp + off, k);
  vv = ldsc(vp + off);
  btv = bp[t];
  gtv = gp[t];
}

// mixed: q/k bf16, v fp32
__device__ __forceinline__ void load_stepM(const unsigned short* __restrict__ qp,
    const unsigned short* __restrict__ kp, const float* __restrict__ vp,
    const float* __restrict__ bp, const float* __restrict__ gp,
    int t, float* q, float* k, float& vv, float& btv, float& gtv) {
  size_t off = (size_t)t * Cc;
  load16(qp + off, q);
  load16(kp + off, k);
  vv = vp[off];
  btv = bp[t];
  gtv = gp[t];
}

// yn/den returned UNDIVIDED
__device__ __forceinline__ void do_step2(const float* q, const float* k, float vv, float btv, float gtv,
                                         float* Ns, float* Ds, float& ynO, float& denO) {
  float yn = 0.f, den = 0.f;
#pragma unroll
  for (int j = 0; j < 16; ++j) {
    float wj = k[j] * gtv;
    float ns = fmaf(Ns[j], btv, wj * vv);
    float ds = fmaf(Ds[j], btv, wj);
    Ns[j] = ns; Ds[j] = ds;
    yn = fmaf(q[j], ns, yn);
    den = fmaf(q[j], ds, den);
  }
  yn += __shfl_xor(yn, 16); yn += __shfl_xor(yn, 32);
  den += __shfl_xor(den, 16); den += __shfl_xor(den, 32);
  ynO = yn; denO = den;
}

// ---------------- Phase A: per-chunk local scan (zero start state) ----------------
__global__ __launch_bounds__(256) void k_scanA(const unsigned short* __restrict__ phiQ,
    const unsigned short* __restrict__ phiK,
    float* __restrict__ VY, const float* __restrict__ betaB, const float* __restrict__ gateB,
    float* __restrict__ denB, float* __restrict__ aB,
    unsigned short* __restrict__ S, float* __restrict__ Dsum, float* __restrict__ Pbuf) {
  int blk = blockIdx.x;
  int bh = blk / NCc, c = blk % NCc;
  int b = bh >> 4, h = bh & 15;
  int tid = threadIdx.x;
  int w = tid >> 6, l = tid & 63;
  int e = (w << 4) | (l & 15);
  int d0 = (l >> 4) << 4;
  size_t base = ((size_t)b * Tc + (size_t)c * Lc) * Cc + h * 64;
  const unsigned short* qp = phiQ + base + d0;
  const unsigned short* kp = phiK + base + d0;
  const float* vp = VY + base + e;
  const float* bp = betaB + (size_t)bh * Tc + c * Lc;
  const float* gp = gateB + (size_t)bh * Tc + c * Lc;
  float* np = VY + base + e;
  float* dnp = denB + (size_t)bh * Tc + c * Lc;
  float* ap = aB + (size_t)bh * Tc + c * Lc;

  float Ns[16], Ds[16];
#pragma unroll
  for (int j = 0; j < 16; ++j) { Ns[j] = 0.f; Ds[j] = 0.f; }
  float aprod = 1.f;
  float qA[16], kA[16], vA, btA, gtA;
  float qB[16], kB[16], vB, btB, gtB;
  load_stepM(qp, kp, vp, bp, gp, 0, qA, kA, vA, btA, gtA);
  load_stepM(qp, kp, vp, bp, gp, 1, qB, kB, vB, btB, gtB);
  const bool wr = (l < 16);
  for (int t = 0; t < Lc; t += 2) {
    float yn, den;
    do_step2(qA, kA, vA, btA, gtA, Ns, Ds, yn, den);
    aprod *= btA;
    if (wr) np[(size_t)t * Cc] = yn;
    if (tid == 0) { dnp[t] = den; ap[t] = aprod; }
    if (t + 2 < Lc) load_stepM(qp, kp, vp, bp, gp, t + 2, qA, kA, vA, btA, gtA);
    do_step2(qB, kB, vB, btB, gtB, Ns, Ds, yn, den);
    aprod *= btB;
    if (wr) np[(size_t)(t + 1) * Cc] = yn;
    if (tid == 0) { dnp[t + 1] = den; ap[t + 1] = aprod; }
    if (t + 3 < Lc) load_stepM(qp, kp, vp, bp, gp, t + 3, qB, kB, vB, btB, gtB);
  }
  size_t sbase = (size_t)blk * 4096;
#pragma unroll
  for (int j = 0; j < 16; ++j)
    S[sbase + (size_t)(d0 + j) * 64 + e] = f2bf(Ns[j]);
  if (w == 0 && (l & 15) == 0) {
#pragma unroll
    for (int j = 0; j < 16; ++j) Dsum[(size_t)blk * 64 + d0 + j] = Ds[j];
  }
  if (tid == 0) Pbuf[blk] = aprod;
}

// ---------------- Phase B: serial carry across chunks (in place) ----------------
__global__ __launch_bounds__(256) void k_scanB(unsigned short* __restrict__ S, float* __restrict__ Dsum,
                                               const float* __restrict__ Pbuf) {
  int bh = blockIdx.x;
  int tid = threadIdx.x;
  float Nreg[16];
#pragma unroll
  for (int k = 0; k < 16; ++k) Nreg[k] = 0.f;
  float Dreg = 0.f;
  for (int c = 0; c < NCc; ++c) {
    size_t sb = ((size_t)bh * NCc + c) * 4096;
    float Pc = Pbuf[bh * NCc + c];
#pragma unroll
    for (int k = 0; k < 16; ++k) {
      size_t f = sb + tid + k * 256;
      float tmp = bf2f(S[f]);
      S[f] = f2bf(Nreg[k]);
      Nreg[k] = Nreg[k] * Pc + tmp;
    }
    if (tid < 64) {
      size_t db = ((size_t)bh * NCc + c) * 64 + tid;
      float tmp = Dsum[db];
      Dsum[db] = Dreg;
      Dreg = Dreg * Pc + tmp;
    }
  }
}

// ---------------- Phase C: apply start-state correction + division -> Ybf (bf16) ----------------
// grid = NBH*NCc*SPLITC blocks; each handles TSC t's with 2-deep pipelined q loads.
__global__ __launch_bounds__(256) void k_scanC(const unsigned short* __restrict__ phiQ,
    const unsigned short* __restrict__ S, const float* __restrict__ Dsum,
    const float* __restrict__ denB, const float* __restrict__ aB,
    const float* __restrict__ VY, unsigned short* __restrict__ Ybf) {
  int blk = blockIdx.x;
  int cid = blk / SPLITC, half = blk % SPLITC;
  int bh = cid / NCc, c = cid % NCc;
  int b = bh >> 4, h = bh & 15;
  int tid = threadIdx.x;
  int w = tid >> 6, l = tid & 63;
  int e = (w << 4) | (l & 15);
  int d0 = (l >> 4) << 4;
  size_t sbase = (size_t)cid * 4096;
  float Nst[16], Dst[16];
#pragma unroll
  for (int j = 0; j < 16; ++j) {
    Nst[j] = bf2f(S[sbase + (size_t)(d0 + j) * 64 + e]);
    Dst[j] = Dsum[(size_t)cid * 64 + d0 + j];
  }
  const int t0 = half * TSC;
  size_t base = ((size_t)b * Tc + (size_t)c * Lc + t0) * Cc + h * 64;
  const unsigned short* qp = phiQ + base + d0;
  const float* aP = aB + (size_t)bh * Tc + c * Lc + t0;
  const float* dP = denB + (size_t)bh * Tc + c * Lc + t0;
  const float* np = VY + base + e;
  unsigned short* yp = Ybf + base + e;
  const bool wr = (l < 16);

  float qA[16], qB[16];
  load16(qp, qA);
  load16(qp + Cc, qB);
  for (int t = 0; t < TSC; t += 2) {
    {
      float acc = 0.f, dac = 0.f;
#pragma unroll
      for (int j = 0; j < 16; ++j) {
        acc = fmaf(qA[j], Nst[j], acc);
        dac = fmaf(qA[j], Dst[j], dac);
      }
      acc += __shfl_xor(acc, 16); acc += __shfl_xor(acc, 32);
      dac += __shfl_xor(dac, 16); dac += __shfl_xor(dac, 32);
      if (t + 2 < TSC) load16(qp + (size_t)(t + 2) * Cc, qA);
      if (wr) {
        float a = aP[t], den = dP[t];
        float num = np[(size_t)t * Cc];
        yp[(size_t)t * Cc] = f2bf((num + a * acc) / (den + a * dac + 1e-6f));
      }
    }
    {
      float acc = 0.f, dac = 0.f;
#pragma unroll
      for (int j = 0; j < 16; ++j) {
        acc = fmaf(qB[j], Nst[j], acc);
        dac = fmaf(qB[j], Dst[j], dac);
      }
      acc += __shfl_xor(acc, 16); acc += __shfl_xor(acc, 32);
      dac += __shfl_xor(dac, 16); dac += __shfl_xor(dac, 32);
      if (t + 3 < TSC) load16(qp + (size_t)(t + 3) * Cc, qB);
      if (wr) {
        float a = aP[t + 1], den = dP[t + 1];
        float num = np[(size_t)(t + 1) * Cc];
        yp[(size_t)(t + 1) * Cc] = f2bf((num + a * acc) / (den + a * dac + 1e-6f));
      }
    }
  }
}

// ---------------- legacy serial scan (fallback path only) ----------------
__device__ __forceinline__ float do_step(const float* q, const float* k, float vv, float btv, float gtv,
                                         float* Ns, float* Ds) {
  float yn, den;
  do_step2(q, k, vv, btv, gtv, Ns, Ds, yn, den);
  return yn / (den + 1e-6f);
}

template <typename ET>
__global__ __launch_bounds__(256) void k_scan(const ET* __restrict__ phiQ, const ET* __restrict__ phiK,
    const ET* __restrict__ Vb, const float* __restrict__ betaB, const float* __restrict__ gateB,
    ET* __restrict__ Yb) {
  int bh = blockIdx.x;
  int b = bh >> 4, h = bh & 15;
  int tid = threadIdx.x;
  int w = tid >> 6, l = tid & 63;
  int e = (w << 4) | (l & 15);
  int d0 = (l >> 4) << 4;
  size_t base = ((size_t)b * Tc) * Cc + h * 64;
  const ET* qp = phiQ + base + d0;
  const ET* kp = phiK + base + d0;
  const ET* vp = Vb + base + e;
  const float* bp = betaB + (size_t)bh * Tc;
  const float* gp = gateB + (size_t)bh * Tc;
  ET* yp = Yb + base + e;

  float Ns[16], Ds[16];
#pragma unroll
  for (int j = 0; j < 16; ++j) { Ns[j] = 0.f; Ds[j] = 0.f; }
  float qA[16], kA[16], vA, btA, gtA;
  float qB[16], kB[16], vB, btB, gtB;
  load_step(qp, kp, vp, bp, gp, 0, qA, kA, vA, btA, gtA);
  load_step(qp, kp, vp, bp, gp, 1, qB, kB, vB, btB, gtB);
  const bool wr = (l < 16);
  for (int t = 0; t < Tc; t += 2) {
    float y0 = do_step(qA, kA, vA, btA, gtA, Ns, Ds);
    if (wr) stv(yp + (size_t)t * Cc, y0);
    if (t + 2 < Tc) load_step(qp, kp, vp, bp, gp, t + 2, qA, kA, vA, btA, gtA);
    float y1 = do_step(qB, kB, vB, btB, gtB, Ns, Ds);
    if (wr) stv(yp + (size_t)(t + 1) * Cc, y1);
    if (t + 3 < Tc) load_step(qp, kp, vp, bp, gp, t + 3, qB, kB, vB, btB, gtB);
  }
}

// ---------------- row LayerNorm -> fp32 out ----------------
__global__ __launch_bounds__(256) void k_ln(const float* __restrict__ pre, const float* __restrict__ ln_g,
    const float* __restrict__ ln_b, float* __restrict__ out) {
  int row = blockIdx.x;
  int tid = threadIdx.x;
  float4 v = *(const float4*)&pre[(size_t)row * Cc + tid * 4];
  float s = v.x + v.y + v.z + v.w;
  float q = v.x * v.x + v.y * v.y + v.z * v.z + v.w * v.w;
#pragma unroll
  for (int off = 1; off < 64; off <<= 1) {
    s += __shfl_xor(s, off);
    q += __shfl_xor(q, off);
  }
  __shared__ float ss[4], qq[4];
  if ((tid & 63) == 0) { ss[tid >> 6] = s; qq[tid >> 6] = q; }
  __syncthreads();
  s = ss[0] + ss[1] + ss[2] + ss[3];
  q = qq[0] + qq[1] + qq[2] + qq[3];
  float mu = s * (1.f / 1024.f);
  float var = q * (1.f / 1024.f) - mu * mu;
  float rstd = rsqrtf(var + 1e-5f);
  int c0 = tid * 4;
  float4 g = *(const float4*)&ln_g[c0];
  float4 bb = *(const float4*)&ln_b[c0];
  float4 o;
  o.x = (v.x - mu) * rstd * g.x + bb.x;
  o.y = (v.y - mu) * rstd * g.y + bb.y;
  o.z = (v.z - mu) * rstd * g.z + bb.z;
  o.w = (v.w - mu) * rstd * g.w + bb.w;
  *(float4*)&out[(size_t)row * Cc + c0] = o;
}

extern "C" void kernel_launch(void* const* d_in, const int* in_sizes, int n_in,
                              void* d_out, int out_size, void* d_ws, size_t ws_size,
                              hipStream_t stream) {
  const float* x        = (const float*)d_in[0];
  const float* q_w      = (const float*)d_in[1];
  const float* k_w      = (const float*)d_in[2];
  const float* v_w      = (const float*)d_in[3];
  const float* out_w    = (const float*)d_in[4];
  const float* out_b    = (const float*)d_in[5];
  const float* decay_w  = (const float*)d_in[6];
  const float* decay_b  = (const float*)d_in[7];
  const float* gate_w   = (const float*)d_in[8];
  const float* gate_b   = (const float*)d_in[9];
  const float* decay_w0 = (const float*)d_in[10];
  const float* ln_g     = (const float*)d_in[11];
  const float* ln_b     = (const float*)d_in[12];
  float* out            = (float*)d_out;   // reference output dtype = float32

  const size_t MC  = (size_t)Mc * Cc;      // 4,194,304 elements
  const size_t BHT = (size_t)Bc * Hc * Tc; // 65,536
  const int NBH = Bc * Hc;                 // 32
  dim3 gg(Cc / 128, Mc / 128);

  const bool fp32path = ws_size >= (size_t)52 * 1024 * 1024;

  if (fp32path) {
    // ---- ~50 MiB layout: bf16 GEMM operands/phi; S aliases xbf (dead after proj GEMMs) ----
    char* p = (char*)d_ws;
    float* tabC = (float*)p;                 p += (size_t)Tc * 32 * 4;
    float* tabS = (float*)p;                 p += (size_t)Tc * 32 * 4;
    unsigned short* xbf   = (unsigned short*)p; p += MC * 2;
    unsigned short* qwT   = (unsigned short*)p; p += (size_t)Cc * Cc * 2;
    unsigned short* kwT   = (unsigned short*)p; p += (size_t)Cc * Cc * 2;
    unsigned short* vwT   = (unsigned short*)p; p += (size_t)Cc * Cc * 2;
    unsigned short* owT   = (unsigned short*)p; p += (size_t)Cc * Cc * 2;
    unsigned short* phiQb = (unsigned short*)p; p += MC * 2;
    unsigned short* phiKb = (unsigned short*)p; p += MC * 2;   // Ybf aliases after scanA
    float* VY    = (float*)p;                p += MC * 4;      // V -> num; preO aliases after scanC
    float* betaB = (float*)p;                p += BHT * 4;
    float* gateB = (float*)p;                p += BHT * 4;
    float* denB  = (float*)p;                p += BHT * 4;
    float* aB    = (float*)p;                p += BHT * 4;
    float* Dsum  = (float*)p;                p += (size_t)NBH * NCc * 64 * 4;
    float* Pbuf  = (float*)p;                p += (size_t)NBH * NCc * 4;
    unsigned short* S = xbf;                 // 8 MiB, exactly MC*2; xbf dead after proj GEMMs
    unsigned short* Ybf = phiKb;             // phiK dead after scanA
    float* preO = VY;                        // VY dead after scanC

    k_tables<<<(Tc * 32) / 256, 256, 0, stream>>>(tabC, tabS);
    k_cvtx<<<(int)(MC / 8 / 256), 256, 0, stream>>>(x, xbf);
    k_trans<<<dim3(Cc / 32, Cc / 32, 4), 256, 0, stream>>>(q_w, k_w, v_w, out_w, qwT, kwT, vwT, owT);

    k_mfma<unsigned short, 1><<<gg, 256, 0, stream>>>(xbf, qwT, phiQb, tabC, tabS, nullptr, nullptr);
    k_mfma<unsigned short, 1><<<gg, 256, 0, stream>>>(xbf, kwT, phiKb, tabC, tabS, nullptr, nullptr);
    k_mfma<float, 0><<<gg, 256, 0, stream>>>(xbf, vwT, VY, nullptr, nullptr, nullptr, nullptr);

    k_small<<<Mc, 256, 0, stream>>>(x, gate_w, gate_b, decay_w, decay_b, decay_w0, gateB, betaB);

    k_scanA<<<NBH * NCc, 256, 0, stream>>>(phiQb, phiKb, VY, betaB, gateB, denB, aB, S, Dsum, Pbuf);
    k_scanB<<<NBH, 256, 0, stream>>>(S, Dsum, Pbuf);
    k_scanC<<<NBH * NCc * SPLITC, 256, 0, stream>>>(phiQb, S, Dsum, denB, aB, VY, Ybf);

    k_mfma<float, 2><<<gg, 256, 0, stream>>>(Ybf, owT, preO, nullptr, nullptr, out_b, x);
    k_ln<<<Mc, 256, 0, stream>>>(preO, ln_g, ln_b, out);
  } else {
    // ---- 33 MiB bf16-intermediate fallback (serial scan, SIMT GEMM) ----
    float* tabC  = (float*)d_ws;
    float* tabS  = tabC + (size_t)Tc * 32;
    unsigned short* phiQb = (unsigned short*)(tabS + (size_t)Tc * 32);
    unsigned short* phiKb = phiQb + MC;
    unsigned short* Vbb   = phiKb + MC;
    unsigned short* Ybb   = Vbb + MC;
    float* betaB = (float*)(Ybb + MC);
    float* gateB = betaB + BHT;
    float* preO  = (float*)phiQb;

    k_tables<<<(Tc * 32) / 256, 256, 0, stream>>>(tabC, tabS);
    k_gemm128<float, unsigned short, 1><<<gg, 256, 0, stream>>>(x, q_w, phiQb, Mc, Cc, Cc, tabC, tabS, nullptr, nullptr);
    k_gemm128<float, unsigned short, 1><<<gg, 256, 0, stream>>>(x, k_w, phiKb, Mc, Cc, Cc, tabC, tabS, nullptr, nullptr);
    k_gemm128<float, unsigned short, 0><<<gg, 256, 0, stream>>>(x, v_w, Vbb, Mc, Cc, Cc, nullptr, nullptr, nullptr, nullptr);
    k_small<<<Mc, 256, 0, stream>>>(x, gate_w, gate_b, decay_w, decay_b, decay_w0, gateB, betaB);
    k_scan<unsigned short><<<Bc * Hc, 256, 0, stream>>>(phiQb, phiKb, Vbb, betaB, gateB, Ybb);
    k_gemm128<unsigned short, float, 2><<<gg, 256, 0, stream>>>(Ybb, out_w, preO, Mc, Cc, Cc, nullptr, nullptr, out_b, x);
    k_ln<<<Mc, 256, 0, stream>>>(preO, ln_g, ln_b, out);
  }
}

// Round 7
// 198.044 us; speedup vs baseline: 8.8235x; 1.4741x over previous
//
#include <hip/hip_runtime.h>
#include <hip/hip_bf16.h>
#include <math.h>

static constexpr int Bc = 2, Tc = 2048, Cc = 1024, Hc = 16;
static constexpr int Mc = Bc * Tc;  // 4096 rows
static constexpr int NCc = 32, Lc = 64;  // chunks per (b,h), chunk length
static constexpr int TP = 72;  // LDS tile pitch in shorts (144 B: 36 dwords == 4 mod 32 -> 2-way max)

typedef __attribute__((ext_vector_type(8))) short bf16x8;
typedef __attribute__((ext_vector_type(4))) float f32x4;

// ---------- dtype helpers ----------
__device__ __forceinline__ float bf2f(unsigned short u) {
  return __uint_as_float((unsigned)u << 16);
}
__device__ __forceinline__ unsigned short f2bf(float f) {
  __hip_bfloat16 h = __float2bfloat16(f);
  return *(unsigned short*)&h;
}
__device__ __forceinline__ float4 ld4(const float* p) { return *(const float4*)p; }
__device__ __forceinline__ float4 ld4(const unsigned short* p) {
  ushort4 u = *(const ushort4*)p;
  return make_float4(bf2f(u.x), bf2f(u.y), bf2f(u.z), bf2f(u.w));
}
__device__ __forceinline__ void stv(float* p, float v) { *p = v; }
__device__ __forceinline__ void stv(unsigned short* p, float v) { *p = f2bf(v); }

// ---------------- RoPE tables ----------------
__global__ __launch_bounds__(256) void k_tables(float* __restrict__ tc, float* __restrict__ ts) {
  int i = blockIdx.x * 256 + threadIdx.x;       // < Tc*32
  int t = i >> 5, f = i & 31;
  float ivf = 1.0f / powf(10000.f, (float)f / 32.f);
  float fr = (float)t * ivf;
  tc[i] = cosf(fr);
  ts[i] = sinf(fr);
}

__device__ __forceinline__ float phi_fn(float x) { return x > 0.f ? x + 1.f : __expf(x); }

// ---------------- fp32 -> bf16 convert (x) ----------------
__global__ __launch_bounds__(256) void k_cvtx(const float* __restrict__ src, unsigned short* __restrict__ dst) {
  int i = blockIdx.x * 256 + threadIdx.x;   // 8 elems each
  float4 a = *(const float4*)&src[(size_t)i * 8];
  float4 b = *(const float4*)&src[(size_t)i * 8 + 4];
  ushort4 u0 = make_ushort4(f2bf(a.x), f2bf(a.y), f2bf(a.z), f2bf(a.w));
  ushort4 u1 = make_ushort4(f2bf(b.x), f2bf(b.y), f2bf(b.z), f2bf(b.w));
  *(ushort4*)&dst[(size_t)i * 8] = u0;
  *(ushort4*)&dst[(size_t)i * 8 + 4] = u1;
}

// ---------------- W[K][N] fp32 -> WT[N][K] bf16, 4 weights via blockIdx.z ----------------
__global__ __launch_bounds__(256) void k_trans(
    const float* __restrict__ w0, const float* __restrict__ w1,
    const float* __restrict__ w2, const float* __restrict__ w3,
    unsigned short* __restrict__ o0, unsigned short* __restrict__ o1,
    unsigned short* __restrict__ o2, unsigned short* __restrict__ o3) {
  const float* W = (blockIdx.z == 0) ? w0 : (blockIdx.z == 1) ? w1 : (blockIdx.z == 2) ? w2 : w3;
  unsigned short* O = (blockIdx.z == 0) ? o0 : (blockIdx.z == 1) ? o1 : (blockIdx.z == 2) ? o2 : o3;
  __shared__ float tile[32][33];
  int k0 = blockIdx.x * 32, n0 = blockIdx.y * 32;
  int t = threadIdx.x;
  int kk = t >> 3, nn4 = (t & 7) * 4;
  float4 v = *(const float4*)&W[(size_t)(k0 + kk) * Cc + n0 + nn4];
  tile[kk][nn4] = v.x; tile[kk][nn4 + 1] = v.y; tile[kk][nn4 + 2] = v.z; tile[kk][nn4 + 3] = v.w;
  __syncthreads();
  int nn = t >> 3, kk4 = (t & 7) * 4;
  ushort4 o = make_ushort4(f2bf(tile[kk4][nn]), f2bf(tile[kk4 + 1][nn]),
                           f2bf(tile[kk4 + 2][nn]), f2bf(tile[kk4 + 3][nn]));
  *(ushort4*)&O[(size_t)(n0 + nn) * Cc + k0 + kk4] = o;
}

// ---------------- bf16 MFMA GEMM: A[M][K] bf16 row-major, BT[N][K] bf16 row-major ----------------
static constexpr int LDP = 40;
template <typename OT, int MODE>
__global__ __launch_bounds__(256) void k_mfma(
    const unsigned short* __restrict__ A, const unsigned short* __restrict__ BT,
    OT* __restrict__ Co,
    const float* __restrict__ tabC, const float* __restrict__ tabS,
    const float* __restrict__ bias, const float* __restrict__ resid) {
  constexpr int K = Cc, N = Cc;
  __shared__ unsigned short As[128 * LDP];
  __shared__ unsigned short Bs[128 * LDP];
  const int tid = threadIdx.x;
  const int n0 = blockIdx.x * 128, m0 = blockIdx.y * 128;
  const int l = tid & 63, w = tid >> 6;
  const int wr = w >> 1, wc = w & 1;
  const int lrow = l & 15, lk = (l >> 4) * 8;

  f32x4 acc[4][4];
#pragma unroll
  for (int i = 0; i < 4; ++i)
#pragma unroll
    for (int j = 0; j < 4; ++j) acc[i][j] = (f32x4){0.f, 0.f, 0.f, 0.f};

  const int srow = tid >> 1, shalf = tid & 1;
  const size_t abase = (size_t)(m0 + srow) * K + shalf * 16;
  const size_t bbase = (size_t)(n0 + srow) * K + shalf * 16;
  const int sdst = srow * LDP + shalf * 16;

  for (int k0 = 0; k0 < K; k0 += 32) {
    uint4 a0 = *(const uint4*)&A[abase + k0];
    uint4 a1 = *(const uint4*)&A[abase + k0 + 8];
    uint4 b0 = *(const uint4*)&BT[bbase + k0];
    uint4 b1 = *(const uint4*)&BT[bbase + k0 + 8];
    __syncthreads();
    *(uint4*)&As[sdst] = a0;
    *(uint4*)&As[sdst + 8] = a1;
    *(uint4*)&Bs[sdst] = b0;
    *(uint4*)&Bs[sdst + 8] = b1;
    __syncthreads();
    bf16x8 af[4], bf[4];
#pragma unroll
    for (int fm = 0; fm < 4; ++fm)
      af[fm] = *(const bf16x8*)&As[(wr * 64 + fm * 16 + lrow) * LDP + lk];
#pragma unroll
    for (int fn = 0; fn < 4; ++fn)
      bf[fn] = *(const bf16x8*)&Bs[(wc * 64 + fn * 16 + lrow) * LDP + lk];
#pragma unroll
    for (int fm = 0; fm < 4; ++fm)
#pragma unroll
      for (int fn = 0; fn < 4; ++fn)
        acc[fm][fn] = __builtin_amdgcn_mfma_f32_16x16x32_bf16(af[fm], bf[fn], acc[fm][fn], 0, 0, 0);
  }

#pragma unroll
  for (int fm = 0; fm < 4; ++fm) {
#pragma unroll
    for (int fn = 0; fn < 4; ++fn) {
#pragma unroll
      for (int r = 0; r < 4; ++r) {
        float v = acc[fm][fn][r];
        int row = m0 + wr * 64 + fm * 16 + (l >> 4) * 4 + r;
        int col = n0 + wc * 64 + fn * 16 + (l & 15);
        if constexpr (MODE == 1) {
          float p = __shfl_xor(v, 1);
          int t = row & (Tc - 1);
          int pi = (col & 63) >> 1;
          float cv = tabC[t * 32 + pi], sv = tabS[t * 32 + pi];
          float res = (col & 1) ? (p * sv + v * cv) : (v * cv - p * sv);
          stv(&Co[(size_t)row * N + col], phi_fn(res));
        } else if constexpr (MODE == 2) {
          stv(&Co[(size_t)row * N + col], v + bias[col] + resid[(size_t)row * N + col]);
        } else {
          stv(&Co[(size_t)row * N + col], v);
        }
      }
    }
  }
}

// ---------------- legacy fp32 SIMT GEMM (fallback path only) ----------------
template <typename AT, typename OT, int MODE>
__global__ __launch_bounds__(256) void k_gemm128(
    const AT* __restrict__ A, const float* __restrict__ Bw, OT* __restrict__ Co,
    int M, int N, int K,
    const float* __restrict__ tabC, const float* __restrict__ tabS,
    const float* __restrict__ bias, const float* __restrict__ resid) {
  __shared__ float As[16][132];
  __shared__ float Bs[16][132];
  const int tid = threadIdx.x;
  const int tx = tid & 15, ty = tid >> 4;
  const int n0 = blockIdx.x * 128, m0 = blockIdx.y * 128;
  float acc[8][8];
#pragma unroll
  for (int i = 0; i < 8; ++i)
#pragma unroll
    for (int j = 0; j < 8; ++j) acc[i][j] = 0.f;
  for (int k0 = 0; k0 < K; k0 += 16) {
#pragma unroll
    for (int rep = 0; rep < 2; ++rep) {
      int lin = tid + rep * 256;
      int r = lin >> 2, c4 = (lin & 3) << 2;
      float4 av = ld4(&A[(size_t)(m0 + r) * K + k0 + c4]);
      As[c4 + 0][r] = av.x; As[c4 + 1][r] = av.y;
      As[c4 + 2][r] = av.z; As[c4 + 3][r] = av.w;
      int rb = lin >> 5, cb = (lin & 31) << 2;
      *(float4*)&Bs[rb][cb] = *(const float4*)&Bw[(size_t)(k0 + rb) * N + n0 + cb];
    }
    __syncthreads();
#pragma unroll
    for (int kk = 0; kk < 16; ++kk) {
      float4 a0 = *(const float4*)&As[kk][ty * 8];
      float4 a1 = *(const float4*)&As[kk][ty * 8 + 4];
      float4 b0 = *(const float4*)&Bs[kk][tx * 8];
      float4 b1 = *(const float4*)&Bs[kk][tx * 8 + 4];
      float avv[8] = {a0.x, a0.y, a0.z, a0.w, a1.x, a1.y, a1.z, a1.w};
      float bvv[8] = {b0.x, b0.y, b0.z, b0.w, b1.x, b1.y, b1.z, b1.w};
#pragma unroll
      for (int i = 0; i < 8; ++i)
#pragma unroll
        for (int j = 0; j < 8; ++j) acc[i][j] = fmaf(avv[i], bvv[j], acc[i][j]);
    }
    __syncthreads();
  }
  if constexpr (MODE == 1) {
#pragma unroll
    for (int i = 0; i < 8; ++i) {
      int row = m0 + ty * 8 + i;
      int t = row & (Tc - 1);
#pragma unroll
      for (int j = 0; j < 8; j += 2) {
        int col = n0 + tx * 8 + j;
        int pi = (col & 63) >> 1;
        float cv = tabC[t * 32 + pi], sv = tabS[t * 32 + pi];
        float xe = acc[i][j], xo = acc[i][j + 1];
        stv(&Co[(size_t)row * N + col], phi_fn(xe * cv - xo * sv));
        stv(&Co[(size_t)row * N + col + 1], phi_fn(xe * sv + xo * cv));
      }
    }
  } else if constexpr (MODE == 2) {
#pragma unroll
    for (int i = 0; i < 8; ++i) {
      int row = m0 + ty * 8 + i;
#pragma unroll
      for (int j = 0; j < 8; ++j) {
        int col = n0 + tx * 8 + j;
        stv(&Co[(size_t)row * N + col], acc[i][j] + bias[col] + resid[(size_t)row * N + col]);
      }
    }
  } else {
#pragma unroll
    for (int i = 0; i < 8; ++i) {
      int row = m0 + ty * 8 + i;
#pragma unroll
      for (int j = 0; j < 8; ++j) {
        int col = n0 + tx * 8 + j;
        stv(&Co[(size_t)row * N + col], acc[i][j]);
      }
    }
  }
}

// ---------------- gate / decay projections (N=32); writes RATE (not beta) ----------------
__global__ __launch_bounds__(256) void k_small(
    const float* __restrict__ x, const float* __restrict__ gate_w, const float* __restrict__ gate_b,
    const float* __restrict__ decay_w, const float* __restrict__ decay_b,
    const float* __restrict__ decay_w0, float* __restrict__ gate_o, float* __restrict__ rate_o) {
  __shared__ float xs[1024];
  __shared__ float part[8][32];
  int bt = blockIdx.x;
  int tid = threadIdx.x;
  *(float4*)&xs[tid * 4] = *(const float4*)&x[(size_t)bt * Cc + tid * 4];
  __syncthreads();
  int o = tid & 31, seg = tid >> 5;
  const float* wp = (o < 16) ? gate_w : decay_w;
  int oc = o & 15;
  float p = 0.f;
  int kb = seg * 128;
#pragma unroll 4
  for (int kk = 0; kk < 128; ++kk) {
    int k = kb + kk;
    p = fmaf(xs[k], wp[(size_t)k * 16 + oc], p);
  }
  part[seg][o] = p;
  __syncthreads();
  if (tid < 32) {
    float s = 0.f;
#pragma unroll
    for (int sg = 0; sg < 8; ++sg) s += part[sg][tid];
    int b = bt >> 11, t = bt & (Tc - 1);
    if (tid < 16) {
      float gv = 1.f / (1.f + expf(-(s + gate_b[tid])));
      gate_o[((size_t)(b * Hc + tid)) * Tc + t] = gv;
    } else {
      int hh = tid - 16;
      float raw = s + decay_b[hh] + decay_w0[hh];
      float sp = raw > 20.f ? raw : log1pf(expf(raw));
      float rate = fminf(fmaxf(sp, 1e-4f), 10.f);
      rate_o[((size_t)(b * Hc + hh)) * Tc + t] = rate;
    }
  }
}

// ---------------- Phase A (MFMA): per-chunk summaries S^T[e][d], Dsum[d], P ----------------
__global__ __launch_bounds__(256) void k_scanA2(
    const unsigned short* __restrict__ Kb, const unsigned short* __restrict__ Vb,
    const float* __restrict__ rateB, const float* __restrict__ gateB,
    unsigned short* __restrict__ S, float* __restrict__ Dsum, float* __restrict__ Pbuf) {
  int blk = blockIdx.x;
  int bh = blk >> 5, c = blk & 31;
  int b = bh >> 4, h = bh & 15;
  int tid = threadIdx.x;
  int l = tid & 63, wv = tid >> 6;
  __shared__ unsigned short KT[64 * TP];   // [d][s]
  __shared__ unsigned short VT[64 * TP];   // [e][s], scaled by w_s
  __shared__ float Rc[64], gs[64], ws[64];
  size_t base = ((size_t)b * Tc + (size_t)c * 64) * Cc + h * 64;
  // stage K^T (unscaled): thread handles row s = tid>>2, 16 cols
  {
    int s = tid >> 2, d0g = (tid & 3) * 16;
    const unsigned short* kr = Kb + base + (size_t)s * Cc + d0g;
    unsigned short kv[16];
    *(uint4*)kv = *(const uint4*)kr; *(uint4*)(kv + 8) = *(const uint4*)(kr + 8);
#pragma unroll
    for (int i = 0; i < 16; ++i) KT[(d0g + i) * TP + s] = kv[i];
  }
  if (wv == 0) {
    float r = rateB[(size_t)bh * Tc + c * 64 + l];
    float g = gateB[(size_t)bh * Tc + c * 64 + l];
    float v = r;
#pragma unroll
    for (int off = 1; off < 64; off <<= 1) { float u = __shfl_up(v, off); if (l >= off) v += u; }
    Rc[l] = v; gs[l] = g;
  }
  __syncthreads();
  float Rtot = Rc[63];
  if (wv == 0) ws[l] = __expf(Rc[l] - Rtot) * gs[l];
  __syncthreads();
  // stage Vtilde^T = V^T scaled by w_s
  {
    int s = tid >> 2, e0g = (tid & 3) * 16;
    float wsv = ws[s];
    const unsigned short* vr = Vb + base + (size_t)s * Cc + e0g;
    unsigned short vvv[16];
    *(uint4*)vvv = *(const uint4*)vr; *(uint4*)(vvv + 8) = *(const uint4*)(vr + 8);
#pragma unroll
    for (int i = 0; i < 16; ++i) VT[(e0g + i) * TP + s] = f2bf(bf2f(vvv[i]) * wsv);
  }
  __syncthreads();
  // C[e][d] = sum_s VT[e][s]*K[s][d]; A=VT (m=e,k=s), B from [n=d][k=s]=KT
  f32x4 acc[4];
#pragma unroll
  for (int i = 0; i < 4; ++i) acc[i] = (f32x4){0.f, 0.f, 0.f, 0.f};
  const int lrow = l & 15, lk8 = (l >> 4) * 8;
#pragma unroll
  for (int ks = 0; ks < 2; ++ks) {
    bf16x8 a = *(const bf16x8*)&VT[(wv * 16 + lrow) * TP + ks * 32 + lk8];
#pragma unroll
    for (int fn = 0; fn < 4; ++fn) {
      bf16x8 bb = *(const bf16x8*)&KT[(fn * 16 + lrow) * TP + ks * 32 + lk8];
      acc[fn] = __builtin_amdgcn_mfma_f32_16x16x32_bf16(a, bb, acc[fn], 0, 0, 0);
    }
  }
  size_t sb = (size_t)blk * 4096;
#pragma unroll
  for (int fn = 0; fn < 4; ++fn)
#pragma unroll
    for (int r = 0; r < 4; ++r) {
      int e = wv * 16 + (l >> 4) * 4 + r;
      int d = fn * 16 + (l & 15);
      S[sb + e * 64 + d] = f2bf(acc[fn][r]);
    }
  if (tid < 64) {
    float s = 0.f;
#pragma unroll 8
    for (int ss = 0; ss < 64; ++ss) s += bf2f(KT[tid * TP + ss]) * ws[ss];
    Dsum[(size_t)blk * 64 + tid] = s;
  }
  if (tid == 0) Pbuf[blk] = __expf(-Rtot);
}

// ---------------- Phase B: serial carry across chunks (1-deep prefetch) ----------------
__global__ __launch_bounds__(256) void k_scanB(unsigned short* __restrict__ S, float* __restrict__ Dsum,
                                               const float* __restrict__ Pbuf) {
  int bh = blockIdx.x;
  int tid = threadIdx.x;
  float Nreg[16];
#pragma unroll
  for (int k = 0; k < 16; ++k) Nreg[k] = 0.f;
  float Dreg = 0.f;
  unsigned short curS[16]; float curD = 0.f, curP;
  {
    size_t sb = ((size_t)bh * NCc) * 4096;
#pragma unroll
    for (int k = 0; k < 16; ++k) curS[k] = S[sb + tid + k * 256];
    if (tid < 64) curD = Dsum[((size_t)bh * NCc) * 64 + tid];
    curP = Pbuf[bh * NCc];
  }
  for (int c = 0; c < NCc; ++c) {
    unsigned short nxtS[16]; float nxtD = 0.f, nxtP = 0.f;
    if (c + 1 < NCc) {
      size_t sb = ((size_t)bh * NCc + c + 1) * 4096;
#pragma unroll
      for (int k = 0; k < 16; ++k) nxtS[k] = S[sb + tid + k * 256];
      if (tid < 64) nxtD = Dsum[((size_t)bh * NCc + c + 1) * 64 + tid];
      nxtP = Pbuf[bh * NCc + c + 1];
    }
    size_t sb = ((size_t)bh * NCc + c) * 4096;
#pragma unroll
    for (int k = 0; k < 16; ++k) {
      float tmp = bf2f(curS[k]);
      S[sb + tid + k * 256] = f2bf(Nreg[k]);
      Nreg[k] = Nreg[k] * curP + tmp;
    }
    if (tid < 64) {
      size_t db = ((size_t)bh * NCc + c) * 64 + tid;
      float tmp = curD;
      Dsum[db] = Dreg;
      Dreg = Dreg * curP + tmp;
    }
#pragma unroll
    for (int k = 0; k < 16; ++k) curS[k] = nxtS[k];
    curD = nxtD; curP = nxtP;
  }
}

// ---------------- Phase C (MFMA): intra-chunk + start-state, full output ----------------
__global__ __launch_bounds__(256) void k_scanC2(
    const unsigned short* __restrict__ Qb, const unsigned short* __restrict__ Kb,
    const unsigned short* __restrict__ Vb,
    const float* __restrict__ rateB, const float* __restrict__ gateB,
    const unsigned short* __restrict__ S, const float* __restrict__ Dsum,
    unsigned short* __restrict__ Yb) {
  int blk = blockIdx.x;
  int bh = blk >> 5, c = blk & 31;
  int b = bh >> 4, h = bh & 15;
  int tid = threadIdx.x;
  int l = tid & 63, wv = tid >> 6;
  __shared__ unsigned short Qs[64 * TP];   // [t][d]
  __shared__ unsigned short Ks[64 * TP];   // [s][d]; overlaid by W' [t][s] after QK
  __shared__ unsigned short VT[64 * TP];   // [e][s]
  __shared__ unsigned short Ss[64 * TP];   // [e][d] start state
  __shared__ float Rc[64], gs[64], DstL[64];
  size_t base = ((size_t)b * Tc + (size_t)c * 64) * Cc + h * 64;
  {
    int rr = tid >> 2, c0 = (tid & 3) * 16;
    const unsigned short* qr = Qb + base + (size_t)rr * Cc + c0;
    const unsigned short* kr = Kb + base + (size_t)rr * Cc + c0;
    const unsigned short* vr = Vb + base + (size_t)rr * Cc + c0;
    const unsigned short* sr = S + (size_t)blk * 4096 + rr * 64 + c0;
    *(uint4*)&Qs[rr * TP + c0] = *(const uint4*)qr;
    *(uint4*)&Qs[rr * TP + c0 + 8] = *(const uint4*)(qr + 8);
    *(uint4*)&Ks[rr * TP + c0] = *(const uint4*)kr;
    *(uint4*)&Ks[rr * TP + c0 + 8] = *(const uint4*)(kr + 8);
    *(uint4*)&Ss[rr * TP + c0] = *(const uint4*)sr;
    *(uint4*)&Ss[rr * TP + c0 + 8] = *(const uint4*)(sr + 8);
    unsigned short vvv[16];
    *(uint4*)vvv = *(const uint4*)vr; *(uint4*)(vvv + 8) = *(const uint4*)(vr + 8);
#pragma unroll
    for (int i = 0; i < 16; ++i) VT[(c0 + i) * TP + rr] = vvv[i];
  }
  if (wv == 0) {
    float r = rateB[(size_t)bh * Tc + c * 64 + l];
    float g = gateB[(size_t)bh * Tc + c * 64 + l];
    float v = r;
#pragma unroll
    for (int off = 1; off < 64; off <<= 1) { float u = __shfl_up(v, off); if (l >= off) v += u; }
    Rc[l] = v; gs[l] = g;
    DstL[l] = Dsum[(size_t)blk * 64 + l];
  }
  __syncthreads();
  const int lrow = l & 15, lk8 = (l >> 4) * 8;
  // QK^T: C[t][s]; A=Qs[t][d], B from [n=s][k=d]=Ks
  f32x4 qk[4];
#pragma unroll
  for (int i = 0; i < 4; ++i) qk[i] = (f32x4){0.f, 0.f, 0.f, 0.f};
#pragma unroll
  for (int ks = 0; ks < 2; ++ks) {
    bf16x8 a = *(const bf16x8*)&Qs[(wv * 16 + lrow) * TP + ks * 32 + lk8];
#pragma unroll
    for (int fn = 0; fn < 4; ++fn) {
      bf16x8 bb = *(const bf16x8*)&Ks[(fn * 16 + lrow) * TP + ks * 32 + lk8];
      qk[fn] = __builtin_amdgcn_mfma_f32_16x16x32_bf16(a, bb, qk[fn], 0, 0, 0);
    }
  }
  __syncthreads();   // everyone done reading Ks -> safe to overlay W'
  // mask+scale, den_intra, write W' bf16 into Ks as [t][s] (own wave's t-stripe only)
  float deni[4] = {0.f, 0.f, 0.f, 0.f};
  float rct[4];
#pragma unroll
  for (int r = 0; r < 4; ++r) rct[r] = Rc[wv * 16 + (l >> 4) * 4 + r];
#pragma unroll
  for (int fn = 0; fn < 4; ++fn) {
    int s = fn * 16 + (l & 15);
    float rs = Rc[s], g = gs[s];
#pragma unroll
    for (int r = 0; r < 4; ++r) {
      int t = wv * 16 + (l >> 4) * 4 + r;
      float wgt = (s <= t) ? __expf(rs - rct[r]) * g : 0.f;
      unsigned short sb16 = f2bf(qk[fn][r] * wgt);
      deni[r] += bf2f(sb16);
      Ks[t * TP + s] = sb16;
    }
  }
#pragma unroll
  for (int r = 0; r < 4; ++r) {
    deni[r] += __shfl_xor(deni[r], 1);
    deni[r] += __shfl_xor(deni[r], 2);
    deni[r] += __shfl_xor(deni[r], 4);
    deni[r] += __shfl_xor(deni[r], 8);
  }
  // num = W' @ V  (A from own-stripe W' rows; B from [n=e][k=s]=VT)
  // num2 = Q @ Nstart (B from [n=e][k=d]=Ss) ; den2 = Q @ Dst (col-0 packed frag)
  f32x4 nm[4], nm2[4], dn2;
#pragma unroll
  for (int i = 0; i < 4; ++i) { nm[i] = (f32x4){0.f,0.f,0.f,0.f}; nm2[i] = (f32x4){0.f,0.f,0.f,0.f}; }
  dn2 = (f32x4){0.f, 0.f, 0.f, 0.f};
#pragma unroll
  for (int ks = 0; ks < 2; ++ks) {
    bf16x8 aw = *(const bf16x8*)&Ks[(wv * 16 + lrow) * TP + ks * 32 + lk8];
    bf16x8 aq = *(const bf16x8*)&Qs[(wv * 16 + lrow) * TP + ks * 32 + lk8];
#pragma unroll
    for (int fn = 0; fn < 4; ++fn) {
      bf16x8 bv = *(const bf16x8*)&VT[(fn * 16 + lrow) * TP + ks * 32 + lk8];
      bf16x8 bs = *(const bf16x8*)&Ss[(fn * 16 + lrow) * TP + ks * 32 + lk8];
      nm[fn] = __builtin_amdgcn_mfma_f32_16x16x32_bf16(aw, bv, nm[fn], 0, 0, 0);
      nm2[fn] = __builtin_amdgcn_mfma_f32_16x16x32_bf16(aq, bs, nm2[fn], 0, 0, 0);
    }
    bf16x8 bd = (bf16x8){0, 0, 0, 0, 0, 0, 0, 0};
    if (lrow == 0) {
#pragma unroll
      for (int i = 0; i < 8; ++i) bd[i] = (short)f2bf(DstL[ks * 32 + lk8 + i]);
    }
    dn2 = __builtin_amdgcn_mfma_f32_16x16x32_bf16(aq, bd, dn2, 0, 0, 0);
  }
  float den2v[4];
#pragma unroll
  for (int r = 0; r < 4; ++r) den2v[r] = __shfl(dn2[r], (l & 48));
  // finalize: y[t][e]
#pragma unroll
  for (int r = 0; r < 4; ++r) {
    int t = wv * 16 + (l >> 4) * 4 + r;
    float at = __expf(-rct[r]);
    float dv = deni[r] + at * den2v[r] + 1e-6f;
#pragma unroll
    for (int fn = 0; fn < 4; ++fn) {
      int e = fn * 16 + (l & 15);
      float numv = nm[fn][r] + at * nm2[fn][r];
      Yb[base + (size_t)t * Cc + e] = f2bf(numv / dv);
    }
  }
}

// ---------------- legacy serial scan (fallback path only; rate input) ----------------
__device__ __forceinline__ void load16(const unsigned short* __restrict__ p, float* d) {
  uint4 u = *(const uint4*)p;
  uint4 v = *(const uint4*)(p + 8);
  d[0] = __uint_as_float(u.x << 16); d[1] = __uint_as_float(u.x & 0xFFFF0000u);
  d[2] = __uint_as_float(u.y << 16); d[3] = __uint_as_float(u.y & 0xFFFF0000u);
  d[4] = __uint_as_float(u.z << 16); d[5] = __uint_as_float(u.z & 0xFFFF0000u);
  d[6] = __uint_as_float(u.w << 16); d[7] = __uint_as_float(u.w & 0xFFFF0000u);
  d[8] = __uint_as_float(v.x << 16); d[9] = __uint_as_float(v.x & 0xFFFF0000u);
  d[10] = __uint_as_float(v.y << 16); d[11] = __uint_as_float(v.y & 0xFFFF0000u);
  d[12] = __uint_as_float(v.z << 16); d[13] = __uint_as_float(v.z & 0xFFFF0000u);
  d[14] = __uint_as_float(v.w << 16); d[15] = __uint_as_float(v.w & 0xFFFF0000u);
}

__global__ __launch_bounds__(256) void k_scan(const unsigned short* __restrict__ phiQ,
    const unsigned short* __restrict__ phiK, const unsigned short* __restrict__ Vb,
    const float* __restrict__ rateB, const float* __restrict__ gateB,
    unsigned short* __restrict__ Yb) {
  int bh = blockIdx.x;
  int b = bh >> 4, h = bh & 15;
  int tid = threadIdx.x;
  int w = tid >> 6, l = tid & 63;
  int e = (w << 4) | (l & 15);
  int d0 = (l >> 4) << 4;
  size_t base = ((size_t)b * Tc) * Cc + h * 64;
  const unsigned short* qp = phiQ + base + d0;
  const unsigned short* kp = phiK + base + d0;
  const unsigned short* vp = Vb + base + e;
  const float* bp = rateB + (size_t)bh * Tc;
  const float* gp = gateB + (size_t)bh * Tc;
  unsigned short* yp = Yb + base + e;
  float Ns[16], Ds[16];
#pragma unroll
  for (int j = 0; j < 16; ++j) { Ns[j] = 0.f; Ds[j] = 0.f; }
  const bool wr = (l < 16);
  for (int t = 0; t < Tc; ++t) {
    float q[16], k[16];
    load16(qp + (size_t)t * Cc, q);
    load16(kp + (size_t)t * Cc, k);
    float vv = bf2f(vp[(size_t)t * Cc]);
    float btv = __expf(-bp[t]), gtv = gp[t];
    float yn = 0.f, den = 0.f;
#pragma unroll
    for (int j = 0; j < 16; ++j) {
      float wj = k[j] * gtv;
      float ns = fmaf(Ns[j], btv, wj * vv);
      float ds = fmaf(Ds[j], btv, wj);
      Ns[j] = ns; Ds[j] = ds;
      yn = fmaf(q[j], ns, yn);
      den = fmaf(q[j], ds, den);
    }
    yn += __shfl_xor(yn, 16); yn += __shfl_xor(yn, 32);
    den += __shfl_xor(den, 16); den += __shfl_xor(den, 32);
    if (wr) yp[(size_t)t * Cc] = f2bf(yn / (den + 1e-6f));
  }
}

// ---------------- row LayerNorm -> fp32 out ----------------
__global__ __launch_bounds__(256) void k_ln(const float* __restrict__ pre, const float* __restrict__ ln_g,
    const float* __restrict__ ln_b, float* __restrict__ out) {
  int row = blockIdx.x;
  int tid = threadIdx.x;
  float4 v = *(const float4*)&pre[(size_t)row * Cc + tid * 4];
  float s = v.x + v.y + v.z + v.w;
  float q = v.x * v.x + v.y * v.y + v.z * v.z + v.w * v.w;
#pragma unroll
  for (int off = 1; off < 64; off <<= 1) {
    s += __shfl_xor(s, off);
    q += __shfl_xor(q, off);
  }
  __shared__ float ss[4], qq[4];
  if ((tid & 63) == 0) { ss[tid >> 6] = s; qq[tid >> 6] = q; }
  __syncthreads();
  s = ss[0] + ss[1] + ss[2] + ss[3];
  q = qq[0] + qq[1] + qq[2] + qq[3];
  float mu = s * (1.f / 1024.f);
  float var = q * (1.f / 1024.f) - mu * mu;
  float rstd = rsqrtf(var + 1e-5f);
  int c0 = tid * 4;
  float4 g = *(const float4*)&ln_g[c0];
  float4 bb = *(const float4*)&ln_b[c0];
  float4 o;
  o.x = (v.x - mu) * rstd * g.x + bb.x;
  o.y = (v.y - mu) * rstd * g.y + bb.y;
  o.z = (v.z - mu) * rstd * g.z + bb.z;
  o.w = (v.w - mu) * rstd * g.w + bb.w;
  *(float4*)&out[(size_t)row * Cc + c0] = o;
}

extern "C" void kernel_launch(void* const* d_in, const int* in_sizes, int n_in,
                              void* d_out, int out_size, void* d_ws, size_t ws_size,
                              hipStream_t stream) {
  const float* x        = (const float*)d_in[0];
  const float* q_w      = (const float*)d_in[1];
  const float* k_w      = (const float*)d_in[2];
  const float* v_w      = (const float*)d_in[3];
  const float* out_w    = (const float*)d_in[4];
  const float* out_b    = (const float*)d_in[5];
  const float* decay_w  = (const float*)d_in[6];
  const float* decay_b  = (const float*)d_in[7];
  const float* gate_w   = (const float*)d_in[8];
  const float* gate_b   = (const float*)d_in[9];
  const float* decay_w0 = (const float*)d_in[10];
  const float* ln_g     = (const float*)d_in[11];
  const float* ln_b     = (const float*)d_in[12];
  float* out            = (float*)d_out;

  const size_t MC  = (size_t)Mc * Cc;
  const size_t BHT = (size_t)Bc * Hc * Tc;
  const int NBH = Bc * Hc;                 // 32
  dim3 gg(Cc / 128, Mc / 128);

  const bool fp32path = ws_size >= (size_t)52 * 1024 * 1024;

  if (fp32path) {
    // ---- ~49.5 MiB layout, all-bf16 tensors + MFMA chunked scan ----
    char* p = (char*)d_ws;
    float* tabC = (float*)p;                    p += (size_t)Tc * 32 * 4;
    float* tabS = (float*)p;                    p += (size_t)Tc * 32 * 4;
    unsigned short* xbf   = (unsigned short*)p; p += MC * 2;        // S aliases (8 MiB)
    unsigned short* qwT   = (unsigned short*)p; p += (size_t)Cc * Cc * 2;
    unsigned short* kwT   = (unsigned short*)p; p += (size_t)Cc * Cc * 2;
    unsigned short* vwT   = (unsigned short*)p; p += (size_t)Cc * Cc * 2;
    unsigned short* owT   = (unsigned short*)p; p += (size_t)Cc * Cc * 2;
    unsigned short* phiQb = (unsigned short*)p; p += MC * 2;        // preO (16MB) overlays phiQb+Vbf
    unsigned short* Vbf   = (unsigned short*)p; p += MC * 2;
    unsigned short* phiKb = (unsigned short*)p; p += MC * 2;
    unsigned short* Ybf   = (unsigned short*)p; p += MC * 2;
    float* rateB = (float*)p;                   p += BHT * 4;
    float* gateB = (float*)p;                   p += BHT * 4;
    float* Dsum  = (float*)p;                   p += (size_t)NBH * NCc * 64 * 4;
    float* Pbuf  = (float*)p;                   p += (size_t)NBH * NCc * 4;
    unsigned short* S = xbf;                    // xbf dead after projection GEMMs
    float* preO = (float*)phiQb;                // phiQb+Vbf dead after scanC2

    k_tables<<<(Tc * 32) / 256, 256, 0, stream>>>(tabC, tabS);
    k_cvtx<<<(int)(MC / 8 / 256), 256, 0, stream>>>(x, xbf);
    k_trans<<<dim3(Cc / 32, Cc / 32, 4), 256, 0, stream>>>(q_w, k_w, v_w, out_w, qwT, kwT, vwT, owT);

    k_mfma<unsigned short, 1><<<gg, 256, 0, stream>>>(xbf, qwT, phiQb, tabC, tabS, nullptr, nullptr);
    k_mfma<unsigned short, 1><<<gg, 256, 0, stream>>>(xbf, kwT, phiKb, tabC, tabS, nullptr, nullptr);
    k_mfma<unsigned short, 0><<<gg, 256, 0, stream>>>(xbf, vwT, Vbf, nullptr, nullptr, nullptr, nullptr);

    k_small<<<Mc, 256, 0, stream>>>(x, gate_w, gate_b, decay_w, decay_b, decay_w0, gateB, rateB);

    k_scanA2<<<NBH * NCc, 256, 0, stream>>>(phiKb, Vbf, rateB, gateB, S, Dsum, Pbuf);
    k_scanB<<<NBH, 256, 0, stream>>>(S, Dsum, Pbuf);
    k_scanC2<<<NBH * NCc, 256, 0, stream>>>(phiQb, phiKb, Vbf, rateB, gateB, S, Dsum, Ybf);

    k_mfma<float, 2><<<gg, 256, 0, stream>>>(Ybf, owT, preO, nullptr, nullptr, out_b, x);
    k_ln<<<Mc, 256, 0, stream>>>(preO, ln_g, ln_b, out);
  } else {
    // ---- 33 MiB bf16-intermediate fallback (serial scan, SIMT GEMM) ----
    float* tabC  = (float*)d_ws;
    float* tabS  = tabC + (size_t)Tc * 32;
    unsigned short* phiQb = (unsigned short*)(tabS + (size_t)Tc * 32);
    unsigned short* phiKb = phiQb + MC;
    unsigned short* Vbb   = phiKb + MC;
    unsigned short* Ybb   = Vbb + MC;
    float* rateB = (float*)(Ybb + MC);
    float* gateB = rateB + BHT;
    float* preO  = (float*)phiQb;

    k_tables<<<(Tc * 32) / 256, 256, 0, stream>>>(tabC, tabS);
    k_gemm128<float, unsigned short, 1><<<gg, 256, 0, stream>>>(x, q_w, phiQb, Mc, Cc, Cc, tabC, tabS, nullptr, nullptr);
    k_gemm128<float, unsigned short, 1><<<gg, 256, 0, stream>>>(x, k_w, phiKb, Mc, Cc, Cc, tabC, tabS, nullptr, nullptr);
    k_gemm128<float, unsigned short, 0><<<gg, 256, 0, stream>>>(x, v_w, Vbb, Mc, Cc, Cc, nullptr, nullptr, nullptr, nullptr);
    k_small<<<Mc, 256, 0, stream>>>(x, gate_w, gate_b, decay_w, decay_b, decay_w0, gateB, rateB);
    k_scan<<<Bc * Hc, 256, 0, stream>>>(phiQb, phiKb, Vbb, rateB, gateB, Ybb);
    k_gemm128<unsigned short, float, 2><<<gg, 256, 0, stream>>>(Ybb, out_w, preO, Mc, Cc, Cc, nullptr, nullptr, out_b, x);
    k_ln<<<Mc, 256, 0, stream>>>(preO, ln_g, ln_b, out);
  }
}

// Round 8
// 157.772 us; speedup vs baseline: 11.0757x; 1.2553x over previous
//
#include <hip/hip_runtime.h>
#include <hip/hip_bf16.h>
#include <math.h>

static constexpr int Bc = 2, Tc = 2048, Cc = 1024, Hc = 16;
static constexpr int Mc = Bc * Tc;  // 4096 rows
static constexpr int NCc = 32, Lc = 64;  // chunks per (b,h), chunk length
static constexpr int TP = 72;  // LDS tile pitch (shorts) for scan kernels

typedef __attribute__((ext_vector_type(8))) short bf16x8;
typedef __attribute__((ext_vector_type(4))) float f32x4;

// ---------- dtype helpers ----------
__device__ __forceinline__ float bf2f(unsigned short u) {
  return __uint_as_float((unsigned)u << 16);
}
__device__ __forceinline__ unsigned short f2bf(float f) {
  __hip_bfloat16 h = __float2bfloat16(f);
  return *(unsigned short*)&h;
}
__device__ __forceinline__ float4 ld4(const float* p) { return *(const float4*)p; }
__device__ __forceinline__ float4 ld4(const unsigned short* p) {
  ushort4 u = *(const ushort4*)p;
  return make_float4(bf2f(u.x), bf2f(u.y), bf2f(u.z), bf2f(u.w));
}
__device__ __forceinline__ void stv(float* p, float v) { *p = v; }
__device__ __forceinline__ void stv(unsigned short* p, float v) { *p = f2bf(v); }

__device__ __forceinline__ void glds16(const unsigned short* src, unsigned short* dst) {
  __builtin_amdgcn_global_load_lds(
      (const __attribute__((address_space(1))) unsigned int*)src,
      (__attribute__((address_space(3))) unsigned int*)dst, 16, 0, 0);
}

// ---------------- RoPE tables ----------------
__global__ __launch_bounds__(256) void k_tables(float* __restrict__ tc, float* __restrict__ ts) {
  int i = blockIdx.x * 256 + threadIdx.x;       // < Tc*32
  int t = i >> 5, f = i & 31;
  float ivf = 1.0f / powf(10000.f, (float)f / 32.f);
  float fr = (float)t * ivf;
  tc[i] = cosf(fr);
  ts[i] = sinf(fr);
}

__device__ __forceinline__ float phi_fn(float x) { return x > 0.f ? x + 1.f : __expf(x); }

// ---------------- fp32 -> bf16 convert (x) ----------------
__global__ __launch_bounds__(256) void k_cvtx(const float* __restrict__ src, unsigned short* __restrict__ dst) {
  int i = blockIdx.x * 256 + threadIdx.x;   // 8 elems each
  float4 a = *(const float4*)&src[(size_t)i * 8];
  float4 b = *(const float4*)&src[(size_t)i * 8 + 4];
  ushort4 u0 = make_ushort4(f2bf(a.x), f2bf(a.y), f2bf(a.z), f2bf(a.w));
  ushort4 u1 = make_ushort4(f2bf(b.x), f2bf(b.y), f2bf(b.z), f2bf(b.w));
  *(ushort4*)&dst[(size_t)i * 8] = u0;
  *(ushort4*)&dst[(size_t)i * 8 + 4] = u1;
}

// ---------------- W[K][N] fp32 -> WT[N][K] bf16, 4 weights via blockIdx.z ----------------
__global__ __launch_bounds__(256) void k_trans(
    const float* __restrict__ w0, const float* __restrict__ w1,
    const float* __restrict__ w2, const float* __restrict__ w3,
    unsigned short* __restrict__ o0, unsigned short* __restrict__ o1,
    unsigned short* __restrict__ o2, unsigned short* __restrict__ o3) {
  const float* W = (blockIdx.z == 0) ? w0 : (blockIdx.z == 1) ? w1 : (blockIdx.z == 2) ? w2 : w3;
  unsigned short* O = (blockIdx.z == 0) ? o0 : (blockIdx.z == 1) ? o1 : (blockIdx.z == 2) ? o2 : o3;
  __shared__ float tile[32][33];
  int k0 = blockIdx.x * 32, n0 = blockIdx.y * 32;
  int t = threadIdx.x;
  int kk = t >> 3, nn4 = (t & 7) * 4;
  float4 v = *(const float4*)&W[(size_t)(k0 + kk) * Cc + n0 + nn4];
  tile[kk][nn4] = v.x; tile[kk][nn4 + 1] = v.y; tile[kk][nn4 + 2] = v.z; tile[kk][nn4 + 3] = v.w;
  __syncthreads();
  int nn = t >> 3, kk4 = (t & 7) * 4;
  ushort4 o = make_ushort4(f2bf(tile[kk4][nn]), f2bf(tile[kk4 + 1][nn]),
                           f2bf(tile[kk4 + 2][nn]), f2bf(tile[kk4 + 3][nn]));
  *(ushort4*)&O[(size_t)(n0 + nn) * Cc + k0 + kk4] = o;
}

// ================ pipelined MFMA GEMM core ================
// A[M][K], BT[N][K] bf16 row-major, K=Cc. Tile BM=32*FM x BN=32*FN, BK=32.
// 4 waves (2x2); wave tile (16*FM)x(16*FN). global_load_lds staging, linear LDS
// double buffer, source-side XOR swizzle blk^=(row>>1)&3 matched on ds_read.
template <int FM, int FN>
__device__ __forceinline__ void gemm_loop(const unsigned short* __restrict__ A,
    const unsigned short* __restrict__ BT,
    unsigned short* As, unsigned short* Bs, f32x4 (&acc)[FM][FN],
    int m0, int n0, int w, int l) {
  constexpr int BM = 32 * FM, BN = 32 * FN;
  constexpr int NT = Cc / 32;
  const int wr = w >> 1, wc = w & 1;
  const int lrow = l & 15, lb = l >> 4;
  const int srow = l >> 2, sblk = l & 3;

  // prologue: stage tile 0 into buffer 0
#pragma unroll
  for (int i = w; i < BM / 16; i += 4) {
    int row = i * 16 + srow;
    int blk = sblk ^ ((row >> 1) & 3);
    glds16(A + (size_t)(m0 + row) * Cc + blk * 8, As + i * 512);
  }
#pragma unroll
  for (int i = w; i < BN / 16; i += 4) {
    int row = i * 16 + srow;
    int blk = sblk ^ ((row >> 1) & 3);
    glds16(BT + (size_t)(n0 + row) * Cc + blk * 8, Bs + i * 512);
  }
  __syncthreads();

  for (int t = 0; t < NT; ++t) {
    const int cur = t & 1;
    if (t + 1 < NT) {
      const int nk = (t + 1) * 32, nb = cur ^ 1;
#pragma unroll
      for (int i = w; i < BM / 16; i += 4) {
        int row = i * 16 + srow;
        int blk = sblk ^ ((row >> 1) & 3);
        glds16(A + (size_t)(m0 + row) * Cc + nk + blk * 8, As + nb * BM * 32 + i * 512);
      }
#pragma unroll
      for (int i = w; i < BN / 16; i += 4) {
        int row = i * 16 + srow;
        int blk = sblk ^ ((row >> 1) & 3);
        glds16(BT + (size_t)(n0 + row) * Cc + nk + blk * 8, Bs + nb * BN * 32 + i * 512);
      }
    }
    const unsigned short* Ab = As + cur * BM * 32;
    const unsigned short* Bb = Bs + cur * BN * 32;
    bf16x8 af[FM], bf[FN];
#pragma unroll
    for (int fm = 0; fm < FM; ++fm) {
      int row = wr * 16 * FM + fm * 16 + lrow;
      af[fm] = *(const bf16x8*)&Ab[row * 32 + ((lb ^ ((row >> 1) & 3)) * 8)];
    }
#pragma unroll
    for (int fn = 0; fn < FN; ++fn) {
      int row = wc * 16 * FN + fn * 16 + lrow;
      bf[fn] = *(const bf16x8*)&Bb[row * 32 + ((lb ^ ((row >> 1) & 3)) * 8)];
    }
#pragma unroll
    for (int fm = 0; fm < FM; ++fm)
#pragma unroll
      for (int fn = 0; fn < FN; ++fn)
        acc[fm][fn] = __builtin_amdgcn_mfma_f32_16x16x32_bf16(af[fm], bf[fn], acc[fm][fn], 0, 0, 0);
    __syncthreads();
  }
}

// ---------------- fused Q/K/V projections (blockIdx.z selects) ----------------
__global__ __launch_bounds__(256) void k_qkv(const unsigned short* __restrict__ xbf,
    const unsigned short* __restrict__ qwT, const unsigned short* __restrict__ kwT,
    const unsigned short* __restrict__ vwT,
    unsigned short* __restrict__ Qo, unsigned short* __restrict__ Ko, unsigned short* __restrict__ Vo,
    const float* __restrict__ tabC, const float* __restrict__ tabS) {
  __shared__ unsigned short As[2 * 128 * 32];
  __shared__ unsigned short Bs[2 * 128 * 32];
  const int zz = blockIdx.z;
  const unsigned short* BT = (zz == 0) ? qwT : (zz == 1) ? kwT : vwT;
  unsigned short* Co = (zz == 0) ? Qo : (zz == 1) ? Ko : Vo;
  const int tid = threadIdx.x;
  const int l = tid & 63, w = tid >> 6;
  const int n0 = blockIdx.x * 128, m0 = blockIdx.y * 128;

  f32x4 acc[4][4];
#pragma unroll
  for (int i = 0; i < 4; ++i)
#pragma unroll
    for (int j = 0; j < 4; ++j) acc[i][j] = (f32x4){0.f, 0.f, 0.f, 0.f};

  gemm_loop<4, 4>(xbf, BT, As, Bs, acc, m0, n0, w, l);

  const int wr = w >> 1, wc = w & 1;
#pragma unroll
  for (int fm = 0; fm < 4; ++fm) {
#pragma unroll
    for (int fn = 0; fn < 4; ++fn) {
#pragma unroll
      for (int r = 0; r < 4; ++r) {
        float v = acc[fm][fn][r];
        int row = m0 + wr * 64 + fm * 16 + (l >> 4) * 4 + r;
        int col = n0 + wc * 64 + fn * 16 + (l & 15);
        if (zz < 2) {
          float p = __shfl_xor(v, 1);
          int t = row & (Tc - 1);
          int pi = (col & 63) >> 1;
          float cv = tabC[t * 32 + pi], sv = tabS[t * 32 + pi];
          float res = (col & 1) ? (p * sv + v * cv) : (v * cv - p * sv);
          Co[(size_t)row * Cc + col] = f2bf(phi_fn(res));
        } else {
          Co[(size_t)row * Cc + col] = f2bf(v);
        }
      }
    }
  }
}

// ---------------- out-proj: 64x128 tile, +bias +residual -> fp32 ----------------
__global__ __launch_bounds__(256) void k_oproj(const unsigned short* __restrict__ Ybf,
    const unsigned short* __restrict__ owT, float* __restrict__ Co,
    const float* __restrict__ bias, const float* __restrict__ resid) {
  __shared__ unsigned short As[2 * 64 * 32];
  __shared__ unsigned short Bs[2 * 128 * 32];
  const int tid = threadIdx.x;
  const int l = tid & 63, w = tid >> 6;
  const int n0 = blockIdx.x * 128, m0 = blockIdx.y * 64;

  f32x4 acc[2][4];
#pragma unroll
  for (int i = 0; i < 2; ++i)
#pragma unroll
    for (int j = 0; j < 4; ++j) acc[i][j] = (f32x4){0.f, 0.f, 0.f, 0.f};

  gemm_loop<2, 4>(Ybf, owT, As, Bs, acc, m0, n0, w, l);

  const int wr = w >> 1, wc = w & 1;
#pragma unroll
  for (int fm = 0; fm < 2; ++fm) {
#pragma unroll
    for (int fn = 0; fn < 4; ++fn) {
#pragma unroll
      for (int r = 0; r < 4; ++r) {
        int row = m0 + wr * 32 + fm * 16 + (l >> 4) * 4 + r;
        int col = n0 + wc * 64 + fn * 16 + (l & 15);
        Co[(size_t)row * Cc + col] = acc[fm][fn][r] + bias[col] + resid[(size_t)row * Cc + col];
      }
    }
  }
}

// ---------------- legacy fp32 SIMT GEMM (fallback path only) ----------------
template <typename AT, typename OT, int MODE>
__global__ __launch_bounds__(256) void k_gemm128(
    const AT* __restrict__ A, const float* __restrict__ Bw, OT* __restrict__ Co,
    int M, int N, int K,
    const float* __restrict__ tabC, const float* __restrict__ tabS,
    const float* __restrict__ bias, const float* __restrict__ resid) {
  __shared__ float As[16][132];
  __shared__ float Bs[16][132];
  const int tid = threadIdx.x;
  const int tx = tid & 15, ty = tid >> 4;
  const int n0 = blockIdx.x * 128, m0 = blockIdx.y * 128;
  float acc[8][8];
#pragma unroll
  for (int i = 0; i < 8; ++i)
#pragma unroll
    for (int j = 0; j < 8; ++j) acc[i][j] = 0.f;
  for (int k0 = 0; k0 < K; k0 += 16) {
#pragma unroll
    for (int rep = 0; rep < 2; ++rep) {
      int lin = tid + rep * 256;
      int r = lin >> 2, c4 = (lin & 3) << 2;
      float4 av = ld4(&A[(size_t)(m0 + r) * K + k0 + c4]);
      As[c4 + 0][r] = av.x; As[c4 + 1][r] = av.y;
      As[c4 + 2][r] = av.z; As[c4 + 3][r] = av.w;
      int rb = lin >> 5, cb = (lin & 31) << 2;
      *(float4*)&Bs[rb][cb] = *(const float4*)&Bw[(size_t)(k0 + rb) * N + n0 + cb];
    }
    __syncthreads();
#pragma unroll
    for (int kk = 0; kk < 16; ++kk) {
      float4 a0 = *(const float4*)&As[kk][ty * 8];
      float4 a1 = *(const float4*)&As[kk][ty * 8 + 4];
      float4 b0 = *(const float4*)&Bs[kk][tx * 8];
      float4 b1 = *(const float4*)&Bs[kk][tx * 8 + 4];
      float avv[8] = {a0.x, a0.y, a0.z, a0.w, a1.x, a1.y, a1.z, a1.w};
      float bvv[8] = {b0.x, b0.y, b0.z, b0.w, b1.x, b1.y, b1.z, b1.w};
#pragma unroll
      for (int i = 0; i < 8; ++i)
#pragma unroll
        for (int j = 0; j < 8; ++j) acc[i][j] = fmaf(avv[i], bvv[j], acc[i][j]);
    }
    __syncthreads();
  }
  if constexpr (MODE == 1) {
#pragma unroll
    for (int i = 0; i < 8; ++i) {
      int row = m0 + ty * 8 + i;
      int t = row & (Tc - 1);
#pragma unroll
      for (int j = 0; j < 8; j += 2) {
        int col = n0 + tx * 8 + j;
        int pi = (col & 63) >> 1;
        float cv = tabC[t * 32 + pi], sv = tabS[t * 32 + pi];
        float xe = acc[i][j], xo = acc[i][j + 1];
        stv(&Co[(size_t)row * N + col], phi_fn(xe * cv - xo * sv));
        stv(&Co[(size_t)row * N + col + 1], phi_fn(xe * sv + xo * cv));
      }
    }
  } else if constexpr (MODE == 2) {
#pragma unroll
    for (int i = 0; i < 8; ++i) {
      int row = m0 + ty * 8 + i;
#pragma unroll
      for (int j = 0; j < 8; ++j) {
        int col = n0 + tx * 8 + j;
        stv(&Co[(size_t)row * N + col], acc[i][j] + bias[col] + resid[(size_t)row * N + col]);
      }
    }
  } else {
#pragma unroll
    for (int i = 0; i < 8; ++i) {
      int row = m0 + ty * 8 + i;
#pragma unroll
      for (int j = 0; j < 8; ++j) {
        int col = n0 + tx * 8 + j;
        stv(&Co[(size_t)row * N + col], acc[i][j]);
      }
    }
  }
}

// ---------------- gate / decay projections (N=32); writes RATE ----------------
__global__ __launch_bounds__(256) void k_small(
    const float* __restrict__ x, const float* __restrict__ gate_w, const float* __restrict__ gate_b,
    const float* __restrict__ decay_w, const float* __restrict__ decay_b,
    const float* __restrict__ decay_w0, float* __restrict__ gate_o, float* __restrict__ rate_o) {
  __shared__ float xs[1024];
  __shared__ float part[8][32];
  int bt = blockIdx.x;
  int tid = threadIdx.x;
  *(float4*)&xs[tid * 4] = *(const float4*)&x[(size_t)bt * Cc + tid * 4];
  __syncthreads();
  int o = tid & 31, seg = tid >> 5;
  const float* wp = (o < 16) ? gate_w : decay_w;
  int oc = o & 15;
  float p = 0.f;
  int kb = seg * 128;
#pragma unroll 4
  for (int kk = 0; kk < 128; ++kk) {
    int k = kb + kk;
    p = fmaf(xs[k], wp[(size_t)k * 16 + oc], p);
  }
  part[seg][o] = p;
  __syncthreads();
  if (tid < 32) {
    float s = 0.f;
#pragma unroll
    for (int sg = 0; sg < 8; ++sg) s += part[sg][tid];
    int b = bt >> 11, t = bt & (Tc - 1);
    if (tid < 16) {
      float gv = 1.f / (1.f + expf(-(s + gate_b[tid])));
      gate_o[((size_t)(b * Hc + tid)) * Tc + t] = gv;
    } else {
      int hh = tid - 16;
      float raw = s + decay_b[hh] + decay_w0[hh];
      float sp = raw > 20.f ? raw : log1pf(expf(raw));
      float rate = fminf(fmaxf(sp, 1e-4f), 10.f);
      rate_o[((size_t)(b * Hc + hh)) * Tc + t] = rate;
    }
  }
}

// ---------------- Phase A (MFMA): per-chunk summaries S^T[e][d], Dsum[d], P ----------------
__global__ __launch_bounds__(256) void k_scanA2(
    const unsigned short* __restrict__ Kb, const unsigned short* __restrict__ Vb,
    const float* __restrict__ rateB, const float* __restrict__ gateB,
    unsigned short* __restrict__ S, float* __restrict__ Dsum, float* __restrict__ Pbuf) {
  int blk = blockIdx.x;
  int bh = blk >> 5, c = blk & 31;
  int b = bh >> 4, h = bh & 15;
  int tid = threadIdx.x;
  int l = tid & 63, wv = tid >> 6;
  __shared__ unsigned short KT[64 * TP];   // [d][s]
  __shared__ unsigned short VT[64 * TP];   // [e][s], scaled by w_s
  __shared__ float Rc[64], gs[64], ws[64];
  size_t base = ((size_t)b * Tc + (size_t)c * 64) * Cc + h * 64;
  {
    int s = tid >> 2, d0g = (tid & 3) * 16;
    const unsigned short* kr = Kb + base + (size_t)s * Cc + d0g;
    unsigned short kv[16];
    *(uint4*)kv = *(const uint4*)kr; *(uint4*)(kv + 8) = *(const uint4*)(kr + 8);
#pragma unroll
    for (int i = 0; i < 16; ++i) KT[(d0g + i) * TP + s] = kv[i];
  }
  if (wv == 0) {
    float r = rateB[(size_t)bh * Tc + c * 64 + l];
    float g = gateB[(size_t)bh * Tc + c * 64 + l];
    float v = r;
#pragma unroll
    for (int off = 1; off < 64; off <<= 1) { float u = __shfl_up(v, off); if (l >= off) v += u; }
    Rc[l] = v; gs[l] = g;
  }
  __syncthreads();
  float Rtot = Rc[63];
  if (wv == 0) ws[l] = __expf(Rc[l] - Rtot) * gs[l];
  __syncthreads();
  {
    int s = tid >> 2, e0g = (tid & 3) * 16;
    float wsv = ws[s];
    const unsigned short* vr = Vb + base + (size_t)s * Cc + e0g;
    unsigned short vvv[16];
    *(uint4*)vvv = *(const uint4*)vr; *(uint4*)(vvv + 8) = *(const uint4*)(vr + 8);
#pragma unroll
    for (int i = 0; i < 16; ++i) VT[(e0g + i) * TP + s] = f2bf(bf2f(vvv[i]) * wsv);
  }
  __syncthreads();
  f32x4 acc[4];
#pragma unroll
  for (int i = 0; i < 4; ++i) acc[i] = (f32x4){0.f, 0.f, 0.f, 0.f};
  const int lrow = l & 15, lk8 = (l >> 4) * 8;
#pragma unroll
  for (int ks = 0; ks < 2; ++ks) {
    bf16x8 a = *(const bf16x8*)&VT[(wv * 16 + lrow) * TP + ks * 32 + lk8];
#pragma unroll
    for (int fn = 0; fn < 4; ++fn) {
      bf16x8 bb = *(const bf16x8*)&KT[(fn * 16 + lrow) * TP + ks * 32 + lk8];
      acc[fn] = __builtin_amdgcn_mfma_f32_16x16x32_bf16(a, bb, acc[fn], 0, 0, 0);
    }
  }
  size_t sb = (size_t)blk * 4096;
#pragma unroll
  for (int fn = 0; fn < 4; ++fn)
#pragma unroll
    for (int r = 0; r < 4; ++r) {
      int e = wv * 16 + (l >> 4) * 4 + r;
      int d = fn * 16 + (l & 15);
      S[sb + e * 64 + d] = f2bf(acc[fn][r]);
    }
  if (tid < 64) {
    float s = 0.f;
#pragma unroll 8
    for (int ss = 0; ss < 64; ++ss) s += bf2f(KT[tid * TP + ss]) * ws[ss];
    Dsum[(size_t)blk * 64 + tid] = s;
  }
  if (tid == 0) Pbuf[blk] = __expf(-Rtot);
}

// ---------------- Phase B: serial carry across chunks (1-deep prefetch) ----------------
__global__ __launch_bounds__(256) void k_scanB(unsigned short* __restrict__ S, float* __restrict__ Dsum,
                                               const float* __restrict__ Pbuf) {
  int bh = blockIdx.x;
  int tid = threadIdx.x;
  float Nreg[16];
#pragma unroll
  for (int k = 0; k < 16; ++k) Nreg[k] = 0.f;
  float Dreg = 0.f;
  unsigned short curS[16]; float curD = 0.f, curP;
  {
    size_t sb = ((size_t)bh * NCc) * 4096;
#pragma unroll
    for (int k = 0; k < 16; ++k) curS[k] = S[sb + tid + k * 256];
    if (tid < 64) curD = Dsum[((size_t)bh * NCc) * 64 + tid];
    curP = Pbuf[bh * NCc];
  }
  for (int c = 0; c < NCc; ++c) {
    unsigned short nxtS[16]; float nxtD = 0.f, nxtP = 0.f;
    if (c + 1 < NCc) {
      size_t sb = ((size_t)bh * NCc + c + 1) * 4096;
#pragma unroll
      for (int k = 0; k < 16; ++k) nxtS[k] = S[sb + tid + k * 256];
      if (tid < 64) nxtD = Dsum[((size_t)bh * NCc + c + 1) * 64 + tid];
      nxtP = Pbuf[bh * NCc + c + 1];
    }
    size_t sb = ((size_t)bh * NCc + c) * 4096;
#pragma unroll
    for (int k = 0; k < 16; ++k) {
      float tmp = bf2f(curS[k]);
      S[sb + tid + k * 256] = f2bf(Nreg[k]);
      Nreg[k] = Nreg[k] * curP + tmp;
    }
    if (tid < 64) {
      size_t db = ((size_t)bh * NCc + c) * 64 + tid;
      float tmp = curD;
      Dsum[db] = Dreg;
      Dreg = Dreg * curP + tmp;
    }
#pragma unroll
    for (int k = 0; k < 16; ++k) curS[k] = nxtS[k];
    curD = nxtD; curP = nxtP;
  }
}

// ---------------- Phase C (MFMA): intra-chunk + start-state, full output ----------------
__global__ __launch_bounds__(256) void k_scanC2(
    const unsigned short* __restrict__ Qb, const unsigned short* __restrict__ Kb,
    const unsigned short* __restrict__ Vb,
    const float* __restrict__ rateB, const float* __restrict__ gateB,
    const unsigned short* __restrict__ S, const float* __restrict__ Dsum,
    unsigned short* __restrict__ Yb) {
  int blk = blockIdx.x;
  int bh = blk >> 5, c = blk & 31;
  int b = bh >> 4, h = bh & 15;
  int tid = threadIdx.x;
  int l = tid & 63, wv = tid >> 6;
  __shared__ unsigned short Qs[64 * TP];
  __shared__ unsigned short Ks[64 * TP];   // overlaid by W' after QK
  __shared__ unsigned short VT[64 * TP];
  __shared__ unsigned short Ss[64 * TP];
  __shared__ float Rc[64], gs[64], DstL[64];
  size_t base = ((size_t)b * Tc + (size_t)c * 64) * Cc + h * 64;
  {
    int rr = tid >> 2, c0 = (tid & 3) * 16;
    const unsigned short* qr = Qb + base + (size_t)rr * Cc + c0;
    const unsigned short* kr = Kb + base + (size_t)rr * Cc + c0;
    const unsigned short* vr = Vb + base + (size_t)rr * Cc + c0;
    const unsigned short* sr = S + (size_t)blk * 4096 + rr * 64 + c0;
    *(uint4*)&Qs[rr * TP + c0] = *(const uint4*)qr;
    *(uint4*)&Qs[rr * TP + c0 + 8] = *(const uint4*)(qr + 8);
    *(uint4*)&Ks[rr * TP + c0] = *(const uint4*)kr;
    *(uint4*)&Ks[rr * TP + c0 + 8] = *(const uint4*)(kr + 8);
    *(uint4*)&Ss[rr * TP + c0] = *(const uint4*)sr;
    *(uint4*)&Ss[rr * TP + c0 + 8] = *(const uint4*)(sr + 8);
    unsigned short vvv[16];
    *(uint4*)vvv = *(const uint4*)vr; *(uint4*)(vvv + 8) = *(const uint4*)(vr + 8);
#pragma unroll
    for (int i = 0; i < 16; ++i) VT[(c0 + i) * TP + rr] = vvv[i];
  }
  if (wv == 0) {
    float r = rateB[(size_t)bh * Tc + c * 64 + l];
    float g = gateB[(size_t)bh * Tc + c * 64 + l];
    float v = r;
#pragma unroll
    for (int off = 1; off < 64; off <<= 1) { float u = __shfl_up(v, off); if (l >= off) v += u; }
    Rc[l] = v; gs[l] = g;
    DstL[l] = Dsum[(size_t)blk * 64 + l];
  }
  __syncthreads();
  const int lrow = l & 15, lk8 = (l >> 4) * 8;
  f32x4 qk[4];
#pragma unroll
  for (int i = 0; i < 4; ++i) qk[i] = (f32x4){0.f, 0.f, 0.f, 0.f};
#pragma unroll
  for (int ks = 0; ks < 2; ++ks) {
    bf16x8 a = *(const bf16x8*)&Qs[(wv * 16 + lrow) * TP + ks * 32 + lk8];
#pragma unroll
    for (int fn = 0; fn < 4; ++fn) {
      bf16x8 bb = *(const bf16x8*)&Ks[(fn * 16 + lrow) * TP + ks * 32 + lk8];
      qk[fn] = __builtin_amdgcn_mfma_f32_16x16x32_bf16(a, bb, qk[fn], 0, 0, 0);
    }
  }
  __syncthreads();
  float deni[4] = {0.f, 0.f, 0.f, 0.f};
  float rct[4];
#pragma unroll
  for (int r = 0; r < 4; ++r) rct[r] = Rc[wv * 16 + (l >> 4) * 4 + r];
#pragma unroll
  for (int fn = 0; fn < 4; ++fn) {
    int s = fn * 16 + (l & 15);
    float rs = Rc[s], g = gs[s];
#pragma unroll
    for (int r = 0; r < 4; ++r) {
      int t = wv * 16 + (l >> 4) * 4 + r;
      float wgt = (s <= t) ? __expf(rs - rct[r]) * g : 0.f;
      unsigned short sb16 = f2bf(qk[fn][r] * wgt);
      deni[r] += bf2f(sb16);
      Ks[t * TP + s] = sb16;
    }
  }
#pragma unroll
  for (int r = 0; r < 4; ++r) {
    deni[r] += __shfl_xor(deni[r], 1);
    deni[r] += __shfl_xor(deni[r], 2);
    deni[r] += __shfl_xor(deni[r], 4);
    deni[r] += __shfl_xor(deni[r], 8);
  }
  f32x4 nm[4], nm2[4], dn2;
#pragma unroll
  for (int i = 0; i < 4; ++i) { nm[i] = (f32x4){0.f,0.f,0.f,0.f}; nm2[i] = (f32x4){0.f,0.f,0.f,0.f}; }
  dn2 = (f32x4){0.f, 0.f, 0.f, 0.f};
#pragma unroll
  for (int ks = 0; ks < 2; ++ks) {
    bf16x8 aw = *(const bf16x8*)&Ks[(wv * 16 + lrow) * TP + ks * 32 + lk8];
    bf16x8 aq = *(const bf16x8*)&Qs[(wv * 16 + lrow) * TP + ks * 32 + lk8];
#pragma unroll
    for (int fn = 0; fn < 4; ++fn) {
      bf16x8 bv = *(const bf16x8*)&VT[(fn * 16 + lrow) * TP + ks * 32 + lk8];
      bf16x8 bs = *(const bf16x8*)&Ss[(fn * 16 + lrow) * TP + ks * 32 + lk8];
      nm[fn] = __builtin_amdgcn_mfma_f32_16x16x32_bf16(aw, bv, nm[fn], 0, 0, 0);
      nm2[fn] = __builtin_amdgcn_mfma_f32_16x16x32_bf16(aq, bs, nm2[fn], 0, 0, 0);
    }
    bf16x8 bd = (bf16x8){0, 0, 0, 0, 0, 0, 0, 0};
    if (lrow == 0) {
#pragma unroll
      for (int i = 0; i < 8; ++i) bd[i] = (short)f2bf(DstL[ks * 32 + lk8 + i]);
    }
    dn2 = __builtin_amdgcn_mfma_f32_16x16x32_bf16(aq, bd, dn2, 0, 0, 0);
  }
  float den2v[4];
#pragma unroll
  for (int r = 0; r < 4; ++r) den2v[r] = __shfl(dn2[r], (l & 48));
#pragma unroll
  for (int r = 0; r < 4; ++r) {
    int t = wv * 16 + (l >> 4) * 4 + r;
    float at = __expf(-rct[r]);
    float dv = deni[r] + at * den2v[r] + 1e-6f;
#pragma unroll
    for (int fn = 0; fn < 4; ++fn) {
      int e = fn * 16 + (l & 15);
      float numv = nm[fn][r] + at * nm2[fn][r];
      Yb[base + (size_t)t * Cc + e] = f2bf(numv / dv);
    }
  }
}

// ---------------- legacy serial scan (fallback path only; rate input) ----------------
__device__ __forceinline__ void load16(const unsigned short* __restrict__ p, float* d) {
  uint4 u = *(const uint4*)p;
  uint4 v = *(const uint4*)(p + 8);
  d[0] = __uint_as_float(u.x << 16); d[1] = __uint_as_float(u.x & 0xFFFF0000u);
  d[2] = __uint_as_float(u.y << 16); d[3] = __uint_as_float(u.y & 0xFFFF0000u);
  d[4] = __uint_as_float(u.z << 16); d[5] = __uint_as_float(u.z & 0xFFFF0000u);
  d[6] = __uint_as_float(u.w << 16); d[7] = __uint_as_float(u.w & 0xFFFF0000u);
  d[8] = __uint_as_float(v.x << 16); d[9] = __uint_as_float(v.x & 0xFFFF0000u);
  d[10] = __uint_as_float(v.y << 16); d[11] = __uint_as_float(v.y & 0xFFFF0000u);
  d[12] = __uint_as_float(v.z << 16); d[13] = __uint_as_float(v.z & 0xFFFF0000u);
  d[14] = __uint_as_float(v.w << 16); d[15] = __uint_as_float(v.w & 0xFFFF0000u);
}

__global__ __launch_bounds__(256) void k_scan(const unsigned short* __restrict__ phiQ,
    const unsigned short* __restrict__ phiK, const unsigned short* __restrict__ Vb,
    const float* __restrict__ rateB, const float* __restrict__ gateB,
    unsigned short* __restrict__ Yb) {
  int bh = blockIdx.x;
  int b = bh >> 4, h = bh & 15;
  int tid = threadIdx.x;
  int w = tid >> 6, l = tid & 63;
  int e = (w << 4) | (l & 15);
  int d0 = (l >> 4) << 4;
  size_t base = ((size_t)b * Tc) * Cc + h * 64;
  const unsigned short* qp = phiQ + base + d0;
  const unsigned short* kp = phiK + base + d0;
  const unsigned short* vp = Vb + base + e;
  const float* bp = rateB + (size_t)bh * Tc;
  const float* gp = gateB + (size_t)bh * Tc;
  unsigned short* yp = Yb + base + e;
  float Ns[16], Ds[16];
#pragma unroll
  for (int j = 0; j < 16; ++j) { Ns[j] = 0.f; Ds[j] = 0.f; }
  const bool wr = (l < 16);
  for (int t = 0; t < Tc; ++t) {
    float q[16], k[16];
    load16(qp + (size_t)t * Cc, q);
    load16(kp + (size_t)t * Cc, k);
    float vv = bf2f(vp[(size_t)t * Cc]);
    float btv = __expf(-bp[t]), gtv = gp[t];
    float yn = 0.f, den = 0.f;
#pragma unroll
    for (int j = 0; j < 16; ++j) {
      float wj = k[j] * gtv;
      float ns = fmaf(Ns[j], btv, wj * vv);
      float ds = fmaf(Ds[j], btv, wj);
      Ns[j] = ns; Ds[j] = ds;
      yn = fmaf(q[j], ns, yn);
      den = fmaf(q[j], ds, den);
    }
    yn += __shfl_xor(yn, 16); yn += __shfl_xor(yn, 32);
    den += __shfl_xor(den, 16); den += __shfl_xor(den, 32);
    if (wr) yp[(size_t)t * Cc] = f2bf(yn / (den + 1e-6f));
  }
}

// ---------------- row LayerNorm -> fp32 out ----------------
__global__ __launch_bounds__(256) void k_ln(const float* __restrict__ pre, const float* __restrict__ ln_g,
    const float* __restrict__ ln_b, float* __restrict__ out) {
  int row = blockIdx.x;
  int tid = threadIdx.x;
  float4 v = *(const float4*)&pre[(size_t)row * Cc + tid * 4];
  float s = v.x + v.y + v.z + v.w;
  float q = v.x * v.x + v.y * v.y + v.z * v.z + v.w * v.w;
#pragma unroll
  for (int off = 1; off < 64; off <<= 1) {
    s += __shfl_xor(s, off);
    q += __shfl_xor(q, off);
  }
  __shared__ float ss[4], qq[4];
  if ((tid & 63) == 0) { ss[tid >> 6] = s; qq[tid >> 6] = q; }
  __syncthreads();
  s = ss[0] + ss[1] + ss[2] + ss[3];
  q = qq[0] + qq[1] + qq[2] + qq[3];
  float mu = s * (1.f / 1024.f);
  float var = q * (1.f / 1024.f) - mu * mu;
  float rstd = rsqrtf(var + 1e-5f);
  int c0 = tid * 4;
  float4 g = *(const float4*)&ln_g[c0];
  float4 bb = *(const float4*)&ln_b[c0];
  float4 o;
  o.x = (v.x - mu) * rstd * g.x + bb.x;
  o.y = (v.y - mu) * rstd * g.y + bb.y;
  o.z = (v.z - mu) * rstd * g.z + bb.z;
  o.w = (v.w - mu) * rstd * g.w + bb.w;
  *(float4*)&out[(size_t)row * Cc + c0] = o;
}

extern "C" void kernel_launch(void* const* d_in, const int* in_sizes, int n_in,
                              void* d_out, int out_size, void* d_ws, size_t ws_size,
                              hipStream_t stream) {
  const float* x        = (const float*)d_in[0];
  const float* q_w      = (const float*)d_in[1];
  const float* k_w      = (const float*)d_in[2];
  const float* v_w      = (const float*)d_in[3];
  const float* out_w    = (const float*)d_in[4];
  const float* out_b    = (const float*)d_in[5];
  const float* decay_w  = (const float*)d_in[6];
  const float* decay_b  = (const float*)d_in[7];
  const float* gate_w   = (const float*)d_in[8];
  const float* gate_b   = (const float*)d_in[9];
  const float* decay_w0 = (const float*)d_in[10];
  const float* ln_g     = (const float*)d_in[11];
  const float* ln_b     = (const float*)d_in[12];
  float* out            = (float*)d_out;

  const size_t MC  = (size_t)Mc * Cc;
  const size_t BHT = (size_t)Bc * Hc * Tc;
  const int NBH = Bc * Hc;                 // 32

  const bool fp32path = ws_size >= (size_t)52 * 1024 * 1024;

  if (fp32path) {
    char* p = (char*)d_ws;
    float* tabC = (float*)p;                    p += (size_t)Tc * 32 * 4;
    float* tabS = (float*)p;                    p += (size_t)Tc * 32 * 4;
    unsigned short* xbf   = (unsigned short*)p; p += MC * 2;        // S aliases (8 MiB)
    unsigned short* qwT   = (unsigned short*)p; p += (size_t)Cc * Cc * 2;
    unsigned short* kwT   = (unsigned short*)p; p += (size_t)Cc * Cc * 2;
    unsigned short* vwT   = (unsigned short*)p; p += (size_t)Cc * Cc * 2;
    unsigned short* owT   = (unsigned short*)p; p += (size_t)Cc * Cc * 2;
    unsigned short* phiQb = (unsigned short*)p; p += MC * 2;        // preO overlays phiQb+Vbf
    unsigned short* Vbf   = (unsigned short*)p; p += MC * 2;
    unsigned short* phiKb = (unsigned short*)p; p += MC * 2;
    unsigned short* Ybf   = (unsigned short*)p; p += MC * 2;
    float* rateB = (float*)p;                   p += BHT * 4;
    float* gateB = (float*)p;                   p += BHT * 4;
    float* Dsum  = (float*)p;                   p += (size_t)NBH * NCc * 64 * 4;
    float* Pbuf  = (float*)p;                   p += (size_t)NBH * NCc * 4;
    unsigned short* S = xbf;                    // xbf dead after projection GEMMs
    float* preO = (float*)phiQb;                // phiQb+Vbf dead after scanC2

    k_tables<<<(Tc * 32) / 256, 256, 0, stream>>>(tabC, tabS);
    k_cvtx<<<(int)(MC / 8 / 256), 256, 0, stream>>>(x, xbf);
    k_trans<<<dim3(Cc / 32, Cc / 32, 4), 256, 0, stream>>>(q_w, k_w, v_w, out_w, qwT, kwT, vwT, owT);
    k_small<<<Mc, 256, 0, stream>>>(x, gate_w, gate_b, decay_w, decay_b, decay_w0, gateB, rateB);

    k_qkv<<<dim3(Cc / 128, Mc / 128, 3), 256, 0, stream>>>(xbf, qwT, kwT, vwT,
                                                           phiQb, phiKb, Vbf, tabC, tabS);

    k_scanA2<<<NBH * NCc, 256, 0, stream>>>(phiKb, Vbf, rateB, gateB, S, Dsum, Pbuf);
    k_scanB<<<NBH, 256, 0, stream>>>(S, Dsum, Pbuf);
    k_scanC2<<<NBH * NCc, 256, 0, stream>>>(phiQb, phiKb, Vbf, rateB, gateB, S, Dsum, Ybf);

    k_oproj<<<dim3(Cc / 128, Mc / 64), 256, 0, stream>>>(Ybf, owT, preO, out_b, x);
    k_ln<<<Mc, 256, 0, stream>>>(preO, ln_g, ln_b, out);
  } else {
    // ---- 33 MiB bf16-intermediate fallback (serial scan, SIMT GEMM) ----
    float* tabC  = (float*)d_ws;
    float* tabS  = tabC + (size_t)Tc * 32;
    unsigned short* phiQb = (unsigned short*)(tabS + (size_t)Tc * 32);
    unsigned short* phiKb = phiQb + MC;
    unsigned short* Vbb   = phiKb + MC;
    unsigned short* Ybb   = Vbb + MC;
    float* rateB = (float*)(Ybb + MC);
    float* gateB = rateB + BHT;
    float* preO  = (float*)phiQb;
    dim3 gg(Cc / 128, Mc / 128);

    k_tables<<<(Tc * 32) / 256, 256, 0, stream>>>(tabC, tabS);
    k_gemm128<float, unsigned short, 1><<<gg, 256, 0, stream>>>(x, q_w, phiQb, Mc, Cc, Cc, tabC, tabS, nullptr, nullptr);
    k_gemm128<float, unsigned short, 1><<<gg, 256, 0, stream>>>(x, k_w, phiKb, Mc, Cc, Cc, tabC, tabS, nullptr, nullptr);
    k_gemm128<float, unsigned short, 0><<<gg, 256, 0, stream>>>(x, v_w, Vbb, Mc, Cc, Cc, nullptr, nullptr, nullptr, nullptr);
    k_small<<<Mc, 256, 0, stream>>>(x, gate_w, gate_b, decay_w, decay_b, decay_w0, gateB, rateB);
    k_scan<<<Bc * Hc, 256, 0, stream>>>(phiQb, phiKb, Vbb, rateB, gateB, Ybb);
    k_gemm128<unsigned short, float, 2><<<gg, 256, 0, stream>>>(Ybb, out_w, preO, Mc, Cc, Cc, nullptr, nullptr, out_b, x);
    k_ln<<<Mc, 256, 0, stream>>>(preO, ln_g, ln_b, out);
  }
}

// Round 9
// 143.648 us; speedup vs baseline: 12.1647x; 1.0983x over previous
//
#include <hip/hip_runtime.h>
#include <hip/hip_bf16.h>
#include <math.h>

static constexpr int Bc = 2, Tc = 2048, Cc = 1024, Hc = 16;
static constexpr int Mc = Bc * Tc;  // 4096 rows
static constexpr int NCc = 32, Lc = 64;  // chunks per (b,h), chunk length
static constexpr int TP = 72;  // LDS tile pitch (shorts) for scan kernels

typedef __attribute__((ext_vector_type(8))) short bf16x8;
typedef __attribute__((ext_vector_type(4))) float f32x4;

// ---------- dtype helpers ----------
__device__ __forceinline__ float bf2f(unsigned short u) {
  return __uint_as_float((unsigned)u << 16);
}
__device__ __forceinline__ unsigned short f2bf(float f) {
  __hip_bfloat16 h = __float2bfloat16(f);
  return *(unsigned short*)&h;
}
__device__ __forceinline__ float4 ld4(const float* p) { return *(const float4*)p; }
__device__ __forceinline__ float4 ld4(const unsigned short* p) {
  ushort4 u = *(const ushort4*)p;
  return make_float4(bf2f(u.x), bf2f(u.y), bf2f(u.z), bf2f(u.w));
}
__device__ __forceinline__ void stv(float* p, float v) { *p = v; }
__device__ __forceinline__ void stv(unsigned short* p, float v) { *p = f2bf(v); }

__device__ __forceinline__ void glds16(const unsigned short* src, unsigned short* dst) {
  __builtin_amdgcn_global_load_lds(
      (const __attribute__((address_space(1))) unsigned int*)src,
      (__attribute__((address_space(3))) unsigned int*)dst, 16, 0, 0);
}

// ---------------- RoPE tables ----------------
__global__ __launch_bounds__(256) void k_tables(float* __restrict__ tc, float* __restrict__ ts) {
  int i = blockIdx.x * 256 + threadIdx.x;       // < Tc*32
  int t = i >> 5, f = i & 31;
  float ivf = 1.0f / powf(10000.f, (float)f / 32.f);
  float fr = (float)t * ivf;
  tc[i] = cosf(fr);
  ts[i] = sinf(fr);
}

__device__ __forceinline__ float phi_fn(float x) { return x > 0.f ? x + 1.f : __expf(x); }

// ---------------- W[K][N] fp32 -> WT[N][K] bf16, 4 weights via blockIdx.z ----------------
__global__ __launch_bounds__(256) void k_trans(
    const float* __restrict__ w0, const float* __restrict__ w1,
    const float* __restrict__ w2, const float* __restrict__ w3,
    unsigned short* __restrict__ o0, unsigned short* __restrict__ o1,
    unsigned short* __restrict__ o2, unsigned short* __restrict__ o3) {
  const float* W = (blockIdx.z == 0) ? w0 : (blockIdx.z == 1) ? w1 : (blockIdx.z == 2) ? w2 : w3;
  unsigned short* O = (blockIdx.z == 0) ? o0 : (blockIdx.z == 1) ? o1 : (blockIdx.z == 2) ? o2 : o3;
  __shared__ float tile[32][33];
  int k0 = blockIdx.x * 32, n0 = blockIdx.y * 32;
  int t = threadIdx.x;
  int kk = t >> 3, nn4 = (t & 7) * 4;
  float4 v = *(const float4*)&W[(size_t)(k0 + kk) * Cc + n0 + nn4];
  tile[kk][nn4] = v.x; tile[kk][nn4 + 1] = v.y; tile[kk][nn4 + 2] = v.z; tile[kk][nn4 + 3] = v.w;
  __syncthreads();
  int nn = t >> 3, kk4 = (t & 7) * 4;
  ushort4 o = make_ushort4(f2bf(tile[kk4][nn]), f2bf(tile[kk4 + 1][nn]),
                           f2bf(tile[kk4 + 2][nn]), f2bf(tile[kk4 + 3][nn]));
  *(ushort4*)&O[(size_t)(n0 + nn) * Cc + k0 + kk4] = o;
}

// ================ pipelined MFMA GEMM core (counted-vmcnt, 3-buffer) ================
// A[M][K], BT[N][K] bf16 row-major, K=Cc. Tile BM=32*FM x BN=32*FN, BK=32.
// 4 waves (2x2); wave tile (16*FM)x(16*FN). global_load_lds staging into 3 LDS
// buffers; raw s_barrier + s_waitcnt vmcnt(NL) (never 0 mid-loop) keeps 1 tile in flight.
// Source-side XOR swizzle blk^=(row>>1)&3, matched on ds_read.
template <int FM, int FN>
__device__ __forceinline__ void stage_tiles(const unsigned short* __restrict__ A,
    const unsigned short* __restrict__ BT, unsigned short* As, unsigned short* Bs,
    int buf, int kt, int m0, int n0, int w, int l) {
  constexpr int BM = 32 * FM, BN = 32 * FN;
  const int srow = l >> 2, sblk = l & 3;
  const int k0 = kt * 32;
#pragma unroll
  for (int i = w; i < BM / 16; i += 4) {
    int row = i * 16 + srow;
    int blk = sblk ^ ((row >> 1) & 3);
    glds16(A + (size_t)(m0 + row) * Cc + k0 + blk * 8, As + buf * (BM * 32) + i * 512);
  }
#pragma unroll
  for (int i = w; i < BN / 16; i += 4) {
    int row = i * 16 + srow;
    int blk = sblk ^ ((row >> 1) & 3);
    glds16(BT + (size_t)(n0 + row) * Cc + k0 + blk * 8, Bs + buf * (BN * 32) + i * 512);
  }
}

template <int FM, int FN>
__device__ __forceinline__ void gemm_loop(const unsigned short* __restrict__ A,
    const unsigned short* __restrict__ BT,
    unsigned short* As, unsigned short* Bs, f32x4 (&acc)[FM][FN],
    int m0, int n0, int w, int l) {
  constexpr int BM = 32 * FM, BN = 32 * FN;
  constexpr int NT = Cc / 32;
  constexpr int NL = (BM + BN) / 64;   // glds16 per wave per stage
  const int wr = w >> 1, wc = w & 1;
  const int lrow = l & 15, lb = l >> 4;

  // prologue: tiles 0,1 into buffers 0,1
  stage_tiles<FM, FN>(A, BT, As, Bs, 0, 0, m0, n0, w, l);
  stage_tiles<FM, FN>(A, BT, As, Bs, 1, 1, m0, n0, w, l);

  int cur = 0, pre = 2;  // pre = (t+2)%3
  for (int t = 0; t < NT; ++t) {
    if (t + 1 < NT) {
      if constexpr (NL == 4) asm volatile("s_waitcnt vmcnt(4)" ::: "memory");
      else if constexpr (NL == 3) asm volatile("s_waitcnt vmcnt(3)" ::: "memory");
      else asm volatile("s_waitcnt vmcnt(0)" ::: "memory");
    } else {
      asm volatile("s_waitcnt vmcnt(0)" ::: "memory");
    }
    __builtin_amdgcn_s_barrier();
    if (t + 2 < NT) stage_tiles<FM, FN>(A, BT, As, Bs, pre, t + 2, m0, n0, w, l);

    const unsigned short* Ab = As + cur * (BM * 32);
    const unsigned short* Bb = Bs + cur * (BN * 32);
    bf16x8 af[FM], bf[FN];
#pragma unroll
    for (int fm = 0; fm < FM; ++fm) {
      int row = wr * 16 * FM + fm * 16 + lrow;
      af[fm] = *(const bf16x8*)&Ab[row * 32 + ((lb ^ ((row >> 1) & 3)) * 8)];
    }
#pragma unroll
    for (int fn = 0; fn < FN; ++fn) {
      int row = wc * 16 * FN + fn * 16 + lrow;
      bf[fn] = *(const bf16x8*)&Bb[row * 32 + ((lb ^ ((row >> 1) & 3)) * 8)];
    }
#pragma unroll
    for (int fm = 0; fm < FM; ++fm)
#pragma unroll
      for (int fn = 0; fn < FN; ++fn)
        acc[fm][fn] = __builtin_amdgcn_mfma_f32_16x16x32_bf16(af[fm], bf[fn], acc[fm][fn], 0, 0, 0);
    cur = (cur == 2) ? 0 : cur + 1;
    pre = (pre == 2) ? 0 : pre + 1;
  }
}

// ---------------- fused Q/K/V projections (blockIdx.z selects) ----------------
__global__ __launch_bounds__(256) void k_qkv(const unsigned short* __restrict__ xbf,
    const unsigned short* __restrict__ qwT, const unsigned short* __restrict__ kwT,
    const unsigned short* __restrict__ vwT,
    unsigned short* __restrict__ Qo, unsigned short* __restrict__ Ko, unsigned short* __restrict__ Vo,
    const float* __restrict__ tabC, const float* __restrict__ tabS) {
  __shared__ unsigned short As[3 * 128 * 32];
  __shared__ unsigned short Bs[3 * 128 * 32];
  const int zz = blockIdx.z;
  const unsigned short* BT = (zz == 0) ? qwT : (zz == 1) ? kwT : vwT;
  unsigned short* Co = (zz == 0) ? Qo : (zz == 1) ? Ko : Vo;
  const int tid = threadIdx.x;
  const int l = tid & 63, w = tid >> 6;
  const int n0 = blockIdx.x * 128, m0 = blockIdx.y * 128;

  f32x4 acc[4][4];
#pragma unroll
  for (int i = 0; i < 4; ++i)
#pragma unroll
    for (int j = 0; j < 4; ++j) acc[i][j] = (f32x4){0.f, 0.f, 0.f, 0.f};

  gemm_loop<4, 4>(xbf, BT, As, Bs, acc, m0, n0, w, l);

  const int wr = w >> 1, wc = w & 1;
#pragma unroll
  for (int fm = 0; fm < 4; ++fm) {
#pragma unroll
    for (int fn = 0; fn < 4; ++fn) {
#pragma unroll
      for (int r = 0; r < 4; ++r) {
        float v = acc[fm][fn][r];
        int row = m0 + wr * 64 + fm * 16 + (l >> 4) * 4 + r;
        int col = n0 + wc * 64 + fn * 16 + (l & 15);
        if (zz < 2) {
          float p = __shfl_xor(v, 1);
          int t = row & (Tc - 1);
          int pi = (col & 63) >> 1;
          float cv = tabC[t * 32 + pi], sv = tabS[t * 32 + pi];
          float res = (col & 1) ? (p * sv + v * cv) : (v * cv - p * sv);
          Co[(size_t)row * Cc + col] = f2bf(phi_fn(res));
        } else {
          Co[(size_t)row * Cc + col] = f2bf(v);
        }
      }
    }
  }
}

// ---------------- out-proj: 64x128 tile, +bias +residual -> fp32 ----------------
__global__ __launch_bounds__(256) void k_oproj(const unsigned short* __restrict__ Ybf,
    const unsigned short* __restrict__ owT, float* __restrict__ Co,
    const float* __restrict__ bias, const float* __restrict__ resid) {
  __shared__ unsigned short As[3 * 64 * 32];
  __shared__ unsigned short Bs[3 * 128 * 32];
  const int tid = threadIdx.x;
  const int l = tid & 63, w = tid >> 6;
  const int n0 = blockIdx.x * 128, m0 = blockIdx.y * 64;

  f32x4 acc[2][4];
#pragma unroll
  for (int i = 0; i < 2; ++i)
#pragma unroll
    for (int j = 0; j < 4; ++j) acc[i][j] = (f32x4){0.f, 0.f, 0.f, 0.f};

  gemm_loop<2, 4>(Ybf, owT, As, Bs, acc, m0, n0, w, l);

  const int wr = w >> 1, wc = w & 1;
#pragma unroll
  for (int fm = 0; fm < 2; ++fm) {
#pragma unroll
    for (int fn = 0; fn < 4; ++fn) {
#pragma unroll
      for (int r = 0; r < 4; ++r) {
        int row = m0 + wr * 32 + fm * 16 + (l >> 4) * 4 + r;
        int col = n0 + wc * 64 + fn * 16 + (l & 15);
        Co[(size_t)row * Cc + col] = acc[fm][fn][r] + bias[col] + resid[(size_t)row * Cc + col];
      }
    }
  }
}

// ---------------- legacy fp32 SIMT GEMM (fallback path only) ----------------
template <typename AT, typename OT, int MODE>
__global__ __launch_bounds__(256) void k_gemm128(
    const AT* __restrict__ A, const float* __restrict__ Bw, OT* __restrict__ Co,
    int M, int N, int K,
    const float* __restrict__ tabC, const float* __restrict__ tabS,
    const float* __restrict__ bias, const float* __restrict__ resid) {
  __shared__ float As[16][132];
  __shared__ float Bs[16][132];
  const int tid = threadIdx.x;
  const int tx = tid & 15, ty = tid >> 4;
  const int n0 = blockIdx.x * 128, m0 = blockIdx.y * 128;
  float acc[8][8];
#pragma unroll
  for (int i = 0; i < 8; ++i)
#pragma unroll
    for (int j = 0; j < 8; ++j) acc[i][j] = 0.f;
  for (int k0 = 0; k0 < K; k0 += 16) {
#pragma unroll
    for (int rep = 0; rep < 2; ++rep) {
      int lin = tid + rep * 256;
      int r = lin >> 2, c4 = (lin & 3) << 2;
      float4 av = ld4(&A[(size_t)(m0 + r) * K + k0 + c4]);
      As[c4 + 0][r] = av.x; As[c4 + 1][r] = av.y;
      As[c4 + 2][r] = av.z; As[c4 + 3][r] = av.w;
      int rb = lin >> 5, cb = (lin & 31) << 2;
      *(float4*)&Bs[rb][cb] = *(const float4*)&Bw[(size_t)(k0 + rb) * N + n0 + cb];
    }
    __syncthreads();
#pragma unroll
    for (int kk = 0; kk < 16; ++kk) {
      float4 a0 = *(const float4*)&As[kk][ty * 8];
      float4 a1 = *(const float4*)&As[kk][ty * 8 + 4];
      float4 b0 = *(const float4*)&Bs[kk][tx * 8];
      float4 b1 = *(const float4*)&Bs[kk][tx * 8 + 4];
      float avv[8] = {a0.x, a0.y, a0.z, a0.w, a1.x, a1.y, a1.z, a1.w};
      float bvv[8] = {b0.x, b0.y, b0.z, b0.w, b1.x, b1.y, b1.z, b1.w};
#pragma unroll
      for (int i = 0; i < 8; ++i)
#pragma unroll
        for (int j = 0; j < 8; ++j) acc[i][j] = fmaf(avv[i], bvv[j], acc[i][j]);
    }
    __syncthreads();
  }
  if constexpr (MODE == 1) {
#pragma unroll
    for (int i = 0; i < 8; ++i) {
      int row = m0 + ty * 8 + i;
      int t = row & (Tc - 1);
#pragma unroll
      for (int j = 0; j < 8; j += 2) {
        int col = n0 + tx * 8 + j;
        int pi = (col & 63) >> 1;
        float cv = tabC[t * 32 + pi], sv = tabS[t * 32 + pi];
        float xe = acc[i][j], xo = acc[i][j + 1];
        stv(&Co[(size_t)row * N + col], phi_fn(xe * cv - xo * sv));
        stv(&Co[(size_t)row * N + col + 1], phi_fn(xe * sv + xo * cv));
      }
    }
  } else if constexpr (MODE == 2) {
#pragma unroll
    for (int i = 0; i < 8; ++i) {
      int row = m0 + ty * 8 + i;
#pragma unroll
      for (int j = 0; j < 8; ++j) {
        int col = n0 + tx * 8 + j;
        stv(&Co[(size_t)row * N + col], acc[i][j] + bias[col] + resid[(size_t)row * N + col]);
      }
    }
  } else {
#pragma unroll
    for (int i = 0; i < 8; ++i) {
      int row = m0 + ty * 8 + i;
#pragma unroll
      for (int j = 0; j < 8; ++j) {
        int col = n0 + tx * 8 + j;
        stv(&Co[(size_t)row * N + col], acc[i][j]);
      }
    }
  }
}

// ---------------- gate/decay projections (writes RATE) + fused x->bf16 ----------------
__global__ __launch_bounds__(256) void k_small(
    const float* __restrict__ x, const float* __restrict__ gate_w, const float* __restrict__ gate_b,
    const float* __restrict__ decay_w, const float* __restrict__ decay_b,
    const float* __restrict__ decay_w0, float* __restrict__ gate_o, float* __restrict__ rate_o,
    unsigned short* __restrict__ xbf_o) {
  __shared__ float xs[1024];
  __shared__ float part[8][32];
  int bt = blockIdx.x;
  int tid = threadIdx.x;
  float4 xv = *(const float4*)&x[(size_t)bt * Cc + tid * 4];
  *(float4*)&xs[tid * 4] = xv;
  if (xbf_o) {
    ushort4 u = make_ushort4(f2bf(xv.x), f2bf(xv.y), f2bf(xv.z), f2bf(xv.w));
    *(ushort4*)&xbf_o[(size_t)bt * Cc + tid * 4] = u;
  }
  __syncthreads();
  int o = tid & 31, seg = tid >> 5;
  const float* wp = (o < 16) ? gate_w : decay_w;
  int oc = o & 15;
  float p = 0.f;
  int kb = seg * 128;
#pragma unroll 4
  for (int kk = 0; kk < 128; ++kk) {
    int k = kb + kk;
    p = fmaf(xs[k], wp[(size_t)k * 16 + oc], p);
  }
  part[seg][o] = p;
  __syncthreads();
  if (tid < 32) {
    float s = 0.f;
#pragma unroll
    for (int sg = 0; sg < 8; ++sg) s += part[sg][tid];
    int b = bt >> 11, t = bt & (Tc - 1);
    if (tid < 16) {
      float gv = 1.f / (1.f + expf(-(s + gate_b[tid])));
      gate_o[((size_t)(b * Hc + tid)) * Tc + t] = gv;
    } else {
      int hh = tid - 16;
      float raw = s + decay_b[hh] + decay_w0[hh];
      float sp = raw > 20.f ? raw : log1pf(expf(raw));
      float rate = fminf(fmaxf(sp, 1e-4f), 10.f);
      rate_o[((size_t)(b * Hc + hh)) * Tc + t] = rate;
    }
  }
}

// ---------------- Phase A (MFMA): per-chunk summaries S^T[e][d], Dsum[d], P ----------------
__global__ __launch_bounds__(256) void k_scanA2(
    const unsigned short* __restrict__ Kb, const unsigned short* __restrict__ Vb,
    const float* __restrict__ rateB, const float* __restrict__ gateB,
    unsigned short* __restrict__ S, float* __restrict__ Dsum, float* __restrict__ Pbuf) {
  int blk = blockIdx.x;
  int bh = blk >> 5, c = blk & 31;
  int b = bh >> 4, h = bh & 15;
  int tid = threadIdx.x;
  int l = tid & 63, wv = tid >> 6;
  __shared__ unsigned short KT[64 * TP];   // [d][s]
  __shared__ unsigned short VT[64 * TP];   // [e][s], scaled by w_s
  __shared__ float Rc[64], gs[64], ws[64];
  size_t base = ((size_t)b * Tc + (size_t)c * 64) * Cc + h * 64;
  {
    int s = tid >> 2, d0g = (tid & 3) * 16;
    const unsigned short* kr = Kb + base + (size_t)s * Cc + d0g;
    unsigned short kv[16];
    *(uint4*)kv = *(const uint4*)kr; *(uint4*)(kv + 8) = *(const uint4*)(kr + 8);
#pragma unroll
    for (int i = 0; i < 16; ++i) KT[(d0g + i) * TP + s] = kv[i];
  }
  if (wv == 0) {
    float r = rateB[(size_t)bh * Tc + c * 64 + l];
    float g = gateB[(size_t)bh * Tc + c * 64 + l];
    float v = r;
#pragma unroll
    for (int off = 1; off < 64; off <<= 1) { float u = __shfl_up(v, off); if (l >= off) v += u; }
    Rc[l] = v; gs[l] = g;
  }
  __syncthreads();
  float Rtot = Rc[63];
  if (wv == 0) ws[l] = __expf(Rc[l] - Rtot) * gs[l];
  __syncthreads();
  {
    int s = tid >> 2, e0g = (tid & 3) * 16;
    float wsv = ws[s];
    const unsigned short* vr = Vb + base + (size_t)s * Cc + e0g;
    unsigned short vvv[16];
    *(uint4*)vvv = *(const uint4*)vr; *(uint4*)(vvv + 8) = *(const uint4*)(vr + 8);
#pragma unroll
    for (int i = 0; i < 16; ++i) VT[(e0g + i) * TP + s] = f2bf(bf2f(vvv[i]) * wsv);
  }
  __syncthreads();
  f32x4 acc[4];
#pragma unroll
  for (int i = 0; i < 4; ++i) acc[i] = (f32x4){0.f, 0.f, 0.f, 0.f};
  const int lrow = l & 15, lk8 = (l >> 4) * 8;
#pragma unroll
  for (int ks = 0; ks < 2; ++ks) {
    bf16x8 a = *(const bf16x8*)&VT[(wv * 16 + lrow) * TP + ks * 32 + lk8];
#pragma unroll
    for (int fn = 0; fn < 4; ++fn) {
      bf16x8 bb = *(const bf16x8*)&KT[(fn * 16 + lrow) * TP + ks * 32 + lk8];
      acc[fn] = __builtin_amdgcn_mfma_f32_16x16x32_bf16(a, bb, acc[fn], 0, 0, 0);
    }
  }
  size_t sb = (size_t)blk * 4096;
#pragma unroll
  for (int fn = 0; fn < 4; ++fn)
#pragma unroll
    for (int r = 0; r < 4; ++r) {
      int e = wv * 16 + (l >> 4) * 4 + r;
      int d = fn * 16 + (l & 15);
      S[sb + e * 64 + d] = f2bf(acc[fn][r]);
    }
  if (tid < 64) {
    float s = 0.f;
#pragma unroll 8
    for (int ss = 0; ss < 64; ++ss) s += bf2f(KT[tid * TP + ss]) * ws[ss];
    Dsum[(size_t)blk * 64 + tid] = s;
  }
  if (tid == 0) Pbuf[blk] = __expf(-Rtot);
}

// ---------------- Phase B: serial carry across chunks (1-deep prefetch) ----------------
__global__ __launch_bounds__(256) void k_scanB(unsigned short* __restrict__ S, float* __restrict__ Dsum,
                                               const float* __restrict__ Pbuf) {
  int bh = blockIdx.x;
  int tid = threadIdx.x;
  float Nreg[16];
#pragma unroll
  for (int k = 0; k < 16; ++k) Nreg[k] = 0.f;
  float Dreg = 0.f;
  unsigned short curS[16]; float curD = 0.f, curP;
  {
    size_t sb = ((size_t)bh * NCc) * 4096;
#pragma unroll
    for (int k = 0; k < 16; ++k) curS[k] = S[sb + tid + k * 256];
    if (tid < 64) curD = Dsum[((size_t)bh * NCc) * 64 + tid];
    curP = Pbuf[bh * NCc];
  }
  for (int c = 0; c < NCc; ++c) {
    unsigned short nxtS[16]; float nxtD = 0.f, nxtP = 0.f;
    if (c + 1 < NCc) {
      size_t sb = ((size_t)bh * NCc + c + 1) * 4096;
#pragma unroll
      for (int k = 0; k < 16; ++k) nxtS[k] = S[sb + tid + k * 256];
      if (tid < 64) nxtD = Dsum[((size_t)bh * NCc + c + 1) * 64 + tid];
      nxtP = Pbuf[bh * NCc + c + 1];
    }
    size_t sb = ((size_t)bh * NCc + c) * 4096;
#pragma unroll
    for (int k = 0; k < 16; ++k) {
      float tmp = bf2f(curS[k]);
      S[sb + tid + k * 256] = f2bf(Nreg[k]);
      Nreg[k] = Nreg[k] * curP + tmp;
    }
    if (tid < 64) {
      size_t db = ((size_t)bh * NCc + c) * 64 + tid;
      float tmp = curD;
      Dsum[db] = Dreg;
      Dreg = Dreg * curP + tmp;
    }
#pragma unroll
    for (int k = 0; k < 16; ++k) curS[k] = nxtS[k];
    curD = nxtD; curP = nxtP;
  }
}

// ---------------- Phase C (MFMA): intra-chunk + start-state, full output ----------------
__global__ __launch_bounds__(256) void k_scanC2(
    const unsigned short* __restrict__ Qb, const unsigned short* __restrict__ Kb,
    const unsigned short* __restrict__ Vb,
    const float* __restrict__ rateB, const float* __restrict__ gateB,
    const unsigned short* __restrict__ S, const float* __restrict__ Dsum,
    unsigned short* __restrict__ Yb) {
  int blk = blockIdx.x;
  int bh = blk >> 5, c = blk & 31;
  int b = bh >> 4, h = bh & 15;
  int tid = threadIdx.x;
  int l = tid & 63, wv = tid >> 6;
  __shared__ unsigned short Qs[64 * TP];
  __shared__ unsigned short Ks[64 * TP];   // overlaid by W' after QK
  __shared__ unsigned short VT[64 * TP];
  __shared__ unsigned short Ss[64 * TP];
  __shared__ float Rc[64], gs[64], DstL[64];
  size_t base = ((size_t)b * Tc + (size_t)c * 64) * Cc + h * 64;
  {
    int rr = tid >> 2, c0 = (tid & 3) * 16;
    const unsigned short* qr = Qb + base + (size_t)rr * Cc + c0;
    const unsigned short* kr = Kb + base + (size_t)rr * Cc + c0;
    const unsigned short* vr = Vb + base + (size_t)rr * Cc + c0;
    const unsigned short* sr = S + (size_t)blk * 4096 + rr * 64 + c0;
    *(uint4*)&Qs[rr * TP + c0] = *(const uint4*)qr;
    *(uint4*)&Qs[rr * TP + c0 + 8] = *(const uint4*)(qr + 8);
    *(uint4*)&Ks[rr * TP + c0] = *(const uint4*)kr;
    *(uint4*)&Ks[rr * TP + c0 + 8] = *(const uint4*)(kr + 8);
    *(uint4*)&Ss[rr * TP + c0] = *(const uint4*)sr;
    *(uint4*)&Ss[rr * TP + c0 + 8] = *(const uint4*)(sr + 8);
    unsigned short vvv[16];
    *(uint4*)vvv = *(const uint4*)vr; *(uint4*)(vvv + 8) = *(const uint4*)(vr + 8);
#pragma unroll
    for (int i = 0; i < 16; ++i) VT[(c0 + i) * TP + rr] = vvv[i];
  }
  if (wv == 0) {
    float r = rateB[(size_t)bh * Tc + c * 64 + l];
    float g = gateB[(size_t)bh * Tc + c * 64 + l];
    float v = r;
#pragma unroll
    for (int off = 1; off < 64; off <<= 1) { float u = __shfl_up(v, off); if (l >= off) v += u; }
    Rc[l] = v; gs[l] = g;
    DstL[l] = Dsum[(size_t)blk * 64 + l];
  }
  __syncthreads();
  const int lrow = l & 15, lk8 = (l >> 4) * 8;
  f32x4 qk[4];
#pragma unroll
  for (int i = 0; i < 4; ++i) qk[i] = (f32x4){0.f, 0.f, 0.f, 0.f};
#pragma unroll
  for (int ks = 0; ks < 2; ++ks) {
    bf16x8 a = *(const bf16x8*)&Qs[(wv * 16 + lrow) * TP + ks * 32 + lk8];
#pragma unroll
    for (int fn = 0; fn < 4; ++fn) {
      bf16x8 bb = *(const bf16x8*)&Ks[(fn * 16 + lrow) * TP + ks * 32 + lk8];
      qk[fn] = __builtin_amdgcn_mfma_f32_16x16x32_bf16(a, bb, qk[fn], 0, 0, 0);
    }
  }
  __syncthreads();
  float deni[4] = {0.f, 0.f, 0.f, 0.f};
  float rct[4];
#pragma unroll
  for (int r = 0; r < 4; ++r) rct[r] = Rc[wv * 16 + (l >> 4) * 4 + r];
#pragma unroll
  for (int fn = 0; fn < 4; ++fn) {
    int s = fn * 16 + (l & 15);
    float rs = Rc[s], g = gs[s];
#pragma unroll
    for (int r = 0; r < 4; ++r) {
      int t = wv * 16 + (l >> 4) * 4 + r;
      float wgt = (s <= t) ? __expf(rs - rct[r]) * g : 0.f;
      unsigned short sb16 = f2bf(qk[fn][r] * wgt);
      deni[r] += bf2f(sb16);
      Ks[t * TP + s] = sb16;
    }
  }
#pragma unroll
  for (int r = 0; r < 4; ++r) {
    deni[r] += __shfl_xor(deni[r], 1);
    deni[r] += __shfl_xor(deni[r], 2);
    deni[r] += __shfl_xor(deni[r], 4);
    deni[r] += __shfl_xor(deni[r], 8);
  }
  f32x4 nm[4], nm2[4], dn2;
#pragma unroll
  for (int i = 0; i < 4; ++i) { nm[i] = (f32x4){0.f,0.f,0.f,0.f}; nm2[i] = (f32x4){0.f,0.f,0.f,0.f}; }
  dn2 = (f32x4){0.f, 0.f, 0.f, 0.f};
#pragma unroll
  for (int ks = 0; ks < 2; ++ks) {
    bf16x8 aw = *(const bf16x8*)&Ks[(wv * 16 + lrow) * TP + ks * 32 + lk8];
    bf16x8 aq = *(const bf16x8*)&Qs[(wv * 16 + lrow) * TP + ks * 32 + lk8];
#pragma unroll
    for (int fn = 0; fn < 4; ++fn) {
      bf16x8 bv = *(const bf16x8*)&VT[(fn * 16 + lrow) * TP + ks * 32 + lk8];
      bf16x8 bs = *(const bf16x8*)&Ss[(fn * 16 + lrow) * TP + ks * 32 + lk8];
      nm[fn] = __builtin_amdgcn_mfma_f32_16x16x32_bf16(aw, bv, nm[fn], 0, 0, 0);
      nm2[fn] = __builtin_amdgcn_mfma_f32_16x16x32_bf16(aq, bs, nm2[fn], 0, 0, 0);
    }
    bf16x8 bd = (bf16x8){0, 0, 0, 0, 0, 0, 0, 0};
    if (lrow == 0) {
#pragma unroll
      for (int i = 0; i < 8; ++i) bd[i] = (short)f2bf(DstL[ks * 32 + lk8 + i]);
    }
    dn2 = __builtin_amdgcn_mfma_f32_16x16x32_bf16(aq, bd, dn2, 0, 0, 0);
  }
  float den2v[4];
#pragma unroll
  for (int r = 0; r < 4; ++r) den2v[r] = __shfl(dn2[r], (l & 48));
#pragma unroll
  for (int r = 0; r < 4; ++r) {
    int t = wv * 16 + (l >> 4) * 4 + r;
    float at = __expf(-rct[r]);
    float dv = deni[r] + at * den2v[r] + 1e-6f;
#pragma unroll
    for (int fn = 0; fn < 4; ++fn) {
      int e = fn * 16 + (l & 15);
      float numv = nm[fn][r] + at * nm2[fn][r];
      Yb[base + (size_t)t * Cc + e] = f2bf(numv / dv);
    }
  }
}

// ---------------- legacy serial scan (fallback path only; rate input) ----------------
__device__ __forceinline__ void load16(const unsigned short* __restrict__ p, float* d) {
  uint4 u = *(const uint4*)p;
  uint4 v = *(const uint4*)(p + 8);
  d[0] = __uint_as_float(u.x << 16); d[1] = __uint_as_float(u.x & 0xFFFF0000u);
  d[2] = __uint_as_float(u.y << 16); d[3] = __uint_as_float(u.y & 0xFFFF0000u);
  d[4] = __uint_as_float(u.z << 16); d[5] = __uint_as_float(u.z & 0xFFFF0000u);
  d[6] = __uint_as_float(u.w << 16); d[7] = __uint_as_float(u.w & 0xFFFF0000u);
  d[8] = __uint_as_float(v.x << 16); d[9] = __uint_as_float(v.x & 0xFFFF0000u);
  d[10] = __uint_as_float(v.y << 16); d[11] = __uint_as_float(v.y & 0xFFFF0000u);
  d[12] = __uint_as_float(v.z << 16); d[13] = __uint_as_float(v.z & 0xFFFF0000u);
  d[14] = __uint_as_float(v.w << 16); d[15] = __uint_as_float(v.w & 0xFFFF0000u);
}

__global__ __launch_bounds__(256) void k_scan(const unsigned short* __restrict__ phiQ,
    const unsigned short* __restrict__ phiK, const unsigned short* __restrict__ Vb,
    const float* __restrict__ rateB, const float* __restrict__ gateB,
    unsigned short* __restrict__ Yb) {
  int bh = blockIdx.x;
  int b = bh >> 4, h = bh & 15;
  int tid = threadIdx.x;
  int w = tid >> 6, l = tid & 63;
  int e = (w << 4) | (l & 15);
  int d0 = (l >> 4) << 4;
  size_t base = ((size_t)b * Tc) * Cc + h * 64;
  const unsigned short* qp = phiQ + base + d0;
  const unsigned short* kp = phiK + base + d0;
  const unsigned short* vp = Vb + base + e;
  const float* bp = rateB + (size_t)bh * Tc;
  const float* gp = gateB + (size_t)bh * Tc;
  unsigned short* yp = Yb + base + e;
  float Ns[16], Ds[16];
#pragma unroll
  for (int j = 0; j < 16; ++j) { Ns[j] = 0.f; Ds[j] = 0.f; }
  const bool wr = (l < 16);
  for (int t = 0; t < Tc; ++t) {
    float q[16], k[16];
    load16(qp + (size_t)t * Cc, q);
    load16(kp + (size_t)t * Cc, k);
    float vv = bf2f(vp[(size_t)t * Cc]);
    float btv = __expf(-bp[t]), gtv = gp[t];
    float yn = 0.f, den = 0.f;
#pragma unroll
    for (int j = 0; j < 16; ++j) {
      float wj = k[j] * gtv;
      float ns = fmaf(Ns[j], btv, wj * vv);
      float ds = fmaf(Ds[j], btv, wj);
      Ns[j] = ns; Ds[j] = ds;
      yn = fmaf(q[j], ns, yn);
      den = fmaf(q[j], ds, den);
    }
    yn += __shfl_xor(yn, 16); yn += __shfl_xor(yn, 32);
    den += __shfl_xor(den, 16); den += __shfl_xor(den, 32);
    if (wr) yp[(size_t)t * Cc] = f2bf(yn / (den + 1e-6f));
  }
}

// ---------------- row LayerNorm -> fp32 out ----------------
__global__ __launch_bounds__(256) void k_ln(const float* __restrict__ pre, const float* __restrict__ ln_g,
    const float* __restrict__ ln_b, float* __restrict__ out) {
  int row = blockIdx.x;
  int tid = threadIdx.x;
  float4 v = *(const float4*)&pre[(size_t)row * Cc + tid * 4];
  float s = v.x + v.y + v.z + v.w;
  float q = v.x * v.x + v.y * v.y + v.z * v.z + v.w * v.w;
#pragma unroll
  for (int off = 1; off < 64; off <<= 1) {
    s += __shfl_xor(s, off);
    q += __shfl_xor(q, off);
  }
  __shared__ float ss[4], qq[4];
  if ((tid & 63) == 0) { ss[tid >> 6] = s; qq[tid >> 6] = q; }
  __syncthreads();
  s = ss[0] + ss[1] + ss[2] + ss[3];
  q = qq[0] + qq[1] + qq[2] + qq[3];
  float mu = s * (1.f / 1024.f);
  float var = q * (1.f / 1024.f) - mu * mu;
  float rstd = rsqrtf(var + 1e-5f);
  int c0 = tid * 4;
  float4 g = *(const float4*)&ln_g[c0];
  float4 bb = *(const float4*)&ln_b[c0];
  float4 o;
  o.x = (v.x - mu) * rstd * g.x + bb.x;
  o.y = (v.y - mu) * rstd * g.y + bb.y;
  o.z = (v.z - mu) * rstd * g.z + bb.z;
  o.w = (v.w - mu) * rstd * g.w + bb.w;
  *(float4*)&out[(size_t)row * Cc + c0] = o;
}

extern "C" void kernel_launch(void* const* d_in, const int* in_sizes, int n_in,
                              void* d_out, int out_size, void* d_ws, size_t ws_size,
                              hipStream_t stream) {
  const float* x        = (const float*)d_in[0];
  const float* q_w      = (const float*)d_in[1];
  const float* k_w      = (const float*)d_in[2];
  const float* v_w      = (const float*)d_in[3];
  const float* out_w    = (const float*)d_in[4];
  const float* out_b    = (const float*)d_in[5];
  const float* decay_w  = (const float*)d_in[6];
  const float* decay_b  = (const float*)d_in[7];
  const float* gate_w   = (const float*)d_in[8];
  const float* gate_b   = (const float*)d_in[9];
  const float* decay_w0 = (const float*)d_in[10];
  const float* ln_g     = (const float*)d_in[11];
  const float* ln_b     = (const float*)d_in[12];
  float* out            = (float*)d_out;

  const size_t MC  = (size_t)Mc * Cc;
  const size_t BHT = (size_t)Bc * Hc * Tc;
  const int NBH = Bc * Hc;                 // 32

  const bool fp32path = ws_size >= (size_t)52 * 1024 * 1024;

  if (fp32path) {
    char* p = (char*)d_ws;
    float* tabC = (float*)p;                    p += (size_t)Tc * 32 * 4;
    float* tabS = (float*)p;                    p += (size_t)Tc * 32 * 4;
    unsigned short* xbf   = (unsigned short*)p; p += MC * 2;        // S aliases (8 MiB)
    unsigned short* qwT   = (unsigned short*)p; p += (size_t)Cc * Cc * 2;
    unsigned short* kwT   = (unsigned short*)p; p += (size_t)Cc * Cc * 2;
    unsigned short* vwT   = (unsigned short*)p; p += (size_t)Cc * Cc * 2;
    unsigned short* owT   = (unsigned short*)p; p += (size_t)Cc * Cc * 2;
    unsigned short* phiQb = (unsigned short*)p; p += MC * 2;        // preO overlays phiQb+Vbf
    unsigned short* Vbf   = (unsigned short*)p; p += MC * 2;
    unsigned short* phiKb = (unsigned short*)p; p += MC * 2;
    unsigned short* Ybf   = (unsigned short*)p; p += MC * 2;
    float* rateB = (float*)p;                   p += BHT * 4;
    float* gateB = (float*)p;                   p += BHT * 4;
    float* Dsum  = (float*)p;                   p += (size_t)NBH * NCc * 64 * 4;
    float* Pbuf  = (float*)p;                   p += (size_t)NBH * NCc * 4;
    unsigned short* S = xbf;                    // xbf dead after projection GEMMs
    float* preO = (float*)phiQb;                // phiQb+Vbf dead after scanC2

    k_tables<<<(Tc * 32) / 256, 256, 0, stream>>>(tabC, tabS);
    k_trans<<<dim3(Cc / 32, Cc / 32, 4), 256, 0, stream>>>(q_w, k_w, v_w, out_w, qwT, kwT, vwT, owT);
    k_small<<<Mc, 256, 0, stream>>>(x, gate_w, gate_b, decay_w, decay_b, decay_w0, gateB, rateB, xbf);

    k_qkv<<<dim3(Cc / 128, Mc / 128, 3), 256, 0, stream>>>(xbf, qwT, kwT, vwT,
                                                           phiQb, phiKb, Vbf, tabC, tabS);

    k_scanA2<<<NBH * NCc, 256, 0, stream>>>(phiKb, Vbf, rateB, gateB, S, Dsum, Pbuf);
    k_scanB<<<NBH, 256, 0, stream>>>(S, Dsum, Pbuf);
    k_scanC2<<<NBH * NCc, 256, 0, stream>>>(phiQb, phiKb, Vbf, rateB, gateB, S, Dsum, Ybf);

    k_oproj<<<dim3(Cc / 128, Mc / 64), 256, 0, stream>>>(Ybf, owT, preO, out_b, x);
    k_ln<<<Mc, 256, 0, stream>>>(preO, ln_g, ln_b, out);
  } else {
    // ---- 33 MiB bf16-intermediate fallback (serial scan, SIMT GEMM) ----
    float* tabC  = (float*)d_ws;
    float* tabS  = tabC + (size_t)Tc * 32;
    unsigned short* phiQb = (unsigned short*)(tabS + (size_t)Tc * 32);
    unsigned short* phiKb = phiQb + MC;
    unsigned short* Vbb   = phiKb + MC;
    unsigned short* Ybb   = Vbb + MC;
    float* rateB = (float*)(Ybb + MC);
    float* gateB = rateB + BHT;
    float* preO  = (float*)phiQb;
    dim3 gg(Cc / 128, Mc / 128);

    k_tables<<<(Tc * 32) / 256, 256, 0, stream>>>(tabC, tabS);
    k_gemm128<float, unsigned short, 1><<<gg, 256, 0, stream>>>(x, q_w, phiQb, Mc, Cc, Cc, tabC, tabS, nullptr, nullptr);
    k_gemm128<float, unsigned short, 1><<<gg, 256, 0, stream>>>(x, k_w, phiKb, Mc, Cc, Cc, tabC, tabS, nullptr, nullptr);
    k_gemm128<float, unsigned short, 0><<<gg, 256, 0, stream>>>(x, v_w, Vbb, Mc, Cc, Cc, nullptr, nullptr, nullptr, nullptr);
    k_small<<<Mc, 256, 0, stream>>>(x, gate_w, gate_b, decay_w, decay_b, decay_w0, gateB, rateB, nullptr);
    k_scan<<<Bc * Hc, 256, 0, stream>>>(phiQb, phiKb, Vbb, rateB, gateB, Ybb);
    k_gemm128<unsigned short, float, 2><<<gg, 256, 0, stream>>>(Ybb, out_w, preO, Mc, Cc, Cc, nullptr, nullptr, out_b, x);
    k_ln<<<Mc, 256, 0, stream>>>(preO, ln_g, ln_b, out);
  }
}